// Round 5
// baseline (458.998 us; speedup 1.0000x reference)
//
#include <hip/hip_runtime.h>
#include <math.h>

// MambaSSMBlock: B=2, L=2048, Dm=1024, Di=2048, N=16, convK=4
// Round 5: xp projection -> 64-block bf16x3 MFMA skinny GEMM (N pad 48);
//   conv emits x_ssm as bf16 hi/lo pair (scan1 reconstructs h+l).
//   Kills xp_kernel's 1.1 GB L2 re-read of W_xproj + 1-wave serialization.
// Workspace: ~193 MB (same footprint as R4).

#define B_SZ 2
#define LSEQ 2048
#define DM   1024
#define DI   2048
#define NS   16
#define RTOT (B_SZ*LSEQ)   // 4096 rows
#define NC   64            // scan chunks
#define TC   (LSEQ/NC)     // 32 steps per chunk
#define XZL  4096          // xz leading dim (x_ssm cols 0..2047, z cols 2048..4095)
#define NPAD 48            // xp GEMM padded N (33 -> 48)

typedef __attribute__((ext_vector_type(8))) short bfrag;
typedef __attribute__((ext_vector_type(4))) float f32x4;

__device__ __forceinline__ float siluf(float v){ return v / (1.f + __expf(-v)); }

__device__ __forceinline__ unsigned short f2bf(float f){
  unsigned int u = __float_as_uint(f);
  u += 0x7FFFu + ((u >> 16) & 1u);
  return (unsigned short)(u >> 16);
}
__device__ __forceinline__ float bf2f(unsigned short h){
  return __uint_as_float(((unsigned int)h) << 16);
}

// ---------------- LayerNorm fused with bf16 hi/lo split ----------------
__global__ __launch_bounds__(256)
void ln_split_kernel(const float* __restrict__ x, const float* __restrict__ g,
                     const float* __restrict__ b,
                     unsigned short* __restrict__ xh, unsigned short* __restrict__ xl) {
  __shared__ float red[8];
  const int r = blockIdx.x, tid = threadIdx.x;
  const float4 v = ((const float4*)(x + (size_t)r*DM))[tid];
  float s  = v.x+v.y+v.z+v.w;
  float ss = v.x*v.x+v.y*v.y+v.z*v.z+v.w*v.w;
  #pragma unroll
  for (int off=32; off; off>>=1){ s += __shfl_xor(s,off); ss += __shfl_xor(ss,off); }
  if ((tid & 63)==0){ int w=tid>>6; red[w]=s; red[4+w]=ss; }
  __syncthreads();
  s  = red[0]+red[1]+red[2]+red[3];
  ss = red[4]+red[5]+red[6]+red[7];
  const float mu  = s*(1.f/DM);
  const float inv = rsqrtf(ss*(1.f/DM) - mu*mu + 1e-5f);
  const float4 gv = ((const float4*)g)[tid];
  const float4 bv = ((const float4*)b)[tid];
  float o[4];
  o[0] = (v.x-mu)*inv*gv.x + bv.x;
  o[1] = (v.y-mu)*inv*gv.y + bv.y;
  o[2] = (v.z-mu)*inv*gv.z + bv.z;
  o[3] = (v.w-mu)*inv*gv.w + bv.w;
  ushort4 h, l;
  h.x = f2bf(o[0]); l.x = f2bf(o[0] - bf2f(h.x));
  h.y = f2bf(o[1]); l.y = f2bf(o[1] - bf2f(h.y));
  h.z = f2bf(o[2]); l.z = f2bf(o[2] - bf2f(h.z));
  h.w = f2bf(o[3]); l.w = f2bf(o[3] - bf2f(h.w));
  ((ushort4*)(xh + (size_t)r*DM))[tid] = h;
  ((ushort4*)(xl + (size_t)r*DM))[tid] = l;
}

// ---------------- generic fp32 -> bf16 hi/lo split (weights) ----------------
__global__ __launch_bounds__(256)
void split_kernel(const float* __restrict__ in, unsigned short* __restrict__ hi,
                  unsigned short* __restrict__ lo, int n4) {
  const int i = blockIdx.x*256 + threadIdx.x;
  if (i >= n4) return;
  const float4 v = ((const float4*)in)[i];
  ushort4 h, l;
  h.x = f2bf(v.x); l.x = f2bf(v.x - bf2f(h.x));
  h.y = f2bf(v.y); l.y = f2bf(v.y - bf2f(h.y));
  h.z = f2bf(v.z); l.z = f2bf(v.z - bf2f(h.z));
  h.w = f2bf(v.w); l.w = f2bf(v.w - bf2f(h.w));
  ((ushort4*)hi)[i] = h;
  ((ushort4*)lo)[i] = l;
}

// ---------------- Wx split with zero pad to 48 rows ----------------
__global__ __launch_bounds__(256)
void split_pad_wx_kernel(const float* __restrict__ in, unsigned short* __restrict__ hi,
                         unsigned short* __restrict__ lo) {
  const int i = blockIdx.x*256 + threadIdx.x;   // over 48*2048/4
  if (i >= NPAD*DI/4) return;
  const int row = i >> 9;            // /512 f32x4 per row
  float4 v = make_float4(0.f,0.f,0.f,0.f);
  if (row < 33) v = ((const float4*)in)[i];
  ushort4 h, l;
  h.x = f2bf(v.x); l.x = f2bf(v.x - bf2f(h.x));
  h.y = f2bf(v.y); l.y = f2bf(v.y - bf2f(h.y));
  h.z = f2bf(v.z); l.z = f2bf(v.z - bf2f(h.z));
  h.w = f2bf(v.w); l.w = f2bf(v.w - bf2f(h.w));
  ((ushort4*)hi)[i] = h;
  ((ushort4*)lo)[i] = l;
}

// ---------------- bf16x3 MFMA GEMM 128x128: C = A * B^T ----------------
__global__ __launch_bounds__(256)
void gemm_bf16x3(const unsigned short* __restrict__ Ah, const unsigned short* __restrict__ Al,
                 const unsigned short* __restrict__ Bh, const unsigned short* __restrict__ Bl,
                 float* __restrict__ C, int M, int N, int K, int ldc)
{
  __shared__ __align__(16) unsigned short lds[4][128][40];
  const int tid = threadIdx.x;
  const int bm = blockIdx.y << 7;
  const int bn = blockIdx.x << 7;
  const int wave = tid >> 6;
  const int lane = tid & 63;
  const int wm = (wave >> 1) << 6;
  const int wn = (wave & 1) << 6;
  const int fr = lane & 15;
  const int kg = lane >> 4;
  const int srow = tid >> 1;          // 0..127
  const int scol = (tid & 1) << 4;    // 0 or 16 (ushort units)

  const unsigned short* pAh = Ah + (size_t)(bm + srow)*K + scol;
  const unsigned short* pAl = Al + (size_t)(bm + srow)*K + scol;
  const unsigned short* pBh = Bh + (size_t)(bn + srow)*K + scol;
  const unsigned short* pBl = Bl + (size_t)(bn + srow)*K + scol;

  f32x4 acc[4][4];
  #pragma unroll
  for (int m=0;m<4;m++)
    #pragma unroll
    for (int n=0;n<4;n++)
      #pragma unroll
      for (int r=0;r<4;r++) acc[m][n][r] = 0.f;

  uint4 ra0, ra1, rb0, rb1, rc0, rc1, rd0, rd1;
#define LOAD8(k0) do { \
    ra0 = *(const uint4*)(pAh + (k0));     ra1 = *(const uint4*)(pAh + (k0) + 8); \
    rb0 = *(const uint4*)(pAl + (k0));     rb1 = *(const uint4*)(pAl + (k0) + 8); \
    rc0 = *(const uint4*)(pBh + (k0));     rc1 = *(const uint4*)(pBh + (k0) + 8); \
    rd0 = *(const uint4*)(pBl + (k0));     rd1 = *(const uint4*)(pBl + (k0) + 8); \
  } while(0)

  const int nIter = K >> 5;
  LOAD8(0);
  for (int it = 0; it < nIter; ++it) {
    __syncthreads();
    *(uint4*)&lds[0][srow][scol] = ra0;  *(uint4*)&lds[0][srow][scol+8] = ra1;
    *(uint4*)&lds[1][srow][scol] = rb0;  *(uint4*)&lds[1][srow][scol+8] = rb1;
    *(uint4*)&lds[2][srow][scol] = rc0;  *(uint4*)&lds[2][srow][scol+8] = rc1;
    *(uint4*)&lds[3][srow][scol] = rd0;  *(uint4*)&lds[3][srow][scol+8] = rd1;
    __syncthreads();
    if (it + 1 < nIter) LOAD8((size_t)(it+1) << 5);

    bfrag ah[4], al[4], bb[4];
    #pragma unroll
    for (int m=0;m<4;m++){
      ah[m] = *(const bfrag*)&lds[0][wm + (m<<4) + fr][kg<<3];
      al[m] = *(const bfrag*)&lds[1][wm + (m<<4) + fr][kg<<3];
    }
    #pragma unroll
    for (int n=0;n<4;n++) bb[n] = *(const bfrag*)&lds[2][wn + (n<<4) + fr][kg<<3];
    #pragma unroll
    for (int m=0;m<4;m++)
      #pragma unroll
      for (int n=0;n<4;n++){
        acc[m][n] = __builtin_amdgcn_mfma_f32_16x16x32_bf16(ah[m], bb[n], acc[m][n], 0, 0, 0);
        acc[m][n] = __builtin_amdgcn_mfma_f32_16x16x32_bf16(al[m], bb[n], acc[m][n], 0, 0, 0);
      }
    #pragma unroll
    for (int n=0;n<4;n++) bb[n] = *(const bfrag*)&lds[3][wn + (n<<4) + fr][kg<<3];
    #pragma unroll
    for (int m=0;m<4;m++)
      #pragma unroll
      for (int n=0;n<4;n++)
        acc[m][n] = __builtin_amdgcn_mfma_f32_16x16x32_bf16(ah[m], bb[n], acc[m][n], 0, 0, 0);
  }
#undef LOAD8

  #pragma unroll
  for (int m=0;m<4;m++)
    #pragma unroll
    for (int n=0;n<4;n++){
      float* Cp = C + (size_t)(bm + wm + (m<<4) + (kg<<2))*ldc + bn + wn + (n<<4) + fr;
      #pragma unroll
      for (int r=0;r<4;r++) Cp[(size_t)r*ldc] = acc[m][n][r];
    }
}

// ---------------- bf16x3 MFMA GEMM 64x128 tile (for K-heavy out GEMM) ----------------
__global__ __launch_bounds__(256)
void gemm_bf16x3_b64(const unsigned short* __restrict__ Ah, const unsigned short* __restrict__ Al,
                     const unsigned short* __restrict__ Bh, const unsigned short* __restrict__ Bl,
                     float* __restrict__ C, int M, int N, int K, int ldc)
{
  __shared__ __align__(16) unsigned short ldsA[2][64][40];
  __shared__ __align__(16) unsigned short ldsB[2][128][40];
  const int tid = threadIdx.x;
  const int bm = blockIdx.y << 6;
  const int bn = blockIdx.x << 7;
  const int wave = tid >> 6;
  const int lane = tid & 63;
  const int wm = (wave >> 1) << 5;    // 0 or 32
  const int wn = (wave & 1) << 6;     // 0 or 64
  const int fr = lane & 15;
  const int kg = lane >> 4;
  const int arow = tid >> 2, acol = (tid & 3) << 3;   // 64x32: 1 uint4/thread
  const int brow = tid >> 1, bcol = (tid & 1) << 4;   // 128x32: 2 uint4/thread

  const unsigned short* pAh = Ah + (size_t)(bm + arow)*K + acol;
  const unsigned short* pAl = Al + (size_t)(bm + arow)*K + acol;
  const unsigned short* pBh = Bh + (size_t)(bn + brow)*K + bcol;
  const unsigned short* pBl = Bl + (size_t)(bn + brow)*K + bcol;

  f32x4 acc[2][4];
  #pragma unroll
  for (int m=0;m<2;m++)
    #pragma unroll
    for (int n=0;n<4;n++)
      #pragma unroll
      for (int r=0;r<4;r++) acc[m][n][r] = 0.f;

  uint4 ra, rb, rc0, rc1, rd0, rd1;
#define LOAD6(k0) do { \
    ra  = *(const uint4*)(pAh + (k0)); \
    rb  = *(const uint4*)(pAl + (k0)); \
    rc0 = *(const uint4*)(pBh + (k0));  rc1 = *(const uint4*)(pBh + (k0) + 8); \
    rd0 = *(const uint4*)(pBl + (k0));  rd1 = *(const uint4*)(pBl + (k0) + 8); \
  } while(0)

  const int nIter = K >> 5;
  LOAD6(0);
  for (int it = 0; it < nIter; ++it) {
    __syncthreads();
    *(uint4*)&ldsA[0][arow][acol] = ra;
    *(uint4*)&ldsA[1][arow][acol] = rb;
    *(uint4*)&ldsB[0][brow][bcol] = rc0;  *(uint4*)&ldsB[0][brow][bcol+8] = rc1;
    *(uint4*)&ldsB[1][brow][bcol] = rd0;  *(uint4*)&ldsB[1][brow][bcol+8] = rd1;
    __syncthreads();
    if (it + 1 < nIter) LOAD6((size_t)(it+1) << 5);

    bfrag ah[2], al[2], bh[4], bl[4];
    #pragma unroll
    for (int m=0;m<2;m++){
      ah[m] = *(const bfrag*)&ldsA[0][wm + (m<<4) + fr][kg<<3];
      al[m] = *(const bfrag*)&ldsA[1][wm + (m<<4) + fr][kg<<3];
    }
    #pragma unroll
    for (int n=0;n<4;n++){
      bh[n] = *(const bfrag*)&ldsB[0][wn + (n<<4) + fr][kg<<3];
      bl[n] = *(const bfrag*)&ldsB[1][wn + (n<<4) + fr][kg<<3];
    }
    #pragma unroll
    for (int m=0;m<2;m++)
      #pragma unroll
      for (int n=0;n<4;n++){
        acc[m][n] = __builtin_amdgcn_mfma_f32_16x16x32_bf16(ah[m], bh[n], acc[m][n], 0, 0, 0);
        acc[m][n] = __builtin_amdgcn_mfma_f32_16x16x32_bf16(al[m], bh[n], acc[m][n], 0, 0, 0);
        acc[m][n] = __builtin_amdgcn_mfma_f32_16x16x32_bf16(ah[m], bl[n], acc[m][n], 0, 0, 0);
      }
  }
#undef LOAD6

  #pragma unroll
  for (int m=0;m<2;m++)
    #pragma unroll
    for (int n=0;n<4;n++){
      float* Cp = C + (size_t)(bm + wm + (m<<4) + (kg<<2))*ldc + bn + wn + (n<<4) + fr;
      #pragma unroll
      for (int r=0;r<4;r++) Cp[(size_t)r*ldc] = acc[m][n][r];
    }
}

// ---------------- depthwise causal conv K=4 + bias + SiLU -> bf16 hi/lo ----------------
__global__ __launch_bounds__(256)
void conv_silu_split_kernel(const float* __restrict__ xz, const float* __restrict__ cw,
                            const float* __restrict__ cb,
                            unsigned short* __restrict__ xsh, unsigned short* __restrict__ xsl) {
  const int idx = blockIdx.x * 256 + threadIdx.x;  // over RTOT * DI/4
  const int d4 = idx & (DI/4 - 1);
  const int r  = idx >> 9;
  const int b  = r >> 11;
  const int t  = r & (LSEQ-1);
  const int d  = d4 << 2;
  const float4 w0 = *(const float4*)(cw + (size_t)(d+0)*4);
  const float4 w1 = *(const float4*)(cw + (size_t)(d+1)*4);
  const float4 w2 = *(const float4*)(cw + (size_t)(d+2)*4);
  const float4 w3 = *(const float4*)(cw + (size_t)(d+3)*4);
  const float wk[4][4] = {{w0.x,w1.x,w2.x,w3.x},{w0.y,w1.y,w2.y,w3.y},
                          {w0.z,w1.z,w2.z,w3.z},{w0.w,w1.w,w2.w,w3.w}};
  float4 acc = *(const float4*)(cb + d);
  #pragma unroll
  for (int k=0;k<4;k++){
    const int tt = t - 3 + k;
    if (tt < 0) continue;
    const float4 xv = *(const float4*)(xz + ((size_t)b*LSEQ + tt)*XZL + d);
    acc.x = fmaf(wk[k][0], xv.x, acc.x);
    acc.y = fmaf(wk[k][1], xv.y, acc.y);
    acc.z = fmaf(wk[k][2], xv.z, acc.z);
    acc.w = fmaf(wk[k][3], xv.w, acc.w);
  }
  acc.x = siluf(acc.x); acc.y = siluf(acc.y); acc.z = siluf(acc.z); acc.w = siluf(acc.w);
  ushort4 h, l;
  h.x = f2bf(acc.x); l.x = f2bf(acc.x - bf2f(h.x));
  h.y = f2bf(acc.y); l.y = f2bf(acc.y - bf2f(h.y));
  h.z = f2bf(acc.z); l.z = f2bf(acc.z - bf2f(h.z));
  h.w = f2bf(acc.w); l.w = f2bf(acc.w - bf2f(h.w));
  *(ushort4*)(xsh + (size_t)r*DI + d) = h;
  *(ushort4*)(xsl + (size_t)r*DI + d) = l;
}

// ---------------- xp = x_ssm @ Wx^T as bf16x3 MFMA skinny GEMM (N=48 pad, write n<33) ----
// 64 blocks x 256 thr; wave w handles rows blk*64 + w*16. Fragments read from global.
__global__ __launch_bounds__(256)
void xp_gemm_kernel(const unsigned short* __restrict__ xsh, const unsigned short* __restrict__ xsl,
                    const unsigned short* __restrict__ wxh, const unsigned short* __restrict__ wxl,
                    float* __restrict__ xp) {
  const int wave = threadIdx.x >> 6, lane = threadIdx.x & 63;
  const int fr = lane & 15, kg = lane >> 4;
  const int m0 = (blockIdx.x << 6) + (wave << 4);
  const unsigned short* pah = xsh + (size_t)(m0 + fr)*DI + (kg<<3);
  const unsigned short* pal = xsl + (size_t)(m0 + fr)*DI + (kg<<3);
  const unsigned short* pbh = wxh + (size_t)fr*DI + (kg<<3);
  const unsigned short* pbl = wxl + (size_t)fr*DI + (kg<<3);
  f32x4 acc[3];
  #pragma unroll
  for (int nf=0;nf<3;nf++)
    #pragma unroll
    for (int r=0;r<4;r++) acc[nf][r] = 0.f;
  for (int kk = 0; kk < DI; kk += 32) {
    const bfrag ah = *(const bfrag*)(pah + kk);
    const bfrag al = *(const bfrag*)(pal + kk);
    #pragma unroll
    for (int nf=0;nf<3;nf++){
      const bfrag bh = *(const bfrag*)(pbh + (size_t)nf*16*DI + kk);
      const bfrag bl = *(const bfrag*)(pbl + (size_t)nf*16*DI + kk);
      acc[nf] = __builtin_amdgcn_mfma_f32_16x16x32_bf16(ah, bh, acc[nf], 0, 0, 0);
      acc[nf] = __builtin_amdgcn_mfma_f32_16x16x32_bf16(al, bh, acc[nf], 0, 0, 0);
      acc[nf] = __builtin_amdgcn_mfma_f32_16x16x32_bf16(ah, bl, acc[nf], 0, 0, 0);
    }
  }
  #pragma unroll
  for (int nf=0;nf<3;nf++){
    const int n = (nf<<4) + fr;
    if (n < 33){
      #pragma unroll
      for (int r=0;r<4;r++){
        const int row = m0 + (kg<<2) + r;
        xp[(size_t)row*33 + n] = acc[nf][r];
      }
    }
  }
}

// ---------------- dt = softplus(xp @ W_dt^T + b_dt) + 1e-3 ----------------
__global__ __launch_bounds__(256)
void dt_kernel(const float* __restrict__ xp, const float* __restrict__ Wdt,
               const float* __restrict__ bdt, float* __restrict__ dt) {
  __shared__ float wl[256][34];
  const int tid = threadIdx.x;
  const int d0 = (blockIdx.x & 7) << 8;
  const int r0 = (blockIdx.x >> 3) << 6;
  for (int i = tid; i < 256*33; i += 256) wl[i/33][i%33] = Wdt[(size_t)d0*33 + i];
  const float bv = bdt[d0 + tid];
  __syncthreads();
  for (int rr=0; rr<64; ++rr){
    const int r = r0 + rr;
    const float* xpr = xp + (size_t)r*33;
    float s = bv;
    #pragma unroll
    for (int j=0;j<33;j++) s = fmaf(xpr[j], wl[tid][j], s);
    const float sp = (s > 20.f) ? s : log1pf(__expf(s));
    dt[(size_t)r*DI + d0 + tid] = sp + 0.001f;
  }
}

// ---------------- scan pass 1: local chunk scan -> y_loc (into xz x-half), P, H ----
__global__ __launch_bounds__(256)
void scan1_kernel(const unsigned short* __restrict__ xsh, const unsigned short* __restrict__ xsl,
                  const float* __restrict__ dt,
                  const float* __restrict__ xp, const float* __restrict__ Alog,
                  const float* __restrict__ Dp,
                  float* __restrict__ y, float* __restrict__ Pbuf, float* __restrict__ Hbuf) {
  const int g  = blockIdx.x*256 + threadIdx.x;
  const int nq = g & 3;
  const int g2 = g >> 2;
  const int d  = g2 & (DI-1);
  const int bc = g2 >> 11;
  const int c  = bc & (NC-1);
  const int b  = bc >> 6;
  const float4 al = *(const float4*)(Alog + (size_t)d*NS + (nq<<2));
  const float Aa[4] = {-__expf(al.x), -__expf(al.y), -__expf(al.z), -__expf(al.w)};
  float rA[4];
  #pragma unroll
  for (int i=0;i<4;i++) rA[i] = 1.f/(Aa[i] + 1e-8f);
  const float Dv = Dp[d];
  float h[4] = {0,0,0,0};
  float P[4] = {1,1,1,1};
  const int t0 = c * TC;
  for (int t = t0; t < t0 + TC; ++t){
    const size_t r = (size_t)b*LSEQ + t;
    const float dtv = dt[r*DI + d];
    const float xv  = bf2f(xsh[r*DI + d]) + bf2f(xsl[r*DI + d]);
    const float* xpr = xp + r*33;
    float e[4];
    #pragma unroll
    for (int i=0;i<4;i++){ e[i] = __expf(Aa[i]*dtv); P[i] *= e[i]; }
    float yp = 0.f;
    #pragma unroll
    for (int i=0;i<4;i++){
      const int n = (nq<<2) + i;
      const float Bv = xpr[1 + n];
      const float Cv = xpr[17 + n];
      const float gbx = rA[i] * (1.f - e[i]) * Bv * xv;
      h[i] = fmaf(e[i], h[i], gbx);
      h[i] = fminf(10.f, fmaxf(-10.f, h[i]));
      yp = fmaf(Cv, h[i], yp);
    }
    yp += __shfl_xor(yp, 1);
    yp += __shfl_xor(yp, 2);
    if (nq == 0) y[r*XZL + d] = yp + Dv*xv;
  }
  const size_t pb = (((size_t)c*B_SZ + b)*DI + d)*NS + (nq<<2);
  *(float4*)(Pbuf+pb) = make_float4(P[0],P[1],P[2],P[3]);
  *(float4*)(Hbuf+pb) = make_float4(h[0],h[1],h[2],h[3]);
}

// ---------------- scan pass 2: sequential chunk combine; hin folded into Hbuf ----
__global__ __launch_bounds__(256)
void scan2_kernel(const float* __restrict__ Pbuf, float* __restrict__ Hbuf) {
  const int g = blockIdx.x*256 + threadIdx.x;  // over B*DI*NS
  const size_t cs = (size_t)B_SZ*DI*NS;
  float h = 0.f;
  for (int c=1;c<NC;++c){
    const float Pv = Pbuf[(size_t)(c-1)*cs + g];
    const float Hv = Hbuf[(size_t)(c-1)*cs + g];
    h = fmaf(Pv, h, Hv);
    Hbuf[(size_t)(c-1)*cs + g] = h;
  }
}

// ---------------- scan pass 3: cross-chunk correction + silu(z) + bf16 split ----
__global__ __launch_bounds__(256)
void scan3_kernel(const float* __restrict__ dt, const float* __restrict__ xp,
                  const float* __restrict__ Alog, const float* __restrict__ hinb,
                  const float* __restrict__ xz,
                  unsigned short* __restrict__ yh, unsigned short* __restrict__ yl) {
  const int g  = blockIdx.x*256 + threadIdx.x;
  const int nq = g & 3;
  const int g2 = g >> 2;
  const int d  = g2 & (DI-1);
  const int bc = g2 >> 11;
  const int c  = bc & (NC-1);
  const int b  = bc >> 6;
  const float4 al = *(const float4*)(Alog + (size_t)d*NS + (nq<<2));
  const float Aa[4] = {-__expf(al.x), -__expf(al.y), -__expf(al.z), -__expf(al.w)};
  float hi[4] = {0.f, 0.f, 0.f, 0.f};
  if (c > 0){
    const size_t pb = (((size_t)(c-1)*B_SZ + b)*DI + d)*NS + (nq<<2);
    const float4 hv = *(const float4*)(hinb + pb);
    hi[0]=hv.x; hi[1]=hv.y; hi[2]=hv.z; hi[3]=hv.w;
  }
  float q[4] = {1,1,1,1};
  const int t0 = c * TC;
  for (int t = t0; t < t0 + TC; ++t){
    const size_t r = (size_t)b*LSEQ + t;
    const float dtv = dt[r*DI + d];
    const float* xpr = xp + r*33;
    float cp = 0.f;
    #pragma unroll
    for (int i=0;i<4;i++){
      q[i] *= __expf(Aa[i]*dtv);
      const float Cv = xpr[17 + (nq<<2) + i];
      cp = fmaf(Cv*q[i], hi[i], cp);
    }
    cp += __shfl_xor(cp, 1);
    cp += __shfl_xor(cp, 2);
    if (nq == 0){
      const float zv = xz[r*XZL + 2048 + d];
      const float yv = (xz[r*XZL + d] + cp) * siluf(zv);
      const unsigned short h16 = f2bf(yv);
      yh[r*DI + d] = h16;
      yl[r*DI + d] = f2bf(yv - bf2f(h16));
    }
  }
}

extern "C" void kernel_launch(void* const* d_in, const int* in_sizes, int n_in,
                              void* d_out, int out_size, void* d_ws, size_t ws_size,
                              hipStream_t stream) {
  const float* x     = (const float*)d_in[0];
  const float* gamma = (const float*)d_in[1];
  const float* beta  = (const float*)d_in[2];
  const float* W_in  = (const float*)d_in[3];
  const float* cw    = (const float*)d_in[4];
  const float* cb    = (const float*)d_in[5];
  const float* Alog  = (const float*)d_in[6];
  const float* Dp    = (const float*)d_in[7];
  const float* Wx    = (const float*)d_in[8];
  const float* Wdt   = (const float*)d_in[9];
  const float* bdt   = (const float*)d_in[10];
  const float* Wout  = (const float*)d_in[11];
  float* out = (float*)d_out;
  float* ws  = (float*)d_ws;

  const size_t M1 = 1048576;
  float* xz   = ws;                 // 16M f32
  float* xsq  = ws + 16*M1;         // 8M f32 slot: xs_h/xs_l (conv out), later y_h/y_l
  float* dtb  = ws + 24*M1;         // 8M
  float* Pb   = ws + 32*M1;         // 4M (NC*B*DI*NS)
  float* Hb   = Pb + 4*M1;          // 4M (hin folded in by scan2)
  float* xpb  = Hb + 4*M1;          // 135168
  float* wxzone = xpb + 135168;     // Wx splits: 2 * 48*2048 us = 98304 f32
  unsigned short* wx_h = (unsigned short*)wxzone;          // 48*2048 us
  unsigned short* wx_l = wx_h + (size_t)NPAD*DI;           // 48*2048 us
  unsigned short* zone = wx_l + (size_t)NPAD*DI;           // 16M ushort
  unsigned short* xn_h = zone;             // 4M us  (dead after gemm1)
  unsigned short* xn_l = zone + 4*M1;      // 4M us
  unsigned short* Wi_h = zone + 8*M1;      // 4M us
  unsigned short* Wi_l = zone + 12*M1;     // 4M us
  unsigned short* Wo_h = zone;             // 2M us (split AFTER gemm1, overlays xn_h)
  unsigned short* Wo_l = zone + 2*M1;      // 2M us
  unsigned short* xs_h = (unsigned short*)xsq;           // 8M us
  unsigned short* xs_l = (unsigned short*)xsq + 8*M1;    // 8M us
  unsigned short* y_h  = (unsigned short*)xsq;           // overlay (xs dead after scan1)
  unsigned short* y_l  = (unsigned short*)xsq + 8*M1;
  // total ~48.23M f32 = 193 MB

  ln_split_kernel<<<RTOT, 256, 0, stream>>>(x, gamma, beta, xn_h, xn_l);
  split_kernel<<<(2*DI*DM/4 + 255)/256, 256, 0, stream>>>(W_in, Wi_h, Wi_l, 2*DI*DM/4);
  split_pad_wx_kernel<<<(NPAD*DI/4 + 255)/256, 256, 0, stream>>>(Wx, wx_h, wx_l);
  gemm_bf16x3<<<dim3(XZL/128, RTOT/128), 256, 0, stream>>>(xn_h, xn_l, Wi_h, Wi_l,
                                                           xz, RTOT, XZL, DM, XZL);
  split_kernel<<<(DM*DI/4 + 255)/256, 256, 0, stream>>>(Wout, Wo_h, Wo_l, DM*DI/4);
  conv_silu_split_kernel<<<(RTOT*(DI/4))/256, 256, 0, stream>>>(xz, cw, cb, xs_h, xs_l);
  xp_gemm_kernel<<<RTOT/64, 256, 0, stream>>>(xs_h, xs_l, wx_h, wx_l, xpb);
  dt_kernel<<<(DI/256)*(RTOT/64), 256, 0, stream>>>(xpb, Wdt, bdt, dtb);
  scan1_kernel<<<(B_SZ*NC*DI*4)/256, 256, 0, stream>>>(xs_h, xs_l, dtb, xpb, Alog, Dp, xz, Pb, Hb);
  scan2_kernel<<<(B_SZ*DI*NS)/256, 256, 0, stream>>>(Pb, Hb);
  scan3_kernel<<<(B_SZ*NC*DI*4)/256, 256, 0, stream>>>(dtb, xpb, Alog, Hb, xz, y_h, y_l);
  gemm_bf16x3_b64<<<dim3(DM/128, RTOT/64), 256, 0, stream>>>(y_h, y_l, Wo_h, Wo_l,
                                                             out, RTOT, DM, DI, DM);
}

// Round 6
// 449.273 us; speedup vs baseline: 1.0216x; 1.0216x over previous
//
#include <hip/hip_runtime.h>
#include <math.h>

// MambaSSMBlock: B=2, L=2048, Dm=1024, Di=2048, N=16, convK=4
// Round 6: (1) xp -> 256-block K-split MFMA w/ LDS reduce + fused dt epilogue;
//          (2) out-GEMM split-K=2 via blockIdx.z (1024 blocks = 4/CU) + add pass.
// Workspace: ~193 MB.

#define B_SZ 2
#define LSEQ 2048
#define DM   1024
#define DI   2048
#define NS   16
#define RTOT (B_SZ*LSEQ)
#define NC   64
#define TC   (LSEQ/NC)
#define XZL  4096
#define NPAD 48

typedef __attribute__((ext_vector_type(8))) short bfrag;
typedef __attribute__((ext_vector_type(4))) float f32x4;

__device__ __forceinline__ float siluf(float v){ return v / (1.f + __expf(-v)); }

__device__ __forceinline__ unsigned short f2bf(float f){
  unsigned int u = __float_as_uint(f);
  u += 0x7FFFu + ((u >> 16) & 1u);
  return (unsigned short)(u >> 16);
}
__device__ __forceinline__ float bf2f(unsigned short h){
  return __uint_as_float(((unsigned int)h) << 16);
}

// ---------------- LayerNorm fused with bf16 hi/lo split ----------------
__global__ __launch_bounds__(256)
void ln_split_kernel(const float* __restrict__ x, const float* __restrict__ g,
                     const float* __restrict__ b,
                     unsigned short* __restrict__ xh, unsigned short* __restrict__ xl) {
  __shared__ float red[8];
  const int r = blockIdx.x, tid = threadIdx.x;
  const float4 v = ((const float4*)(x + (size_t)r*DM))[tid];
  float s  = v.x+v.y+v.z+v.w;
  float ss = v.x*v.x+v.y*v.y+v.z*v.z+v.w*v.w;
  #pragma unroll
  for (int off=32; off; off>>=1){ s += __shfl_xor(s,off); ss += __shfl_xor(ss,off); }
  if ((tid & 63)==0){ int w=tid>>6; red[w]=s; red[4+w]=ss; }
  __syncthreads();
  s  = red[0]+red[1]+red[2]+red[3];
  ss = red[4]+red[5]+red[6]+red[7];
  const float mu  = s*(1.f/DM);
  const float inv = rsqrtf(ss*(1.f/DM) - mu*mu + 1e-5f);
  const float4 gv = ((const float4*)g)[tid];
  const float4 bv = ((const float4*)b)[tid];
  float o[4];
  o[0] = (v.x-mu)*inv*gv.x + bv.x;
  o[1] = (v.y-mu)*inv*gv.y + bv.y;
  o[2] = (v.z-mu)*inv*gv.z + bv.z;
  o[3] = (v.w-mu)*inv*gv.w + bv.w;
  ushort4 h, l;
  h.x = f2bf(o[0]); l.x = f2bf(o[0] - bf2f(h.x));
  h.y = f2bf(o[1]); l.y = f2bf(o[1] - bf2f(h.y));
  h.z = f2bf(o[2]); l.z = f2bf(o[2] - bf2f(h.z));
  h.w = f2bf(o[3]); l.w = f2bf(o[3] - bf2f(h.w));
  ((ushort4*)(xh + (size_t)r*DM))[tid] = h;
  ((ushort4*)(xl + (size_t)r*DM))[tid] = l;
}

// ---------------- generic fp32 -> bf16 hi/lo split ----------------
__global__ __launch_bounds__(256)
void split_kernel(const float* __restrict__ in, unsigned short* __restrict__ hi,
                  unsigned short* __restrict__ lo, int n4) {
  const int i = blockIdx.x*256 + threadIdx.x;
  if (i >= n4) return;
  const float4 v = ((const float4*)in)[i];
  ushort4 h, l;
  h.x = f2bf(v.x); l.x = f2bf(v.x - bf2f(h.x));
  h.y = f2bf(v.y); l.y = f2bf(v.y - bf2f(h.y));
  h.z = f2bf(v.z); l.z = f2bf(v.z - bf2f(h.z));
  h.w = f2bf(v.w); l.w = f2bf(v.w - bf2f(h.w));
  ((ushort4*)hi)[i] = h;
  ((ushort4*)lo)[i] = l;
}

// ---------------- Wx split with zero pad to 48 rows ----------------
__global__ __launch_bounds__(256)
void split_pad_wx_kernel(const float* __restrict__ in, unsigned short* __restrict__ hi,
                         unsigned short* __restrict__ lo) {
  const int i = blockIdx.x*256 + threadIdx.x;
  if (i >= NPAD*DI/4) return;
  const int row = i >> 9;
  float4 v = make_float4(0.f,0.f,0.f,0.f);
  if (row < 33) v = ((const float4*)in)[i];
  ushort4 h, l;
  h.x = f2bf(v.x); l.x = f2bf(v.x - bf2f(h.x));
  h.y = f2bf(v.y); l.y = f2bf(v.y - bf2f(h.y));
  h.z = f2bf(v.z); l.z = f2bf(v.z - bf2f(h.z));
  h.w = f2bf(v.w); l.w = f2bf(v.w - bf2f(h.w));
  ((ushort4*)hi)[i] = h;
  ((ushort4*)lo)[i] = l;
}

// ---------------- bf16x3 MFMA GEMM 128x128: C = A * B^T ----------------
__global__ __launch_bounds__(256)
void gemm_bf16x3(const unsigned short* __restrict__ Ah, const unsigned short* __restrict__ Al,
                 const unsigned short* __restrict__ Bh, const unsigned short* __restrict__ Bl,
                 float* __restrict__ C, int M, int N, int K, int ldc)
{
  __shared__ __align__(16) unsigned short lds[4][128][40];
  const int tid = threadIdx.x;
  const int bm = blockIdx.y << 7;
  const int bn = blockIdx.x << 7;
  const int wave = tid >> 6;
  const int lane = tid & 63;
  const int wm = (wave >> 1) << 6;
  const int wn = (wave & 1) << 6;
  const int fr = lane & 15;
  const int kg = lane >> 4;
  const int srow = tid >> 1;
  const int scol = (tid & 1) << 4;

  const unsigned short* pAh = Ah + (size_t)(bm + srow)*K + scol;
  const unsigned short* pAl = Al + (size_t)(bm + srow)*K + scol;
  const unsigned short* pBh = Bh + (size_t)(bn + srow)*K + scol;
  const unsigned short* pBl = Bl + (size_t)(bn + srow)*K + scol;

  f32x4 acc[4][4];
  #pragma unroll
  for (int m=0;m<4;m++)
    #pragma unroll
    for (int n=0;n<4;n++)
      #pragma unroll
      for (int r=0;r<4;r++) acc[m][n][r] = 0.f;

  uint4 ra0, ra1, rb0, rb1, rc0, rc1, rd0, rd1;
#define LOAD8(k0) do { \
    ra0 = *(const uint4*)(pAh + (k0));     ra1 = *(const uint4*)(pAh + (k0) + 8); \
    rb0 = *(const uint4*)(pAl + (k0));     rb1 = *(const uint4*)(pAl + (k0) + 8); \
    rc0 = *(const uint4*)(pBh + (k0));     rc1 = *(const uint4*)(pBh + (k0) + 8); \
    rd0 = *(const uint4*)(pBl + (k0));     rd1 = *(const uint4*)(pBl + (k0) + 8); \
  } while(0)

  const int nIter = K >> 5;
  LOAD8(0);
  for (int it = 0; it < nIter; ++it) {
    __syncthreads();
    *(uint4*)&lds[0][srow][scol] = ra0;  *(uint4*)&lds[0][srow][scol+8] = ra1;
    *(uint4*)&lds[1][srow][scol] = rb0;  *(uint4*)&lds[1][srow][scol+8] = rb1;
    *(uint4*)&lds[2][srow][scol] = rc0;  *(uint4*)&lds[2][srow][scol+8] = rc1;
    *(uint4*)&lds[3][srow][scol] = rd0;  *(uint4*)&lds[3][srow][scol+8] = rd1;
    __syncthreads();
    if (it + 1 < nIter) LOAD8((size_t)(it+1) << 5);

    bfrag ah[4], al[4], bb[4];
    #pragma unroll
    for (int m=0;m<4;m++){
      ah[m] = *(const bfrag*)&lds[0][wm + (m<<4) + fr][kg<<3];
      al[m] = *(const bfrag*)&lds[1][wm + (m<<4) + fr][kg<<3];
    }
    #pragma unroll
    for (int n=0;n<4;n++) bb[n] = *(const bfrag*)&lds[2][wn + (n<<4) + fr][kg<<3];
    #pragma unroll
    for (int m=0;m<4;m++)
      #pragma unroll
      for (int n=0;n<4;n++){
        acc[m][n] = __builtin_amdgcn_mfma_f32_16x16x32_bf16(ah[m], bb[n], acc[m][n], 0, 0, 0);
        acc[m][n] = __builtin_amdgcn_mfma_f32_16x16x32_bf16(al[m], bb[n], acc[m][n], 0, 0, 0);
      }
    #pragma unroll
    for (int n=0;n<4;n++) bb[n] = *(const bfrag*)&lds[3][wn + (n<<4) + fr][kg<<3];
    #pragma unroll
    for (int m=0;m<4;m++)
      #pragma unroll
      for (int n=0;n<4;n++)
        acc[m][n] = __builtin_amdgcn_mfma_f32_16x16x32_bf16(ah[m], bb[n], acc[m][n], 0, 0, 0);
  }
#undef LOAD8

  #pragma unroll
  for (int m=0;m<4;m++)
    #pragma unroll
    for (int n=0;n<4;n++){
      float* Cp = C + (size_t)(bm + wm + (m<<4) + (kg<<2))*ldc + bn + wn + (n<<4) + fr;
      #pragma unroll
      for (int r=0;r<4;r++) Cp[(size_t)r*ldc] = acc[m][n][r];
    }
}

// ---------------- bf16x3 MFMA GEMM 64x128 tile, split-K via blockIdx.z ----------------
__global__ __launch_bounds__(256)
void gemm_bf16x3_b64sk(const unsigned short* __restrict__ Ah, const unsigned short* __restrict__ Al,
                       const unsigned short* __restrict__ Bh, const unsigned short* __restrict__ Bl,
                       float* __restrict__ C0, float* __restrict__ C1,
                       int lda, int kLen, int ldc)
{
  __shared__ __align__(16) unsigned short ldsA[2][64][40];
  __shared__ __align__(16) unsigned short ldsB[2][128][40];
  const int tid = threadIdx.x;
  const int bm = blockIdx.y << 6;
  const int bn = blockIdx.x << 7;
  const int koff = blockIdx.z * kLen;
  const int wave = tid >> 6;
  const int lane = tid & 63;
  const int wm = (wave >> 1) << 5;
  const int wn = (wave & 1) << 6;
  const int fr = lane & 15;
  const int kg = lane >> 4;
  const int arow = tid >> 2, acol = (tid & 3) << 3;
  const int brow = tid >> 1, bcol = (tid & 1) << 4;

  const unsigned short* pAh = Ah + (size_t)(bm + arow)*lda + acol + koff;
  const unsigned short* pAl = Al + (size_t)(bm + arow)*lda + acol + koff;
  const unsigned short* pBh = Bh + (size_t)(bn + brow)*lda + bcol + koff;
  const unsigned short* pBl = Bl + (size_t)(bn + brow)*lda + bcol + koff;
  float* Cz = blockIdx.z ? C1 : C0;

  f32x4 acc[2][4];
  #pragma unroll
  for (int m=0;m<2;m++)
    #pragma unroll
    for (int n=0;n<4;n++)
      #pragma unroll
      for (int r=0;r<4;r++) acc[m][n][r] = 0.f;

  uint4 ra, rb, rc0, rc1, rd0, rd1;
#define LOAD6(k0) do { \
    ra  = *(const uint4*)(pAh + (k0)); \
    rb  = *(const uint4*)(pAl + (k0)); \
    rc0 = *(const uint4*)(pBh + (k0));  rc1 = *(const uint4*)(pBh + (k0) + 8); \
    rd0 = *(const uint4*)(pBl + (k0));  rd1 = *(const uint4*)(pBl + (k0) + 8); \
  } while(0)

  const int nIter = kLen >> 5;
  LOAD6(0);
  for (int it = 0; it < nIter; ++it) {
    __syncthreads();
    *(uint4*)&ldsA[0][arow][acol] = ra;
    *(uint4*)&ldsA[1][arow][acol] = rb;
    *(uint4*)&ldsB[0][brow][bcol] = rc0;  *(uint4*)&ldsB[0][brow][bcol+8] = rc1;
    *(uint4*)&ldsB[1][brow][bcol] = rd0;  *(uint4*)&ldsB[1][brow][bcol+8] = rd1;
    __syncthreads();
    if (it + 1 < nIter) LOAD6((size_t)(it+1) << 5);

    bfrag ah[2], al[2], bh[4], bl[4];
    #pragma unroll
    for (int m=0;m<2;m++){
      ah[m] = *(const bfrag*)&ldsA[0][wm + (m<<4) + fr][kg<<3];
      al[m] = *(const bfrag*)&ldsA[1][wm + (m<<4) + fr][kg<<3];
    }
    #pragma unroll
    for (int n=0;n<4;n++){
      bh[n] = *(const bfrag*)&ldsB[0][wn + (n<<4) + fr][kg<<3];
      bl[n] = *(const bfrag*)&ldsB[1][wn + (n<<4) + fr][kg<<3];
    }
    #pragma unroll
    for (int m=0;m<2;m++)
      #pragma unroll
      for (int n=0;n<4;n++){
        acc[m][n] = __builtin_amdgcn_mfma_f32_16x16x32_bf16(ah[m], bh[n], acc[m][n], 0, 0, 0);
        acc[m][n] = __builtin_amdgcn_mfma_f32_16x16x32_bf16(al[m], bh[n], acc[m][n], 0, 0, 0);
        acc[m][n] = __builtin_amdgcn_mfma_f32_16x16x32_bf16(ah[m], bl[n], acc[m][n], 0, 0, 0);
      }
  }
#undef LOAD6

  #pragma unroll
  for (int m=0;m<2;m++)
    #pragma unroll
    for (int n=0;n<4;n++){
      float* Cp = Cz + (size_t)(bm + wm + (m<<4) + (kg<<2))*ldc + bn + wn + (n<<4) + fr;
      #pragma unroll
      for (int r=0;r<4;r++) Cp[(size_t)r*ldc] = acc[m][n][r];
    }
}

// ---------------- add partial ----------------
__global__ __launch_bounds__(256)
void add_kernel(float* __restrict__ out, const float* __restrict__ part, int n4) {
  const int i = blockIdx.x*256 + threadIdx.x;
  if (i >= n4) return;
  const float4 a = ((const float4*)out)[i];
  const float4 b = ((const float4*)part)[i];
  ((float4*)out)[i] = make_float4(a.x+b.x, a.y+b.y, a.z+b.z, a.w+b.w);
}

// ---------------- depthwise causal conv K=4 + bias + SiLU -> bf16 hi/lo ----------------
__global__ __launch_bounds__(256)
void conv_silu_split_kernel(const float* __restrict__ xz, const float* __restrict__ cw,
                            const float* __restrict__ cb,
                            unsigned short* __restrict__ xsh, unsigned short* __restrict__ xsl) {
  const int idx = blockIdx.x * 256 + threadIdx.x;
  const int d4 = idx & (DI/4 - 1);
  const int r  = idx >> 9;
  const int b  = r >> 11;
  const int t  = r & (LSEQ-1);
  const int d  = d4 << 2;
  const float4 w0 = *(const float4*)(cw + (size_t)(d+0)*4);
  const float4 w1 = *(const float4*)(cw + (size_t)(d+1)*4);
  const float4 w2 = *(const float4*)(cw + (size_t)(d+2)*4);
  const float4 w3 = *(const float4*)(cw + (size_t)(d+3)*4);
  const float wk[4][4] = {{w0.x,w1.x,w2.x,w3.x},{w0.y,w1.y,w2.y,w3.y},
                          {w0.z,w1.z,w2.z,w3.z},{w0.w,w1.w,w2.w,w3.w}};
  float4 acc = *(const float4*)(cb + d);
  #pragma unroll
  for (int k=0;k<4;k++){
    const int tt = t - 3 + k;
    if (tt < 0) continue;
    const float4 xv = *(const float4*)(xz + ((size_t)b*LSEQ + tt)*XZL + d);
    acc.x = fmaf(wk[k][0], xv.x, acc.x);
    acc.y = fmaf(wk[k][1], xv.y, acc.y);
    acc.z = fmaf(wk[k][2], xv.z, acc.z);
    acc.w = fmaf(wk[k][3], xv.w, acc.w);
  }
  acc.x = siluf(acc.x); acc.y = siluf(acc.y); acc.z = siluf(acc.z); acc.w = siluf(acc.w);
  ushort4 h, l;
  h.x = f2bf(acc.x); l.x = f2bf(acc.x - bf2f(h.x));
  h.y = f2bf(acc.y); l.y = f2bf(acc.y - bf2f(h.y));
  h.z = f2bf(acc.z); l.z = f2bf(acc.z - bf2f(h.z));
  h.w = f2bf(acc.w); l.w = f2bf(acc.w - bf2f(h.w));
  *(ushort4*)(xsh + (size_t)r*DI + d) = h;
  *(ushort4*)(xsl + (size_t)r*DI + d) = l;
}

// ---------------- xp (K-split MFMA, LDS-reduce) + fused dt ----------------
__global__ __launch_bounds__(256)
void xp_dt_kernel(const unsigned short* __restrict__ xsh, const unsigned short* __restrict__ xsl,
                  const unsigned short* __restrict__ wxh, const unsigned short* __restrict__ wxl,
                  const float* __restrict__ Wdt, const float* __restrict__ bdt,
                  float* __restrict__ xp, float* __restrict__ dtb) {
  __shared__ float red[4][64][12];
  __shared__ float xp_lds[16][34];
  __shared__ float wl[256*33 + 8];
  const int tid = threadIdx.x;
  const int wave = tid >> 6, lane = tid & 63;
  const int fr = lane & 15, kg = lane >> 4;
  const int m0 = blockIdx.x << 4;
  const size_t koff = (size_t)wave << 9;

  const unsigned short* pah = xsh + (size_t)(m0 + fr)*DI + (kg<<3) + koff;
  const unsigned short* pal = xsl + (size_t)(m0 + fr)*DI + (kg<<3) + koff;
  const unsigned short* pbh = wxh + (size_t)fr*DI + (kg<<3) + koff;
  const unsigned short* pbl = wxl + (size_t)fr*DI + (kg<<3) + koff;

  f32x4 acc[3];
  #pragma unroll
  for (int nf=0;nf<3;nf++)
    #pragma unroll
    for (int r=0;r<4;r++) acc[nf][r] = 0.f;

  for (int kk = 0; kk < 512; kk += 32) {
    const bfrag ah = *(const bfrag*)(pah + kk);
    const bfrag al_ = *(const bfrag*)(pal + kk);
    #pragma unroll
    for (int nf=0;nf<3;nf++){
      const bfrag bh = *(const bfrag*)(pbh + (size_t)nf*16*DI + kk);
      const bfrag bl = *(const bfrag*)(pbl + (size_t)nf*16*DI + kk);
      acc[nf] = __builtin_amdgcn_mfma_f32_16x16x32_bf16(ah, bh, acc[nf], 0, 0, 0);
      acc[nf] = __builtin_amdgcn_mfma_f32_16x16x32_bf16(al_, bh, acc[nf], 0, 0, 0);
      acc[nf] = __builtin_amdgcn_mfma_f32_16x16x32_bf16(ah, bl, acc[nf], 0, 0, 0);
    }
  }
  #pragma unroll
  for (int nf=0;nf<3;nf++)
    #pragma unroll
    for (int r=0;r<4;r++) red[wave][lane][nf*4+r] = acc[nf][r];
  __syncthreads();
  if (wave == 0){
    #pragma unroll
    for (int nf=0;nf<3;nf++){
      const int col = (nf<<4) + fr;
      #pragma unroll
      for (int r=0;r<4;r++){
        const float v = red[0][lane][nf*4+r] + red[1][lane][nf*4+r]
                      + red[2][lane][nf*4+r] + red[3][lane][nf*4+r];
        if (col < 33){
          const int row = (kg<<2) + r;
          xp_lds[row][col] = v;
          xp[(size_t)(m0 + row)*33 + col] = v;
        }
      }
    }
  }
  __syncthreads();
  for (int j=0;j<8;j++){
    const int d0 = j << 8;
    for (int i = tid; i < 256*33; i += 256) wl[i] = Wdt[(size_t)d0*33 + i];
    __syncthreads();
    const float bv = bdt[d0 + tid];
    const float* wrow = &wl[tid*33];
    #pragma unroll
    for (int row=0; row<16; ++row){
      float s = bv;
      #pragma unroll
      for (int k=0;k<33;k++) s = fmaf(xp_lds[row][k], wrow[k], s);
      const float sp = (s > 20.f) ? s : log1pf(__expf(s));
      dtb[(size_t)(m0 + row)*DI + d0 + tid] = sp + 0.001f;
    }
    __syncthreads();
  }
}

// ---------------- scan pass 1 ----------------
__global__ __launch_bounds__(256)
void scan1_kernel(const unsigned short* __restrict__ xsh, const unsigned short* __restrict__ xsl,
                  const float* __restrict__ dt,
                  const float* __restrict__ xp, const float* __restrict__ Alog,
                  const float* __restrict__ Dp,
                  float* __restrict__ y, float* __restrict__ Pbuf, float* __restrict__ Hbuf) {
  const int g  = blockIdx.x*256 + threadIdx.x;
  const int nq = g & 3;
  const int g2 = g >> 2;
  const int d  = g2 & (DI-1);
  const int bc = g2 >> 11;
  const int c  = bc & (NC-1);
  const int b  = bc >> 6;
  const float4 al = *(const float4*)(Alog + (size_t)d*NS + (nq<<2));
  const float Aa[4] = {-__expf(al.x), -__expf(al.y), -__expf(al.z), -__expf(al.w)};
  float rA[4];
  #pragma unroll
  for (int i=0;i<4;i++) rA[i] = 1.f/(Aa[i] + 1e-8f);
  const float Dv = Dp[d];
  float h[4] = {0,0,0,0};
  float P[4] = {1,1,1,1};
  const int t0 = c * TC;
  for (int t = t0; t < t0 + TC; ++t){
    const size_t r = (size_t)b*LSEQ + t;
    const float dtv = dt[r*DI + d];
    const float xv  = bf2f(xsh[r*DI + d]) + bf2f(xsl[r*DI + d]);
    const float* xpr = xp + r*33;
    float e[4];
    #pragma unroll
    for (int i=0;i<4;i++){ e[i] = __expf(Aa[i]*dtv); P[i] *= e[i]; }
    float yp = 0.f;
    #pragma unroll
    for (int i=0;i<4;i++){
      const int n = (nq<<2) + i;
      const float Bv = xpr[1 + n];
      const float Cv = xpr[17 + n];
      const float gbx = rA[i] * (1.f - e[i]) * Bv * xv;
      h[i] = fmaf(e[i], h[i], gbx);
      h[i] = fminf(10.f, fmaxf(-10.f, h[i]));
      yp = fmaf(Cv, h[i], yp);
    }
    yp += __shfl_xor(yp, 1);
    yp += __shfl_xor(yp, 2);
    if (nq == 0) y[r*XZL + d] = yp + Dv*xv;
  }
  const size_t pb = (((size_t)c*B_SZ + b)*DI + d)*NS + (nq<<2);
  *(float4*)(Pbuf+pb) = make_float4(P[0],P[1],P[2],P[3]);
  *(float4*)(Hbuf+pb) = make_float4(h[0],h[1],h[2],h[3]);
}

// ---------------- scan pass 2 ----------------
__global__ __launch_bounds__(256)
void scan2_kernel(const float* __restrict__ Pbuf, float* __restrict__ Hbuf) {
  const int g = blockIdx.x*256 + threadIdx.x;
  const size_t cs = (size_t)B_SZ*DI*NS;
  float h = 0.f;
  for (int c=1;c<NC;++c){
    const float Pv = Pbuf[(size_t)(c-1)*cs + g];
    const float Hv = Hbuf[(size_t)(c-1)*cs + g];
    h = fmaf(Pv, h, Hv);
    Hbuf[(size_t)(c-1)*cs + g] = h;
  }
}

// ---------------- scan pass 3 ----------------
__global__ __launch_bounds__(256)
void scan3_kernel(const float* __restrict__ dt, const float* __restrict__ xp,
                  const float* __restrict__ Alog, const float* __restrict__ hinb,
                  const float* __restrict__ xz,
                  unsigned short* __restrict__ yh, unsigned short* __restrict__ yl) {
  const int g  = blockIdx.x*256 + threadIdx.x;
  const int nq = g & 3;
  const int g2 = g >> 2;
  const int d  = g2 & (DI-1);
  const int bc = g2 >> 11;
  const int c  = bc & (NC-1);
  const int b  = bc >> 6;
  const float4 al = *(const float4*)(Alog + (size_t)d*NS + (nq<<2));
  const float Aa[4] = {-__expf(al.x), -__expf(al.y), -__expf(al.z), -__expf(al.w)};
  float hi[4] = {0.f, 0.f, 0.f, 0.f};
  if (c > 0){
    const size_t pb = (((size_t)(c-1)*B_SZ + b)*DI + d)*NS + (nq<<2);
    const float4 hv = *(const float4*)(hinb + pb);
    hi[0]=hv.x; hi[1]=hv.y; hi[2]=hv.z; hi[3]=hv.w;
  }
  float q[4] = {1,1,1,1};
  const int t0 = c * TC;
  for (int t = t0; t < t0 + TC; ++t){
    const size_t r = (size_t)b*LSEQ + t;
    const float dtv = dt[r*DI + d];
    const float* xpr = xp + r*33;
    float cp = 0.f;
    #pragma unroll
    for (int i=0;i<4;i++){
      q[i] *= __expf(Aa[i]*dtv);
      const float Cv = xpr[17 + (nq<<2) + i];
      cp = fmaf(Cv*q[i], hi[i], cp);
    }
    cp += __shfl_xor(cp, 1);
    cp += __shfl_xor(cp, 2);
    if (nq == 0){
      const float zv = xz[r*XZL + 2048 + d];
      const float yv = (xz[r*XZL + d] + cp) * siluf(zv);
      const unsigned short h16 = f2bf(yv);
      yh[r*DI + d] = h16;
      yl[r*DI + d] = f2bf(yv - bf2f(h16));
    }
  }
}

extern "C" void kernel_launch(void* const* d_in, const int* in_sizes, int n_in,
                              void* d_out, int out_size, void* d_ws, size_t ws_size,
                              hipStream_t stream) {
  const float* x     = (const float*)d_in[0];
  const float* gamma = (const float*)d_in[1];
  const float* beta  = (const float*)d_in[2];
  const float* W_in  = (const float*)d_in[3];
  const float* cw    = (const float*)d_in[4];
  const float* cb    = (const float*)d_in[5];
  const float* Alog  = (const float*)d_in[6];
  const float* Dp    = (const float*)d_in[7];
  const float* Wx    = (const float*)d_in[8];
  const float* Wdt   = (const float*)d_in[9];
  const float* bdt   = (const float*)d_in[10];
  const float* Wout  = (const float*)d_in[11];
  float* out = (float*)d_out;
  float* ws  = (float*)d_ws;

  const size_t M1 = 1048576;
  float* xz   = ws;                 // 16M f32
  float* xsq  = ws + 16*M1;         // 8M f32: xs_h/xs_l, later y_h/y_l
  float* dtb  = ws + 24*M1;         // 8M
  float* Pb   = ws + 32*M1;         // 4M
  float* Hb   = Pb + 4*M1;          // 4M
  float* xpb  = Hb + 4*M1;          // 135168
  float* wxzone = xpb + 135168;
  unsigned short* wx_h = (unsigned short*)wxzone;
  unsigned short* wx_l = wx_h + (size_t)NPAD*DI;
  unsigned short* zone = wx_l + (size_t)NPAD*DI;   // 16M ushort = 32MB
  unsigned short* xn_h = zone;
  unsigned short* xn_l = zone + 4*M1;
  unsigned short* Wi_h = zone + 8*M1;
  unsigned short* Wi_l = zone + 12*M1;
  unsigned short* Wo_h = zone;              // split AFTER gemm1
  unsigned short* Wo_l = zone + 2*M1;
  float* partial = (float*)(zone + 4*M1);   // 4M f32, inside zone (8..24MB region)
  unsigned short* xs_h = (unsigned short*)xsq;
  unsigned short* xs_l = (unsigned short*)xsq + 8*M1;
  unsigned short* y_h  = (unsigned short*)xsq;
  unsigned short* y_l  = (unsigned short*)xsq + 8*M1;

  ln_split_kernel<<<RTOT, 256, 0, stream>>>(x, gamma, beta, xn_h, xn_l);
  split_kernel<<<(2*DI*DM/4 + 255)/256, 256, 0, stream>>>(W_in, Wi_h, Wi_l, 2*DI*DM/4);
  split_pad_wx_kernel<<<(NPAD*DI/4 + 255)/256, 256, 0, stream>>>(Wx, wx_h, wx_l);
  gemm_bf16x3<<<dim3(XZL/128, RTOT/128), 256, 0, stream>>>(xn_h, xn_l, Wi_h, Wi_l,
                                                           xz, RTOT, XZL, DM, XZL);
  split_kernel<<<(DM*DI/4 + 255)/256, 256, 0, stream>>>(Wout, Wo_h, Wo_l, DM*DI/4);
  conv_silu_split_kernel<<<(RTOT*(DI/4))/256, 256, 0, stream>>>(xz, cw, cb, xs_h, xs_l);
  xp_dt_kernel<<<RTOT/16, 256, 0, stream>>>(xs_h, xs_l, wx_h, wx_l, Wdt, bdt, xpb, dtb);
  scan1_kernel<<<(B_SZ*NC*DI*4)/256, 256, 0, stream>>>(xs_h, xs_l, dtb, xpb, Alog, Dp, xz, Pb, Hb);
  scan2_kernel<<<(B_SZ*DI*NS)/256, 256, 0, stream>>>(Pb, Hb);
  scan3_kernel<<<(B_SZ*NC*DI*4)/256, 256, 0, stream>>>(dtb, xpb, Alog, Hb, xz, y_h, y_l);
  gemm_bf16x3_b64sk<<<dim3(DM/128, RTOT/64, 2), 256, 0, stream>>>(y_h, y_l, Wo_h, Wo_l,
                                                                  out, partial, DI, DI/2, DM);
  add_kernel<<<(RTOT*DM/4 + 255)/256, 256, 0, stream>>>(out, partial, RTOT*DM/4);
}

// Round 8
// 439.008 us; speedup vs baseline: 1.0455x; 1.0234x over previous
//
#include <hip/hip_runtime.h>
#include <math.h>

// MambaSSMBlock: B=2, L=2048, Dm=1024, Di=2048, N=16, convK=4
// Round 8: recovery round. xz GEMM reverted to proven 128^2 bf16x3 kernel
//   (R7's 256-tile had incomplete LDS staging -> NaN). Kept from R7:
//   (a) out GEMM = 128^2 + split-K=2 (z-dim) + add pass;
//   (b) scan1 slim (P,H only) + scan3 full recompute seeded with h_in.
// Workspace: ~193 MB.

#define B_SZ 2
#define LSEQ 2048
#define DM   1024
#define DI   2048
#define NS   16
#define RTOT (B_SZ*LSEQ)
#define NC   64
#define TC   (LSEQ/NC)
#define XZL  4096
#define NPAD 48

typedef __attribute__((ext_vector_type(8))) short bfrag;
typedef __attribute__((ext_vector_type(4))) float f32x4;

__device__ __forceinline__ float siluf(float v){ return v / (1.f + __expf(-v)); }

__device__ __forceinline__ unsigned short f2bf(float f){
  unsigned int u = __float_as_uint(f);
  u += 0x7FFFu + ((u >> 16) & 1u);
  return (unsigned short)(u >> 16);
}
__device__ __forceinline__ float bf2f(unsigned short h){
  return __uint_as_float(((unsigned int)h) << 16);
}

// ---------------- LayerNorm fused with bf16 hi/lo split ----------------
__global__ __launch_bounds__(256)
void ln_split_kernel(const float* __restrict__ x, const float* __restrict__ g,
                     const float* __restrict__ b,
                     unsigned short* __restrict__ xh, unsigned short* __restrict__ xl) {
  __shared__ float red[8];
  const int r = blockIdx.x, tid = threadIdx.x;
  const float4 v = ((const float4*)(x + (size_t)r*DM))[tid];
  float s  = v.x+v.y+v.z+v.w;
  float ss = v.x*v.x+v.y*v.y+v.z*v.z+v.w*v.w;
  #pragma unroll
  for (int off=32; off; off>>=1){ s += __shfl_xor(s,off); ss += __shfl_xor(ss,off); }
  if ((tid & 63)==0){ int w=tid>>6; red[w]=s; red[4+w]=ss; }
  __syncthreads();
  s  = red[0]+red[1]+red[2]+red[3];
  ss = red[4]+red[5]+red[6]+red[7];
  const float mu  = s*(1.f/DM);
  const float inv = rsqrtf(ss*(1.f/DM) - mu*mu + 1e-5f);
  const float4 gv = ((const float4*)g)[tid];
  const float4 bv = ((const float4*)b)[tid];
  float o[4];
  o[0] = (v.x-mu)*inv*gv.x + bv.x;
  o[1] = (v.y-mu)*inv*gv.y + bv.y;
  o[2] = (v.z-mu)*inv*gv.z + bv.z;
  o[3] = (v.w-mu)*inv*gv.w + bv.w;
  ushort4 h, l;
  h.x = f2bf(o[0]); l.x = f2bf(o[0] - bf2f(h.x));
  h.y = f2bf(o[1]); l.y = f2bf(o[1] - bf2f(h.y));
  h.z = f2bf(o[2]); l.z = f2bf(o[2] - bf2f(h.z));
  h.w = f2bf(o[3]); l.w = f2bf(o[3] - bf2f(h.w));
  ((ushort4*)(xh + (size_t)r*DM))[tid] = h;
  ((ushort4*)(xl + (size_t)r*DM))[tid] = l;
}

// ---------------- generic fp32 -> bf16 hi/lo split ----------------
__global__ __launch_bounds__(256)
void split_kernel(const float* __restrict__ in, unsigned short* __restrict__ hi,
                  unsigned short* __restrict__ lo, int n4) {
  const int i = blockIdx.x*256 + threadIdx.x;
  if (i >= n4) return;
  const float4 v = ((const float4*)in)[i];
  ushort4 h, l;
  h.x = f2bf(v.x); l.x = f2bf(v.x - bf2f(h.x));
  h.y = f2bf(v.y); l.y = f2bf(v.y - bf2f(h.y));
  h.z = f2bf(v.z); l.z = f2bf(v.z - bf2f(h.z));
  h.w = f2bf(v.w); l.w = f2bf(v.w - bf2f(h.w));
  ((ushort4*)hi)[i] = h;
  ((ushort4*)lo)[i] = l;
}

// ---------------- Wx split with zero pad to 48 rows ----------------
__global__ __launch_bounds__(256)
void split_pad_wx_kernel(const float* __restrict__ in, unsigned short* __restrict__ hi,
                         unsigned short* __restrict__ lo) {
  const int i = blockIdx.x*256 + threadIdx.x;
  if (i >= NPAD*DI/4) return;
  const int row = i >> 9;
  float4 v = make_float4(0.f,0.f,0.f,0.f);
  if (row < 33) v = ((const float4*)in)[i];
  ushort4 h, l;
  h.x = f2bf(v.x); l.x = f2bf(v.x - bf2f(h.x));
  h.y = f2bf(v.y); l.y = f2bf(v.y - bf2f(h.y));
  h.z = f2bf(v.z); l.z = f2bf(v.z - bf2f(h.z));
  h.w = f2bf(v.w); l.w = f2bf(v.w - bf2f(h.w));
  ((ushort4*)hi)[i] = h;
  ((ushort4*)lo)[i] = l;
}

// ---------------- bf16x3 MFMA GEMM 128x128, optional split-K via blockIdx.z ----
// Proven kernel (R3-R6, 940 TF). z=0 -> C0, z=1 -> C1; koff = z*kLen.
__global__ __launch_bounds__(256)
void gemm_bf16x3(const unsigned short* __restrict__ Ah, const unsigned short* __restrict__ Al,
                 const unsigned short* __restrict__ Bh, const unsigned short* __restrict__ Bl,
                 float* __restrict__ C0, float* __restrict__ C1,
                 int lda, int kLen, int ldc)
{
  __shared__ __align__(16) unsigned short lds[4][128][40];
  const int tid = threadIdx.x;
  const int bm = blockIdx.y << 7;
  const int bn = blockIdx.x << 7;
  const int koff = blockIdx.z * kLen;
  const int wave = tid >> 6;
  const int lane = tid & 63;
  const int wm = (wave >> 1) << 6;
  const int wn = (wave & 1) << 6;
  const int fr = lane & 15;
  const int kg = lane >> 4;
  const int srow = tid >> 1;
  const int scol = (tid & 1) << 4;

  const unsigned short* pAh = Ah + (size_t)(bm + srow)*lda + scol + koff;
  const unsigned short* pAl = Al + (size_t)(bm + srow)*lda + scol + koff;
  const unsigned short* pBh = Bh + (size_t)(bn + srow)*lda + scol + koff;
  const unsigned short* pBl = Bl + (size_t)(bn + srow)*lda + scol + koff;
  float* Cz = blockIdx.z ? C1 : C0;

  f32x4 acc[4][4];
  #pragma unroll
  for (int m=0;m<4;m++)
    #pragma unroll
    for (int n=0;n<4;n++)
      #pragma unroll
      for (int r=0;r<4;r++) acc[m][n][r] = 0.f;

  uint4 ra0, ra1, rb0, rb1, rc0, rc1, rd0, rd1;
#define LOAD8(k0) do { \
    ra0 = *(const uint4*)(pAh + (k0));     ra1 = *(const uint4*)(pAh + (k0) + 8); \
    rb0 = *(const uint4*)(pAl + (k0));     rb1 = *(const uint4*)(pAl + (k0) + 8); \
    rc0 = *(const uint4*)(pBh + (k0));     rc1 = *(const uint4*)(pBh + (k0) + 8); \
    rd0 = *(const uint4*)(pBl + (k0));     rd1 = *(const uint4*)(pBl + (k0) + 8); \
  } while(0)

  const int nIter = kLen >> 5;
  LOAD8(0);
  for (int it = 0; it < nIter; ++it) {
    __syncthreads();
    *(uint4*)&lds[0][srow][scol] = ra0;  *(uint4*)&lds[0][srow][scol+8] = ra1;
    *(uint4*)&lds[1][srow][scol] = rb0;  *(uint4*)&lds[1][srow][scol+8] = rb1;
    *(uint4*)&lds[2][srow][scol] = rc0;  *(uint4*)&lds[2][srow][scol+8] = rc1;
    *(uint4*)&lds[3][srow][scol] = rd0;  *(uint4*)&lds[3][srow][scol+8] = rd1;
    __syncthreads();
    if (it + 1 < nIter) LOAD8((size_t)(it+1) << 5);

    bfrag ah[4], al[4], bb[4];
    #pragma unroll
    for (int m=0;m<4;m++){
      ah[m] = *(const bfrag*)&lds[0][wm + (m<<4) + fr][kg<<3];
      al[m] = *(const bfrag*)&lds[1][wm + (m<<4) + fr][kg<<3];
    }
    #pragma unroll
    for (int n=0;n<4;n++) bb[n] = *(const bfrag*)&lds[2][wn + (n<<4) + fr][kg<<3];
    #pragma unroll
    for (int m=0;m<4;m++)
      #pragma unroll
      for (int n=0;n<4;n++){
        acc[m][n] = __builtin_amdgcn_mfma_f32_16x16x32_bf16(ah[m], bb[n], acc[m][n], 0, 0, 0);
        acc[m][n] = __builtin_amdgcn_mfma_f32_16x16x32_bf16(al[m], bb[n], acc[m][n], 0, 0, 0);
      }
    #pragma unroll
    for (int n=0;n<4;n++) bb[n] = *(const bfrag*)&lds[3][wn + (n<<4) + fr][kg<<3];
    #pragma unroll
    for (int m=0;m<4;m++)
      #pragma unroll
      for (int n=0;n<4;n++)
        acc[m][n] = __builtin_amdgcn_mfma_f32_16x16x32_bf16(ah[m], bb[n], acc[m][n], 0, 0, 0);
  }
#undef LOAD8

  #pragma unroll
  for (int m=0;m<4;m++)
    #pragma unroll
    for (int n=0;n<4;n++){
      float* Cp = Cz + (size_t)(bm + wm + (m<<4) + (kg<<2))*ldc + bn + wn + (n<<4) + fr;
      #pragma unroll
      for (int r=0;r<4;r++) Cp[(size_t)r*ldc] = acc[m][n][r];
    }
}

// ---------------- add partial ----------------
__global__ __launch_bounds__(256)
void add_kernel(float* __restrict__ out, const float* __restrict__ part, int n4) {
  const int i = blockIdx.x*256 + threadIdx.x;
  if (i >= n4) return;
  const float4 a = ((const float4*)out)[i];
  const float4 b = ((const float4*)part)[i];
  ((float4*)out)[i] = make_float4(a.x+b.x, a.y+b.y, a.z+b.z, a.w+b.w);
}

// ---------------- depthwise causal conv K=4 + bias + SiLU -> bf16 hi/lo ----------------
__global__ __launch_bounds__(256)
void conv_silu_split_kernel(const float* __restrict__ xz, const float* __restrict__ cw,
                            const float* __restrict__ cb,
                            unsigned short* __restrict__ xsh, unsigned short* __restrict__ xsl) {
  const int idx = blockIdx.x * 256 + threadIdx.x;
  const int d4 = idx & (DI/4 - 1);
  const int r  = idx >> 9;
  const int b  = r >> 11;
  const int t  = r & (LSEQ-1);
  const int d  = d4 << 2;
  const float4 w0 = *(const float4*)(cw + (size_t)(d+0)*4);
  const float4 w1 = *(const float4*)(cw + (size_t)(d+1)*4);
  const float4 w2 = *(const float4*)(cw + (size_t)(d+2)*4);
  const float4 w3 = *(const float4*)(cw + (size_t)(d+3)*4);
  const float wk[4][4] = {{w0.x,w1.x,w2.x,w3.x},{w0.y,w1.y,w2.y,w3.y},
                          {w0.z,w1.z,w2.z,w3.z},{w0.w,w1.w,w2.w,w3.w}};
  float4 acc = *(const float4*)(cb + d);
  #pragma unroll
  for (int k=0;k<4;k++){
    const int tt = t - 3 + k;
    if (tt < 0) continue;
    const float4 xv = *(const float4*)(xz + ((size_t)b*LSEQ + tt)*XZL + d);
    acc.x = fmaf(wk[k][0], xv.x, acc.x);
    acc.y = fmaf(wk[k][1], xv.y, acc.y);
    acc.z = fmaf(wk[k][2], xv.z, acc.z);
    acc.w = fmaf(wk[k][3], xv.w, acc.w);
  }
  acc.x = siluf(acc.x); acc.y = siluf(acc.y); acc.z = siluf(acc.z); acc.w = siluf(acc.w);
  ushort4 h, l;
  h.x = f2bf(acc.x); l.x = f2bf(acc.x - bf2f(h.x));
  h.y = f2bf(acc.y); l.y = f2bf(acc.y - bf2f(h.y));
  h.z = f2bf(acc.z); l.z = f2bf(acc.z - bf2f(h.z));
  h.w = f2bf(acc.w); l.w = f2bf(acc.w - bf2f(h.w));
  *(ushort4*)(xsh + (size_t)r*DI + d) = h;
  *(ushort4*)(xsl + (size_t)r*DI + d) = l;
}

// ---------------- xp (K-split MFMA, LDS-reduce) + fused dt ----------------
__global__ __launch_bounds__(256)
void xp_dt_kernel(const unsigned short* __restrict__ xsh, const unsigned short* __restrict__ xsl,
                  const unsigned short* __restrict__ wxh, const unsigned short* __restrict__ wxl,
                  const float* __restrict__ Wdt, const float* __restrict__ bdt,
                  float* __restrict__ xp, float* __restrict__ dtb) {
  __shared__ float red[4][64][12];
  __shared__ float xp_lds[16][34];
  __shared__ float wl[256*33 + 8];
  const int tid = threadIdx.x;
  const int wave = tid >> 6, lane = tid & 63;
  const int fr = lane & 15, kg = lane >> 4;
  const int m0 = blockIdx.x << 4;
  const size_t koff = (size_t)wave << 9;

  const unsigned short* pah = xsh + (size_t)(m0 + fr)*DI + (kg<<3) + koff;
  const unsigned short* pal = xsl + (size_t)(m0 + fr)*DI + (kg<<3) + koff;
  const unsigned short* pbh = wxh + (size_t)fr*DI + (kg<<3) + koff;
  const unsigned short* pbl = wxl + (size_t)fr*DI + (kg<<3) + koff;

  f32x4 acc[3];
  #pragma unroll
  for (int nf=0;nf<3;nf++)
    #pragma unroll
    for (int r=0;r<4;r++) acc[nf][r] = 0.f;

  for (int kk = 0; kk < 512; kk += 32) {
    const bfrag ah = *(const bfrag*)(pah + kk);
    const bfrag al_ = *(const bfrag*)(pal + kk);
    #pragma unroll
    for (int nf=0;nf<3;nf++){
      const bfrag bh = *(const bfrag*)(pbh + (size_t)nf*16*DI + kk);
      const bfrag bl = *(const bfrag*)(pbl + (size_t)nf*16*DI + kk);
      acc[nf] = __builtin_amdgcn_mfma_f32_16x16x32_bf16(ah, bh, acc[nf], 0, 0, 0);
      acc[nf] = __builtin_amdgcn_mfma_f32_16x16x32_bf16(al_, bh, acc[nf], 0, 0, 0);
      acc[nf] = __builtin_amdgcn_mfma_f32_16x16x32_bf16(ah, bl, acc[nf], 0, 0, 0);
    }
  }
  #pragma unroll
  for (int nf=0;nf<3;nf++)
    #pragma unroll
    for (int r=0;r<4;r++) red[wave][lane][nf*4+r] = acc[nf][r];
  __syncthreads();
  if (wave == 0){
    #pragma unroll
    for (int nf=0;nf<3;nf++){
      const int col = (nf<<4) + fr;
      #pragma unroll
      for (int r=0;r<4;r++){
        const float v = red[0][lane][nf*4+r] + red[1][lane][nf*4+r]
                      + red[2][lane][nf*4+r] + red[3][lane][nf*4+r];
        if (col < 33){
          const int row = (kg<<2) + r;
          xp_lds[row][col] = v;
          xp[(size_t)(m0 + row)*33 + col] = v;
        }
      }
    }
  }
  __syncthreads();
  for (int j=0;j<8;j++){
    const int d0 = j << 8;
    for (int i = tid; i < 256*33; i += 256) wl[i] = Wdt[(size_t)d0*33 + i];
    __syncthreads();
    const float bv = bdt[d0 + tid];
    const float* wrow = &wl[tid*33];
    #pragma unroll
    for (int row=0; row<16; ++row){
      float s = bv;
      #pragma unroll
      for (int k=0;k<33;k++) s = fmaf(xp_lds[row][k], wrow[k], s);
      const float sp = (s > 20.f) ? s : log1pf(__expf(s));
      dtb[(size_t)(m0 + row)*DI + d0 + tid] = sp + 0.001f;
    }
    __syncthreads();
  }
}

// ---------------- scan pass 1 (slim): local chunk scan -> P, H only ----------------
__global__ __launch_bounds__(256)
void scan1_kernel(const unsigned short* __restrict__ xsh, const unsigned short* __restrict__ xsl,
                  const float* __restrict__ dt,
                  const float* __restrict__ xp, const float* __restrict__ Alog,
                  float* __restrict__ Pbuf, float* __restrict__ Hbuf) {
  const int g  = blockIdx.x*256 + threadIdx.x;
  const int nq = g & 3;
  const int g2 = g >> 2;
  const int d  = g2 & (DI-1);
  const int bc = g2 >> 11;
  const int c  = bc & (NC-1);
  const int b  = bc >> 6;
  const float4 al = *(const float4*)(Alog + (size_t)d*NS + (nq<<2));
  const float Aa[4] = {-__expf(al.x), -__expf(al.y), -__expf(al.z), -__expf(al.w)};
  float rA[4];
  #pragma unroll
  for (int i=0;i<4;i++) rA[i] = 1.f/(Aa[i] + 1e-8f);
  float h[4] = {0,0,0,0};
  float P[4] = {1,1,1,1};
  const int t0 = c * TC;
  for (int t = t0; t < t0 + TC; ++t){
    const size_t r = (size_t)b*LSEQ + t;
    const float dtv = dt[r*DI + d];
    const float xv  = bf2f(xsh[r*DI + d]) + bf2f(xsl[r*DI + d]);
    const float* xpr = xp + r*33;
    #pragma unroll
    for (int i=0;i<4;i++){
      const float e = __expf(Aa[i]*dtv);
      P[i] *= e;
      const float Bv = xpr[1 + (nq<<2) + i];
      const float gbx = rA[i] * (1.f - e) * Bv * xv;
      h[i] = fmaf(e, h[i], gbx);
      h[i] = fminf(10.f, fmaxf(-10.f, h[i]));
    }
  }
  const size_t pb = (((size_t)c*B_SZ + b)*DI + d)*NS + (nq<<2);
  *(float4*)(Pbuf+pb) = make_float4(P[0],P[1],P[2],P[3]);
  *(float4*)(Hbuf+pb) = make_float4(h[0],h[1],h[2],h[3]);
}

// ---------------- scan pass 2: sequential chunk combine; hin folded into Hbuf ----
__global__ __launch_bounds__(256)
void scan2_kernel(const float* __restrict__ Pbuf, float* __restrict__ Hbuf) {
  const int g = blockIdx.x*256 + threadIdx.x;
  const size_t cs = (size_t)B_SZ*DI*NS;
  float h = 0.f;
  for (int c=1;c<NC;++c){
    const float Pv = Pbuf[(size_t)(c-1)*cs + g];
    const float Hv = Hbuf[(size_t)(c-1)*cs + g];
    h = fmaf(Pv, h, Hv);
    Hbuf[(size_t)(c-1)*cs + g] = h;
  }
}

// ---------------- scan pass 3: full recompute seeded with h_in; y + silu(z) + split ----
__global__ __launch_bounds__(256)
void scan3_kernel(const unsigned short* __restrict__ xsh, const unsigned short* __restrict__ xsl,
                  const float* __restrict__ dt, const float* __restrict__ xp,
                  const float* __restrict__ Alog, const float* __restrict__ Dp,
                  const float* __restrict__ hinb, const float* __restrict__ xz,
                  unsigned short* __restrict__ yh, unsigned short* __restrict__ yl) {
  const int g  = blockIdx.x*256 + threadIdx.x;
  const int nq = g & 3;
  const int g2 = g >> 2;
  const int d  = g2 & (DI-1);
  const int bc = g2 >> 11;
  const int c  = bc & (NC-1);
  const int b  = bc >> 6;
  const float4 al = *(const float4*)(Alog + (size_t)d*NS + (nq<<2));
  const float Aa[4] = {-__expf(al.x), -__expf(al.y), -__expf(al.z), -__expf(al.w)};
  float rA[4];
  #pragma unroll
  for (int i=0;i<4;i++) rA[i] = 1.f/(Aa[i] + 1e-8f);
  const float Dv = Dp[d];
  float h[4] = {0.f, 0.f, 0.f, 0.f};
  if (c > 0){
    const size_t pb = (((size_t)(c-1)*B_SZ + b)*DI + d)*NS + (nq<<2);
    const float4 hv = *(const float4*)(hinb + pb);
    h[0]=hv.x; h[1]=hv.y; h[2]=hv.z; h[3]=hv.w;
  }
  const int t0 = c * TC;
  for (int t = t0; t < t0 + TC; ++t){
    const size_t r = (size_t)b*LSEQ + t;
    const float dtv = dt[r*DI + d];
    const float xv  = bf2f(xsh[r*DI + d]) + bf2f(xsl[r*DI + d]);
    const float* xpr = xp + r*33;
    float yp = 0.f;
    #pragma unroll
    for (int i=0;i<4;i++){
      const int n = (nq<<2) + i;
      const float e = __expf(Aa[i]*dtv);
      const float Bv = xpr[1 + n];
      const float Cv = xpr[17 + n];
      const float gbx = rA[i] * (1.f - e) * Bv * xv;
      h[i] = fmaf(e, h[i], gbx);
      h[i] = fminf(10.f, fmaxf(-10.f, h[i]));
      yp = fmaf(Cv, h[i], yp);
    }
    yp += __shfl_xor(yp, 1);
    yp += __shfl_xor(yp, 2);
    if (nq == 0){
      const float zv = xz[r*XZL + 2048 + d];
      const float yv = (yp + Dv*xv) * siluf(zv);
      const unsigned short h16 = f2bf(yv);
      yh[r*DI + d] = h16;
      yl[r*DI + d] = f2bf(yv - bf2f(h16));
    }
  }
}

extern "C" void kernel_launch(void* const* d_in, const int* in_sizes, int n_in,
                              void* d_out, int out_size, void* d_ws, size_t ws_size,
                              hipStream_t stream) {
  const float* x     = (const float*)d_in[0];
  const float* gamma = (const float*)d_in[1];
  const float* beta  = (const float*)d_in[2];
  const float* W_in  = (const float*)d_in[3];
  const float* cw    = (const float*)d_in[4];
  const float* cb    = (const float*)d_in[5];
  const float* Alog  = (const float*)d_in[6];
  const float* Dp    = (const float*)d_in[7];
  const float* Wx    = (const float*)d_in[8];
  const float* Wdt   = (const float*)d_in[9];
  const float* bdt   = (const float*)d_in[10];
  const float* Wout  = (const float*)d_in[11];
  float* out = (float*)d_out;
  float* ws  = (float*)d_ws;

  const size_t M1 = 1048576;
  float* xz   = ws;                 // 16M f32
  float* xsq  = ws + 16*M1;         // 8M f32: xs_h/xs_l, later y_h/y_l overlay
  float* dtb  = ws + 24*M1;         // 8M
  float* Pb   = ws + 32*M1;         // 4M
  float* Hb   = Pb + 4*M1;          // 4M
  float* xpb  = Hb + 4*M1;          // 135168
  float* wxzone = xpb + 135168;
  unsigned short* wx_h = (unsigned short*)wxzone;
  unsigned short* wx_l = wx_h + (size_t)NPAD*DI;
  unsigned short* zone = wx_l + (size_t)NPAD*DI;   // 16M ushort = 32MB
  unsigned short* xn_h = zone;
  unsigned short* xn_l = zone + 4*M1;
  unsigned short* Wi_h = zone + 8*M1;
  unsigned short* Wi_l = zone + 12*M1;
  unsigned short* Wo_h = zone;              // split AFTER gemm1
  unsigned short* Wo_l = zone + 2*M1;
  float* partial = (float*)(zone + 4*M1);   // 4M f32 (overlays dead xn_l/Wi region)
  unsigned short* xs_h = (unsigned short*)xsq;
  unsigned short* xs_l = (unsigned short*)xsq + 8*M1;
  unsigned short* y_h  = (unsigned short*)xsq;
  unsigned short* y_l  = (unsigned short*)xsq + 8*M1;

  ln_split_kernel<<<RTOT, 256, 0, stream>>>(x, gamma, beta, xn_h, xn_l);
  split_kernel<<<(2*DI*DM/4 + 255)/256, 256, 0, stream>>>(W_in, Wi_h, Wi_l, 2*DI*DM/4);
  split_pad_wx_kernel<<<(NPAD*DI/4 + 255)/256, 256, 0, stream>>>(Wx, wx_h, wx_l);
  // xz = xn @ W_in^T : proven 128^2 kernel, no split-K (z extent 1)
  gemm_bf16x3<<<dim3(XZL/128, RTOT/128, 1), 256, 0, stream>>>(xn_h, xn_l, Wi_h, Wi_l,
                                                              xz, xz, DM, DM, XZL);
  split_kernel<<<(DM*DI/4 + 255)/256, 256, 0, stream>>>(Wout, Wo_h, Wo_l, DM*DI/4);
  conv_silu_split_kernel<<<(RTOT*(DI/4))/256, 256, 0, stream>>>(xz, cw, cb, xs_h, xs_l);
  xp_dt_kernel<<<RTOT/16, 256, 0, stream>>>(xs_h, xs_l, wx_h, wx_l, Wdt, bdt, xpb, dtb);
  scan1_kernel<<<(B_SZ*NC*DI*4)/256, 256, 0, stream>>>(xs_h, xs_l, dtb, xpb, Alog, Pb, Hb);
  scan2_kernel<<<(B_SZ*DI*NS)/256, 256, 0, stream>>>(Pb, Hb);
  scan3_kernel<<<(B_SZ*NC*DI*4)/256, 256, 0, stream>>>(xs_h, xs_l, dtb, xpb, Alog, Dp,
                                                       Hb, xz, y_h, y_l);
  // out = y @ Wout^T : 128^2 kernel, split-K=2, grid (8,32,2)
  gemm_bf16x3<<<dim3(DM/128, RTOT/128, 2), 256, 0, stream>>>(y_h, y_l, Wo_h, Wo_l,
                                                             out, partial, DI, DI/2, DM);
  add_kernel<<<(RTOT*DM/4 + 255)/256, 256, 0, stream>>>(out, partial, RTOT*DM/4);
}

// Round 9
// 428.753 us; speedup vs baseline: 1.0705x; 1.0239x over previous
//
#include <hip/hip_runtime.h>
#include <math.h>

// MambaSSMBlock: B=2, L=2048, Dm=1024, Di=2048, N=16, convK=4
// Round 9: re-converge to R4's measured-best mid-structure (scan1-y +
//   scan3-light + b64 full-K out GEMM), keep R6's fused xp_dt, drop xs_l
//   (x_ssm as single bf16), merge weight-split launches (13 -> 10).
// Workspace: ~193 MB (same footprint as R8).

#define B_SZ 2
#define LSEQ 2048
#define DM   1024
#define DI   2048
#define NS   16
#define RTOT (B_SZ*LSEQ)
#define NC   64
#define TC   (LSEQ/NC)
#define XZL  4096
#define NPAD 48

typedef __attribute__((ext_vector_type(8))) short bfrag;
typedef __attribute__((ext_vector_type(4))) float f32x4;

__device__ __forceinline__ float siluf(float v){ return v / (1.f + __expf(-v)); }

__device__ __forceinline__ unsigned short f2bf(float f){
  unsigned int u = __float_as_uint(f);
  u += 0x7FFFu + ((u >> 16) & 1u);
  return (unsigned short)(u >> 16);
}
__device__ __forceinline__ float bf2f(unsigned short h){
  return __uint_as_float(((unsigned int)h) << 16);
}

// ---------------- LayerNorm fused with bf16 hi/lo split ----------------
__global__ __launch_bounds__(256)
void ln_split_kernel(const float* __restrict__ x, const float* __restrict__ g,
                     const float* __restrict__ b,
                     unsigned short* __restrict__ xh, unsigned short* __restrict__ xl) {
  __shared__ float red[8];
  const int r = blockIdx.x, tid = threadIdx.x;
  const float4 v = ((const float4*)(x + (size_t)r*DM))[tid];
  float s  = v.x+v.y+v.z+v.w;
  float ss = v.x*v.x+v.y*v.y+v.z*v.z+v.w*v.w;
  #pragma unroll
  for (int off=32; off; off>>=1){ s += __shfl_xor(s,off); ss += __shfl_xor(ss,off); }
  if ((tid & 63)==0){ int w=tid>>6; red[w]=s; red[4+w]=ss; }
  __syncthreads();
  s  = red[0]+red[1]+red[2]+red[3];
  ss = red[4]+red[5]+red[6]+red[7];
  const float mu  = s*(1.f/DM);
  const float inv = rsqrtf(ss*(1.f/DM) - mu*mu + 1e-5f);
  const float4 gv = ((const float4*)g)[tid];
  const float4 bv = ((const float4*)b)[tid];
  float o[4];
  o[0] = (v.x-mu)*inv*gv.x + bv.x;
  o[1] = (v.y-mu)*inv*gv.y + bv.y;
  o[2] = (v.z-mu)*inv*gv.z + bv.z;
  o[3] = (v.w-mu)*inv*gv.w + bv.w;
  ushort4 h, l;
  h.x = f2bf(o[0]); l.x = f2bf(o[0] - bf2f(h.x));
  h.y = f2bf(o[1]); l.y = f2bf(o[1] - bf2f(h.y));
  h.z = f2bf(o[2]); l.z = f2bf(o[2] - bf2f(h.z));
  h.w = f2bf(o[3]); l.w = f2bf(o[3] - bf2f(h.w));
  ((ushort4*)(xh + (size_t)r*DM))[tid] = h;
  ((ushort4*)(xl + (size_t)r*DM))[tid] = l;
}

// ---------------- merged W_in + Wx(pad48) fp32 -> bf16 hi/lo split ----------------
__global__ __launch_bounds__(256)
void split_win_wx_kernel(const float* __restrict__ Win, const float* __restrict__ Wx,
                         unsigned short* __restrict__ wih, unsigned short* __restrict__ wil,
                         unsigned short* __restrict__ wxh, unsigned short* __restrict__ wxl) {
  const int NWIN = 2*DI*DM/4;           // 1048576 float4
  const int NWX  = NPAD*DI/4;           // 24576 float4
  const int i = blockIdx.x*256 + threadIdx.x;
  if (i < NWIN){
    const float4 v = ((const float4*)Win)[i];
    ushort4 h, l;
    h.x = f2bf(v.x); l.x = f2bf(v.x - bf2f(h.x));
    h.y = f2bf(v.y); l.y = f2bf(v.y - bf2f(h.y));
    h.z = f2bf(v.z); l.z = f2bf(v.z - bf2f(h.z));
    h.w = f2bf(v.w); l.w = f2bf(v.w - bf2f(h.w));
    ((ushort4*)wih)[i] = h;
    ((ushort4*)wil)[i] = l;
  } else if (i < NWIN + NWX){
    const int j = i - NWIN;
    const int row = j >> 9;
    float4 v = make_float4(0.f,0.f,0.f,0.f);
    if (row < 33) v = ((const float4*)Wx)[j];
    ushort4 h, l;
    h.x = f2bf(v.x); l.x = f2bf(v.x - bf2f(h.x));
    h.y = f2bf(v.y); l.y = f2bf(v.y - bf2f(h.y));
    h.z = f2bf(v.z); l.z = f2bf(v.z - bf2f(h.z));
    h.w = f2bf(v.w); l.w = f2bf(v.w - bf2f(h.w));
    ((ushort4*)wxh)[j] = h;
    ((ushort4*)wxl)[j] = l;
  }
}

// ---------------- generic fp32 -> bf16 hi/lo split (Wout) ----------------
__global__ __launch_bounds__(256)
void split_kernel(const float* __restrict__ in, unsigned short* __restrict__ hi,
                  unsigned short* __restrict__ lo, int n4) {
  const int i = blockIdx.x*256 + threadIdx.x;
  if (i >= n4) return;
  const float4 v = ((const float4*)in)[i];
  ushort4 h, l;
  h.x = f2bf(v.x); l.x = f2bf(v.x - bf2f(h.x));
  h.y = f2bf(v.y); l.y = f2bf(v.y - bf2f(h.y));
  h.z = f2bf(v.z); l.z = f2bf(v.z - bf2f(h.z));
  h.w = f2bf(v.w); l.w = f2bf(v.w - bf2f(h.w));
  ((ushort4*)hi)[i] = h;
  ((ushort4*)lo)[i] = l;
}

// ---------------- bf16x3 MFMA GEMM 128x128: C = A * B^T (proven, 940 TF) ----------------
__global__ __launch_bounds__(256)
void gemm_bf16x3(const unsigned short* __restrict__ Ah, const unsigned short* __restrict__ Al,
                 const unsigned short* __restrict__ Bh, const unsigned short* __restrict__ Bl,
                 float* __restrict__ C, int M, int N, int K, int ldc)
{
  __shared__ __align__(16) unsigned short lds[4][128][40];
  const int tid = threadIdx.x;
  const int bm = blockIdx.y << 7;
  const int bn = blockIdx.x << 7;
  const int wave = tid >> 6;
  const int lane = tid & 63;
  const int wm = (wave >> 1) << 6;
  const int wn = (wave & 1) << 6;
  const int fr = lane & 15;
  const int kg = lane >> 4;
  const int srow = tid >> 1;
  const int scol = (tid & 1) << 4;

  const unsigned short* pAh = Ah + (size_t)(bm + srow)*K + scol;
  const unsigned short* pAl = Al + (size_t)(bm + srow)*K + scol;
  const unsigned short* pBh = Bh + (size_t)(bn + srow)*K + scol;
  const unsigned short* pBl = Bl + (size_t)(bn + srow)*K + scol;

  f32x4 acc[4][4];
  #pragma unroll
  for (int m=0;m<4;m++)
    #pragma unroll
    for (int n=0;n<4;n++)
      #pragma unroll
      for (int r=0;r<4;r++) acc[m][n][r] = 0.f;

  uint4 ra0, ra1, rb0, rb1, rc0, rc1, rd0, rd1;
#define LOAD8(k0) do { \
    ra0 = *(const uint4*)(pAh + (k0));     ra1 = *(const uint4*)(pAh + (k0) + 8); \
    rb0 = *(const uint4*)(pAl + (k0));     rb1 = *(const uint4*)(pAl + (k0) + 8); \
    rc0 = *(const uint4*)(pBh + (k0));     rc1 = *(const uint4*)(pBh + (k0) + 8); \
    rd0 = *(const uint4*)(pBl + (k0));     rd1 = *(const uint4*)(pBl + (k0) + 8); \
  } while(0)

  const int nIter = K >> 5;
  LOAD8(0);
  for (int it = 0; it < nIter; ++it) {
    __syncthreads();
    *(uint4*)&lds[0][srow][scol] = ra0;  *(uint4*)&lds[0][srow][scol+8] = ra1;
    *(uint4*)&lds[1][srow][scol] = rb0;  *(uint4*)&lds[1][srow][scol+8] = rb1;
    *(uint4*)&lds[2][srow][scol] = rc0;  *(uint4*)&lds[2][srow][scol+8] = rc1;
    *(uint4*)&lds[3][srow][scol] = rd0;  *(uint4*)&lds[3][srow][scol+8] = rd1;
    __syncthreads();
    if (it + 1 < nIter) LOAD8((size_t)(it+1) << 5);

    bfrag ah[4], al[4], bb[4];
    #pragma unroll
    for (int m=0;m<4;m++){
      ah[m] = *(const bfrag*)&lds[0][wm + (m<<4) + fr][kg<<3];
      al[m] = *(const bfrag*)&lds[1][wm + (m<<4) + fr][kg<<3];
    }
    #pragma unroll
    for (int n=0;n<4;n++) bb[n] = *(const bfrag*)&lds[2][wn + (n<<4) + fr][kg<<3];
    #pragma unroll
    for (int m=0;m<4;m++)
      #pragma unroll
      for (int n=0;n<4;n++){
        acc[m][n] = __builtin_amdgcn_mfma_f32_16x16x32_bf16(ah[m], bb[n], acc[m][n], 0, 0, 0);
        acc[m][n] = __builtin_amdgcn_mfma_f32_16x16x32_bf16(al[m], bb[n], acc[m][n], 0, 0, 0);
      }
    #pragma unroll
    for (int n=0;n<4;n++) bb[n] = *(const bfrag*)&lds[3][wn + (n<<4) + fr][kg<<3];
    #pragma unroll
    for (int m=0;m<4;m++)
      #pragma unroll
      for (int n=0;n<4;n++)
        acc[m][n] = __builtin_amdgcn_mfma_f32_16x16x32_bf16(ah[m], bb[n], acc[m][n], 0, 0, 0);
  }
#undef LOAD8

  #pragma unroll
  for (int m=0;m<4;m++)
    #pragma unroll
    for (int n=0;n<4;n++){
      float* Cp = C + (size_t)(bm + wm + (m<<4) + (kg<<2))*ldc + bn + wn + (n<<4) + fr;
      #pragma unroll
      for (int r=0;r<4;r++) Cp[(size_t)r*ldc] = acc[m][n][r];
    }
}

// ---------------- bf16x3 MFMA GEMM 64x128 tile, full-K (out GEMM, R4's proven) ----
__global__ __launch_bounds__(256)
void gemm_bf16x3_b64(const unsigned short* __restrict__ Ah, const unsigned short* __restrict__ Al,
                     const unsigned short* __restrict__ Bh, const unsigned short* __restrict__ Bl,
                     float* __restrict__ C, int M, int N, int K, int ldc)
{
  __shared__ __align__(16) unsigned short ldsA[2][64][40];
  __shared__ __align__(16) unsigned short ldsB[2][128][40];
  const int tid = threadIdx.x;
  const int bm = blockIdx.y << 6;
  const int bn = blockIdx.x << 7;
  const int wave = tid >> 6;
  const int lane = tid & 63;
  const int wm = (wave >> 1) << 5;
  const int wn = (wave & 1) << 6;
  const int fr = lane & 15;
  const int kg = lane >> 4;
  const int arow = tid >> 2, acol = (tid & 3) << 3;
  const int brow = tid >> 1, bcol = (tid & 1) << 4;

  const unsigned short* pAh = Ah + (size_t)(bm + arow)*K + acol;
  const unsigned short* pAl = Al + (size_t)(bm + arow)*K + acol;
  const unsigned short* pBh = Bh + (size_t)(bn + brow)*K + bcol;
  const unsigned short* pBl = Bl + (size_t)(bn + brow)*K + bcol;

  f32x4 acc[2][4];
  #pragma unroll
  for (int m=0;m<2;m++)
    #pragma unroll
    for (int n=0;n<4;n++)
      #pragma unroll
      for (int r=0;r<4;r++) acc[m][n][r] = 0.f;

  uint4 ra, rb, rc0, rc1, rd0, rd1;
#define LOAD6(k0) do { \
    ra  = *(const uint4*)(pAh + (k0)); \
    rb  = *(const uint4*)(pAl + (k0)); \
    rc0 = *(const uint4*)(pBh + (k0));  rc1 = *(const uint4*)(pBh + (k0) + 8); \
    rd0 = *(const uint4*)(pBl + (k0));  rd1 = *(const uint4*)(pBl + (k0) + 8); \
  } while(0)

  const int nIter = K >> 5;
  LOAD6(0);
  for (int it = 0; it < nIter; ++it) {
    __syncthreads();
    *(uint4*)&ldsA[0][arow][acol] = ra;
    *(uint4*)&ldsA[1][arow][acol] = rb;
    *(uint4*)&ldsB[0][brow][bcol] = rc0;  *(uint4*)&ldsB[0][brow][bcol+8] = rc1;
    *(uint4*)&ldsB[1][brow][bcol] = rd0;  *(uint4*)&ldsB[1][brow][bcol+8] = rd1;
    __syncthreads();
    if (it + 1 < nIter) LOAD6((size_t)(it+1) << 5);

    bfrag ah[2], al[2], bh[4], bl[4];
    #pragma unroll
    for (int m=0;m<2;m++){
      ah[m] = *(const bfrag*)&ldsA[0][wm + (m<<4) + fr][kg<<3];
      al[m] = *(const bfrag*)&ldsA[1][wm + (m<<4) + fr][kg<<3];
    }
    #pragma unroll
    for (int n=0;n<4;n++){
      bh[n] = *(const bfrag*)&ldsB[0][wn + (n<<4) + fr][kg<<3];
      bl[n] = *(const bfrag*)&ldsB[1][wn + (n<<4) + fr][kg<<3];
    }
    #pragma unroll
    for (int m=0;m<2;m++)
      #pragma unroll
      for (int n=0;n<4;n++){
        acc[m][n] = __builtin_amdgcn_mfma_f32_16x16x32_bf16(ah[m], bh[n], acc[m][n], 0, 0, 0);
        acc[m][n] = __builtin_amdgcn_mfma_f32_16x16x32_bf16(al[m], bh[n], acc[m][n], 0, 0, 0);
        acc[m][n] = __builtin_amdgcn_mfma_f32_16x16x32_bf16(ah[m], bl[n], acc[m][n], 0, 0, 0);
      }
  }
#undef LOAD6

  #pragma unroll
  for (int m=0;m<2;m++)
    #pragma unroll
    for (int n=0;n<4;n++){
      float* Cp = C + (size_t)(bm + wm + (m<<4) + (kg<<2))*ldc + bn + wn + (n<<4) + fr;
      #pragma unroll
      for (int r=0;r<4;r++) Cp[(size_t)r*ldc] = acc[m][n][r];
    }
}

// ---------------- depthwise causal conv K=4 + bias + SiLU -> single bf16 ----------------
__global__ __launch_bounds__(256)
void conv_silu_h_kernel(const float* __restrict__ xz, const float* __restrict__ cw,
                        const float* __restrict__ cb, unsigned short* __restrict__ xsh) {
  const int idx = blockIdx.x * 256 + threadIdx.x;
  const int d4 = idx & (DI/4 - 1);
  const int r  = idx >> 9;
  const int b  = r >> 11;
  const int t  = r & (LSEQ-1);
  const int d  = d4 << 2;
  const float4 w0 = *(const float4*)(cw + (size_t)(d+0)*4);
  const float4 w1 = *(const float4*)(cw + (size_t)(d+1)*4);
  const float4 w2 = *(const float4*)(cw + (size_t)(d+2)*4);
  const float4 w3 = *(const float4*)(cw + (size_t)(d+3)*4);
  const float wk[4][4] = {{w0.x,w1.x,w2.x,w3.x},{w0.y,w1.y,w2.y,w3.y},
                          {w0.z,w1.z,w2.z,w3.z},{w0.w,w1.w,w2.w,w3.w}};
  float4 acc = *(const float4*)(cb + d);
  #pragma unroll
  for (int k=0;k<4;k++){
    const int tt = t - 3 + k;
    if (tt < 0) continue;
    const float4 xv = *(const float4*)(xz + ((size_t)b*LSEQ + tt)*XZL + d);
    acc.x = fmaf(wk[k][0], xv.x, acc.x);
    acc.y = fmaf(wk[k][1], xv.y, acc.y);
    acc.z = fmaf(wk[k][2], xv.z, acc.z);
    acc.w = fmaf(wk[k][3], xv.w, acc.w);
  }
  ushort4 h;
  h.x = f2bf(siluf(acc.x));
  h.y = f2bf(siluf(acc.y));
  h.z = f2bf(siluf(acc.z));
  h.w = f2bf(siluf(acc.w));
  *(ushort4*)(xsh + (size_t)r*DI + d) = h;
}

// ---------------- xp (K-split MFMA, LDS-reduce) + fused dt; xs single-bf16 ----------------
__global__ __launch_bounds__(256)
void xp_dt_kernel(const unsigned short* __restrict__ xsh,
                  const unsigned short* __restrict__ wxh, const unsigned short* __restrict__ wxl,
                  const float* __restrict__ Wdt, const float* __restrict__ bdt,
                  float* __restrict__ xp, float* __restrict__ dtb) {
  __shared__ float red[4][64][12];
  __shared__ float xp_lds[16][34];
  __shared__ float wl[256*33 + 8];
  const int tid = threadIdx.x;
  const int wave = tid >> 6, lane = tid & 63;
  const int fr = lane & 15, kg = lane >> 4;
  const int m0 = blockIdx.x << 4;
  const size_t koff = (size_t)wave << 9;

  const unsigned short* pah = xsh + (size_t)(m0 + fr)*DI + (kg<<3) + koff;
  const unsigned short* pbh = wxh + (size_t)fr*DI + (kg<<3) + koff;
  const unsigned short* pbl = wxl + (size_t)fr*DI + (kg<<3) + koff;

  f32x4 acc[3];
  #pragma unroll
  for (int nf=0;nf<3;nf++)
    #pragma unroll
    for (int r=0;r<4;r++) acc[nf][r] = 0.f;

  for (int kk = 0; kk < 512; kk += 32) {
    const bfrag ah = *(const bfrag*)(pah + kk);
    #pragma unroll
    for (int nf=0;nf<3;nf++){
      const bfrag bh = *(const bfrag*)(pbh + (size_t)nf*16*DI + kk);
      const bfrag bl = *(const bfrag*)(pbl + (size_t)nf*16*DI + kk);
      acc[nf] = __builtin_amdgcn_mfma_f32_16x16x32_bf16(ah, bh, acc[nf], 0, 0, 0);
      acc[nf] = __builtin_amdgcn_mfma_f32_16x16x32_bf16(ah, bl, acc[nf], 0, 0, 0);
    }
  }
  #pragma unroll
  for (int nf=0;nf<3;nf++)
    #pragma unroll
    for (int r=0;r<4;r++) red[wave][lane][nf*4+r] = acc[nf][r];
  __syncthreads();
  if (wave == 0){
    #pragma unroll
    for (int nf=0;nf<3;nf++){
      const int col = (nf<<4) + fr;
      #pragma unroll
      for (int r=0;r<4;r++){
        const float v = red[0][lane][nf*4+r] + red[1][lane][nf*4+r]
                      + red[2][lane][nf*4+r] + red[3][lane][nf*4+r];
        if (col < 33){
          const int row = (kg<<2) + r;
          xp_lds[row][col] = v;
          xp[(size_t)(m0 + row)*33 + col] = v;
        }
      }
    }
  }
  __syncthreads();
  for (int j=0;j<8;j++){
    const int d0 = j << 8;
    for (int i = tid; i < 256*33; i += 256) wl[i] = Wdt[(size_t)d0*33 + i];
    __syncthreads();
    const float bv = bdt[d0 + tid];
    const float* wrow = &wl[tid*33];
    #pragma unroll
    for (int row=0; row<16; ++row){
      float s = bv;
      #pragma unroll
      for (int k=0;k<33;k++) s = fmaf(xp_lds[row][k], wrow[k], s);
      const float sp = (s > 20.f) ? s : log1pf(__expf(s));
      dtb[(size_t)(m0 + row)*DI + d0 + tid] = sp + 0.001f;
    }
    __syncthreads();
  }
}

// ---------------- scan pass 1: local chunk scan -> y_loc (xz x-half), P, H ----------------
__global__ __launch_bounds__(256)
void scan1_kernel(const unsigned short* __restrict__ xsh, const float* __restrict__ dt,
                  const float* __restrict__ xp, const float* __restrict__ Alog,
                  const float* __restrict__ Dp,
                  float* __restrict__ y, float* __restrict__ Pbuf, float* __restrict__ Hbuf) {
  const int g  = blockIdx.x*256 + threadIdx.x;
  const int nq = g & 3;
  const int g2 = g >> 2;
  const int d  = g2 & (DI-1);
  const int bc = g2 >> 11;
  const int c  = bc & (NC-1);
  const int b  = bc >> 6;
  const float4 al = *(const float4*)(Alog + (size_t)d*NS + (nq<<2));
  const float Aa[4] = {-__expf(al.x), -__expf(al.y), -__expf(al.z), -__expf(al.w)};
  float rA[4];
  #pragma unroll
  for (int i=0;i<4;i++) rA[i] = 1.f/(Aa[i] + 1e-8f);
  const float Dv = Dp[d];
  float h[4] = {0,0,0,0};
  float P[4] = {1,1,1,1};
  const int t0 = c * TC;
  for (int t = t0; t < t0 + TC; ++t){
    const size_t r = (size_t)b*LSEQ + t;
    const float dtv = dt[r*DI + d];
    const float xv  = bf2f(xsh[r*DI + d]);
    const float* xpr = xp + r*33;
    float yp = 0.f;
    #pragma unroll
    for (int i=0;i<4;i++){
      const int n = (nq<<2) + i;
      const float e = __expf(Aa[i]*dtv);
      P[i] *= e;
      const float Bv = xpr[1 + n];
      const float Cv = xpr[17 + n];
      const float gbx = rA[i] * (1.f - e) * Bv * xv;
      h[i] = fmaf(e, h[i], gbx);
      h[i] = fminf(10.f, fmaxf(-10.f, h[i]));
      yp = fmaf(Cv, h[i], yp);
    }
    yp += __shfl_xor(yp, 1);
    yp += __shfl_xor(yp, 2);
    if (nq == 0) y[r*XZL + d] = yp + Dv*xv;
  }
  const size_t pb = (((size_t)c*B_SZ + b)*DI + d)*NS + (nq<<2);
  *(float4*)(Pbuf+pb) = make_float4(P[0],P[1],P[2],P[3]);
  *(float4*)(Hbuf+pb) = make_float4(h[0],h[1],h[2],h[3]);
}

// ---------------- scan pass 2: sequential chunk combine; hin folded into Hbuf ----
__global__ __launch_bounds__(256)
void scan2_kernel(const float* __restrict__ Pbuf, float* __restrict__ Hbuf) {
  const int g = blockIdx.x*256 + threadIdx.x;
  const size_t cs = (size_t)B_SZ*DI*NS;
  float h = 0.f;
  for (int c=1;c<NC;++c){
    const float Pv = Pbuf[(size_t)(c-1)*cs + g];
    const float Hv = Hbuf[(size_t)(c-1)*cs + g];
    h = fmaf(Pv, h, Hv);
    Hbuf[(size_t)(c-1)*cs + g] = h;
  }
}

// ---------------- scan pass 3: light cross-chunk correction + silu(z) + y split ----
__global__ __launch_bounds__(256)
void scan3_kernel(const float* __restrict__ dt, const float* __restrict__ xp,
                  const float* __restrict__ Alog, const float* __restrict__ hinb,
                  const float* __restrict__ xz,
                  unsigned short* __restrict__ yh, unsigned short* __restrict__ yl) {
  const int g  = blockIdx.x*256 + threadIdx.x;
  const int nq = g & 3;
  const int g2 = g >> 2;
  const int d  = g2 & (DI-1);
  const int bc = g2 >> 11;
  const int c  = bc & (NC-1);
  const int b  = bc >> 6;
  const float4 al = *(const float4*)(Alog + (size_t)d*NS + (nq<<2));
  const float Aa[4] = {-__expf(al.x), -__expf(al.y), -__expf(al.z), -__expf(al.w)};
  float hi[4] = {0.f, 0.f, 0.f, 0.f};
  if (c > 0){
    const size_t pb = (((size_t)(c-1)*B_SZ + b)*DI + d)*NS + (nq<<2);
    const float4 hv = *(const float4*)(hinb + pb);
    hi[0]=hv.x; hi[1]=hv.y; hi[2]=hv.z; hi[3]=hv.w;
  }
  float q[4] = {1,1,1,1};
  const int t0 = c * TC;
  for (int t = t0; t < t0 + TC; ++t){
    const size_t r = (size_t)b*LSEQ + t;
    const float dtv = dt[r*DI + d];
    const float* xpr = xp + r*33;
    float cp = 0.f;
    #pragma unroll
    for (int i=0;i<4;i++){
      q[i] *= __expf(Aa[i]*dtv);
      const float Cv = xpr[17 + (nq<<2) + i];
      cp = fmaf(Cv*q[i], hi[i], cp);
    }
    cp += __shfl_xor(cp, 1);
    cp += __shfl_xor(cp, 2);
    if (nq == 0){
      const float zv = xz[r*XZL + 2048 + d];
      const float yv = (xz[r*XZL + d] + cp) * siluf(zv);
      const unsigned short h16 = f2bf(yv);
      yh[r*DI + d] = h16;
      yl[r*DI + d] = f2bf(yv - bf2f(h16));
    }
  }
}

extern "C" void kernel_launch(void* const* d_in, const int* in_sizes, int n_in,
                              void* d_out, int out_size, void* d_ws, size_t ws_size,
                              hipStream_t stream) {
  const float* x     = (const float*)d_in[0];
  const float* gamma = (const float*)d_in[1];
  const float* beta  = (const float*)d_in[2];
  const float* W_in  = (const float*)d_in[3];
  const float* cw    = (const float*)d_in[4];
  const float* cb    = (const float*)d_in[5];
  const float* Alog  = (const float*)d_in[6];
  const float* Dp    = (const float*)d_in[7];
  const float* Wx    = (const float*)d_in[8];
  const float* Wdt   = (const float*)d_in[9];
  const float* bdt   = (const float*)d_in[10];
  const float* Wout  = (const float*)d_in[11];
  float* out = (float*)d_out;
  float* ws  = (float*)d_ws;

  const size_t M1 = 1048576;
  float* xz   = ws;                 // 16M f32 (x-half -> y_loc after scan1; z-half)
  float* xsq  = ws + 16*M1;         // 8M f32 slot: xs_h (16MB) | y_l region
  float* dtb  = ws + 24*M1;         // 8M
  float* Pb   = ws + 32*M1;         // 4M
  float* Hb   = Pb + 4*M1;          // 4M
  float* xpb  = Hb + 4*M1;          // 135168
  float* wxzone = xpb + 135168;
  unsigned short* wx_h = (unsigned short*)wxzone;
  unsigned short* wx_l = wx_h + (size_t)NPAD*DI;
  unsigned short* zone = wx_l + (size_t)NPAD*DI;   // 16M ushort = 32MB
  unsigned short* xn_h = zone;
  unsigned short* xn_l = zone + 4*M1;
  unsigned short* Wi_h = zone + 8*M1;
  unsigned short* Wi_l = zone + 12*M1;
  unsigned short* Wo_h = zone;              // split AFTER gemm1 (overlays xn)
  unsigned short* Wo_l = zone + 2*M1;
  unsigned short* xs_h = (unsigned short*)xsq;          // 8M us = 16MB
  unsigned short* y_h  = (unsigned short*)xsq;          // in-place overlay of xs_h (scan3)
  unsigned short* y_l  = (unsigned short*)xsq + 8*M1;   // old xs_l slot

  ln_split_kernel<<<RTOT, 256, 0, stream>>>(x, gamma, beta, xn_h, xn_l);
  split_win_wx_kernel<<<(2*DI*DM/4 + NPAD*DI/4 + 255)/256, 256, 0, stream>>>(
      W_in, Wx, Wi_h, Wi_l, wx_h, wx_l);
  gemm_bf16x3<<<dim3(XZL/128, RTOT/128), 256, 0, stream>>>(xn_h, xn_l, Wi_h, Wi_l,
                                                           xz, RTOT, XZL, DM, XZL);
  split_kernel<<<(DM*DI/4 + 255)/256, 256, 0, stream>>>(Wout, Wo_h, Wo_l, DM*DI/4);
  conv_silu_h_kernel<<<(RTOT*(DI/4))/256, 256, 0, stream>>>(xz, cw, cb, xs_h);
  xp_dt_kernel<<<RTOT/16, 256, 0, stream>>>(xs_h, wx_h, wx_l, Wdt, bdt, xpb, dtb);
  scan1_kernel<<<(B_SZ*NC*DI*4)/256, 256, 0, stream>>>(xs_h, dtb, xpb, Alog, Dp, xz, Pb, Hb);
  scan2_kernel<<<(B_SZ*DI*NS)/256, 256, 0, stream>>>(Pb, Hb);
  scan3_kernel<<<(B_SZ*NC*DI*4)/256, 256, 0, stream>>>(dtb, xpb, Alog, Hb, xz, y_h, y_l);
  gemm_bf16x3_b64<<<dim3(DM/128, RTOT/64), 256, 0, stream>>>(y_h, y_l, Wo_h, Wo_l,
                                                             out, RTOT, DM, DI, DM);
}

// Round 10
// 378.028 us; speedup vs baseline: 1.2142x; 1.1342x over previous
//
#include <hip/hip_runtime.h>
#include <math.h>

// MambaSSMBlock: B=2, L=2048, Dm=1024, Di=2048, N=16, convK=4
// Round 10: GEMMs -> bf16x2 one-sided split (A = hi+lo, B = single bf16):
//   error budget measured in R9 (absmax 1.5e-5 of 8.24e-5) affords the
//   ~0.06%-relative W-rounding; MFMA work -33%, LDS staging -25% on both
//   top dispatches. Mid-structure byte-identical to R9.
// Workspace: ~193 MB.

#define B_SZ 2
#define LSEQ 2048
#define DM   1024
#define DI   2048
#define NS   16
#define RTOT (B_SZ*LSEQ)
#define NC   64
#define TC   (LSEQ/NC)
#define XZL  4096
#define NPAD 48

typedef __attribute__((ext_vector_type(8))) short bfrag;
typedef __attribute__((ext_vector_type(4))) float f32x4;

__device__ __forceinline__ float siluf(float v){ return v / (1.f + __expf(-v)); }

__device__ __forceinline__ unsigned short f2bf(float f){
  unsigned int u = __float_as_uint(f);
  u += 0x7FFFu + ((u >> 16) & 1u);
  return (unsigned short)(u >> 16);
}
__device__ __forceinline__ float bf2f(unsigned short h){
  return __uint_as_float(((unsigned int)h) << 16);
}

// ---------------- LayerNorm fused with bf16 hi/lo split ----------------
__global__ __launch_bounds__(256)
void ln_split_kernel(const float* __restrict__ x, const float* __restrict__ g,
                     const float* __restrict__ b,
                     unsigned short* __restrict__ xh, unsigned short* __restrict__ xl) {
  __shared__ float red[8];
  const int r = blockIdx.x, tid = threadIdx.x;
  const float4 v = ((const float4*)(x + (size_t)r*DM))[tid];
  float s  = v.x+v.y+v.z+v.w;
  float ss = v.x*v.x+v.y*v.y+v.z*v.z+v.w*v.w;
  #pragma unroll
  for (int off=32; off; off>>=1){ s += __shfl_xor(s,off); ss += __shfl_xor(ss,off); }
  if ((tid & 63)==0){ int w=tid>>6; red[w]=s; red[4+w]=ss; }
  __syncthreads();
  s  = red[0]+red[1]+red[2]+red[3];
  ss = red[4]+red[5]+red[6]+red[7];
  const float mu  = s*(1.f/DM);
  const float inv = rsqrtf(ss*(1.f/DM) - mu*mu + 1e-5f);
  const float4 gv = ((const float4*)g)[tid];
  const float4 bv = ((const float4*)b)[tid];
  float o[4];
  o[0] = (v.x-mu)*inv*gv.x + bv.x;
  o[1] = (v.y-mu)*inv*gv.y + bv.y;
  o[2] = (v.z-mu)*inv*gv.z + bv.z;
  o[3] = (v.w-mu)*inv*gv.w + bv.w;
  ushort4 h, l;
  h.x = f2bf(o[0]); l.x = f2bf(o[0] - bf2f(h.x));
  h.y = f2bf(o[1]); l.y = f2bf(o[1] - bf2f(h.y));
  h.z = f2bf(o[2]); l.z = f2bf(o[2] - bf2f(h.z));
  h.w = f2bf(o[3]); l.w = f2bf(o[3] - bf2f(h.w));
  ((ushort4*)(xh + (size_t)r*DM))[tid] = h;
  ((ushort4*)(xl + (size_t)r*DM))[tid] = l;
}

// ---------------- merged W_in(hi only) + Wx(pad48, hi/lo) split ----------------
__global__ __launch_bounds__(256)
void split_win_wx_kernel(const float* __restrict__ Win, const float* __restrict__ Wx,
                         unsigned short* __restrict__ wih,
                         unsigned short* __restrict__ wxh, unsigned short* __restrict__ wxl) {
  const int NWIN = 2*DI*DM/4;           // 1048576 float4
  const int NWX  = NPAD*DI/4;           // 24576 float4
  const int i = blockIdx.x*256 + threadIdx.x;
  if (i < NWIN){
    const float4 v = ((const float4*)Win)[i];
    ushort4 h;
    h.x = f2bf(v.x); h.y = f2bf(v.y); h.z = f2bf(v.z); h.w = f2bf(v.w);
    ((ushort4*)wih)[i] = h;
  } else if (i < NWIN + NWX){
    const int j = i - NWIN;
    const int row = j >> 9;
    float4 v = make_float4(0.f,0.f,0.f,0.f);
    if (row < 33) v = ((const float4*)Wx)[j];
    ushort4 h, l;
    h.x = f2bf(v.x); l.x = f2bf(v.x - bf2f(h.x));
    h.y = f2bf(v.y); l.y = f2bf(v.y - bf2f(h.y));
    h.z = f2bf(v.z); l.z = f2bf(v.z - bf2f(h.z));
    h.w = f2bf(v.w); l.w = f2bf(v.w - bf2f(h.w));
    ((ushort4*)wxh)[j] = h;
    ((ushort4*)wxl)[j] = l;
  }
}

// ---------------- fp32 -> single bf16 (Wout) ----------------
__global__ __launch_bounds__(256)
void split_hi_kernel(const float* __restrict__ in, unsigned short* __restrict__ hi, int n4) {
  const int i = blockIdx.x*256 + threadIdx.x;
  if (i >= n4) return;
  const float4 v = ((const float4*)in)[i];
  ushort4 h;
  h.x = f2bf(v.x); h.y = f2bf(v.y); h.z = f2bf(v.z); h.w = f2bf(v.w);
  ((ushort4*)hi)[i] = h;
}

// ---------------- bf16x2 MFMA GEMM 128x128: C = (Ah+Al) * Bh^T ----------------
// 3 LDS buffers (30.7KB), 12 ds_read_b128 / 32 MFMA per K-tile per wave.
__global__ __launch_bounds__(256)
void gemm_bf16x2(const unsigned short* __restrict__ Ah, const unsigned short* __restrict__ Al,
                 const unsigned short* __restrict__ Bh,
                 float* __restrict__ C, int M, int N, int K, int ldc)
{
  __shared__ __align__(16) unsigned short lds[3][128][40];
  const int tid = threadIdx.x;
  const int bm = blockIdx.y << 7;
  const int bn = blockIdx.x << 7;
  const int wave = tid >> 6;
  const int lane = tid & 63;
  const int wm = (wave >> 1) << 6;
  const int wn = (wave & 1) << 6;
  const int fr = lane & 15;
  const int kg = lane >> 4;
  const int srow = tid >> 1;
  const int scol = (tid & 1) << 4;

  const unsigned short* pAh = Ah + (size_t)(bm + srow)*K + scol;
  const unsigned short* pAl = Al + (size_t)(bm + srow)*K + scol;
  const unsigned short* pBh = Bh + (size_t)(bn + srow)*K + scol;

  f32x4 acc[4][4];
  #pragma unroll
  for (int m=0;m<4;m++)
    #pragma unroll
    for (int n=0;n<4;n++)
      #pragma unroll
      for (int r=0;r<4;r++) acc[m][n][r] = 0.f;

  uint4 ra0, ra1, rb0, rb1, rc0, rc1;
#define LOAD6(k0) do { \
    ra0 = *(const uint4*)(pAh + (k0));     ra1 = *(const uint4*)(pAh + (k0) + 8); \
    rb0 = *(const uint4*)(pAl + (k0));     rb1 = *(const uint4*)(pAl + (k0) + 8); \
    rc0 = *(const uint4*)(pBh + (k0));     rc1 = *(const uint4*)(pBh + (k0) + 8); \
  } while(0)

  const int nIter = K >> 5;
  LOAD6(0);
  for (int it = 0; it < nIter; ++it) {
    __syncthreads();
    *(uint4*)&lds[0][srow][scol] = ra0;  *(uint4*)&lds[0][srow][scol+8] = ra1;
    *(uint4*)&lds[1][srow][scol] = rb0;  *(uint4*)&lds[1][srow][scol+8] = rb1;
    *(uint4*)&lds[2][srow][scol] = rc0;  *(uint4*)&lds[2][srow][scol+8] = rc1;
    __syncthreads();
    if (it + 1 < nIter) LOAD6((size_t)(it+1) << 5);

    bfrag ah[4], al[4], bb[4];
    #pragma unroll
    for (int m=0;m<4;m++){
      ah[m] = *(const bfrag*)&lds[0][wm + (m<<4) + fr][kg<<3];
      al[m] = *(const bfrag*)&lds[1][wm + (m<<4) + fr][kg<<3];
    }
    #pragma unroll
    for (int n=0;n<4;n++) bb[n] = *(const bfrag*)&lds[2][wn + (n<<4) + fr][kg<<3];
    #pragma unroll
    for (int m=0;m<4;m++)
      #pragma unroll
      for (int n=0;n<4;n++){
        acc[m][n] = __builtin_amdgcn_mfma_f32_16x16x32_bf16(ah[m], bb[n], acc[m][n], 0, 0, 0);
        acc[m][n] = __builtin_amdgcn_mfma_f32_16x16x32_bf16(al[m], bb[n], acc[m][n], 0, 0, 0);
      }
  }
#undef LOAD6

  #pragma unroll
  for (int m=0;m<4;m++)
    #pragma unroll
    for (int n=0;n<4;n++){
      float* Cp = C + (size_t)(bm + wm + (m<<4) + (kg<<2))*ldc + bn + wn + (n<<4) + fr;
      #pragma unroll
      for (int r=0;r<4;r++) Cp[(size_t)r*ldc] = acc[m][n][r];
    }
}

// ---------------- bf16x2 MFMA GEMM 64x128 tile, full-K (out GEMM) ----------------
__global__ __launch_bounds__(256)
void gemm_bf16x2_b64(const unsigned short* __restrict__ Ah, const unsigned short* __restrict__ Al,
                     const unsigned short* __restrict__ Bh,
                     float* __restrict__ C, int M, int N, int K, int ldc)
{
  __shared__ __align__(16) unsigned short ldsA[2][64][40];
  __shared__ __align__(16) unsigned short ldsB[128][40];
  const int tid = threadIdx.x;
  const int bm = blockIdx.y << 6;
  const int bn = blockIdx.x << 7;
  const int wave = tid >> 6;
  const int lane = tid & 63;
  const int wm = (wave >> 1) << 5;
  const int wn = (wave & 1) << 6;
  const int fr = lane & 15;
  const int kg = lane >> 4;
  const int arow = tid >> 2, acol = (tid & 3) << 3;
  const int brow = tid >> 1, bcol = (tid & 1) << 4;

  const unsigned short* pAh = Ah + (size_t)(bm + arow)*K + acol;
  const unsigned short* pAl = Al + (size_t)(bm + arow)*K + acol;
  const unsigned short* pBh = Bh + (size_t)(bn + brow)*K + bcol;

  f32x4 acc[2][4];
  #pragma unroll
  for (int m=0;m<2;m++)
    #pragma unroll
    for (int n=0;n<4;n++)
      #pragma unroll
      for (int r=0;r<4;r++) acc[m][n][r] = 0.f;

  uint4 ra, rb, rc0, rc1;
#define LOAD4(k0) do { \
    ra  = *(const uint4*)(pAh + (k0)); \
    rb  = *(const uint4*)(pAl + (k0)); \
    rc0 = *(const uint4*)(pBh + (k0));  rc1 = *(const uint4*)(pBh + (k0) + 8); \
  } while(0)

  const int nIter = K >> 5;
  LOAD4(0);
  for (int it = 0; it < nIter; ++it) {
    __syncthreads();
    *(uint4*)&ldsA[0][arow][acol] = ra;
    *(uint4*)&ldsA[1][arow][acol] = rb;
    *(uint4*)&ldsB[brow][bcol] = rc0;  *(uint4*)&ldsB[brow][bcol+8] = rc1;
    __syncthreads();
    if (it + 1 < nIter) LOAD4((size_t)(it+1) << 5);

    bfrag ah[2], al[2], bh[4];
    #pragma unroll
    for (int m=0;m<2;m++){
      ah[m] = *(const bfrag*)&ldsA[0][wm + (m<<4) + fr][kg<<3];
      al[m] = *(const bfrag*)&ldsA[1][wm + (m<<4) + fr][kg<<3];
    }
    #pragma unroll
    for (int n=0;n<4;n++) bh[n] = *(const bfrag*)&ldsB[wn + (n<<4) + fr][kg<<3];
    #pragma unroll
    for (int m=0;m<2;m++)
      #pragma unroll
      for (int n=0;n<4;n++){
        acc[m][n] = __builtin_amdgcn_mfma_f32_16x16x32_bf16(ah[m], bh[n], acc[m][n], 0, 0, 0);
        acc[m][n] = __builtin_amdgcn_mfma_f32_16x16x32_bf16(al[m], bh[n], acc[m][n], 0, 0, 0);
      }
  }
#undef LOAD4

  #pragma unroll
  for (int m=0;m<2;m++)
    #pragma unroll
    for (int n=0;n<4;n++){
      float* Cp = C + (size_t)(bm + wm + (m<<4) + (kg<<2))*ldc + bn + wn + (n<<4) + fr;
      #pragma unroll
      for (int r=0;r<4;r++) Cp[(size_t)r*ldc] = acc[m][n][r];
    }
}

// ---------------- depthwise causal conv K=4 + bias + SiLU -> single bf16 ----------------
__global__ __launch_bounds__(256)
void conv_silu_h_kernel(const float* __restrict__ xz, const float* __restrict__ cw,
                        const float* __restrict__ cb, unsigned short* __restrict__ xsh) {
  const int idx = blockIdx.x * 256 + threadIdx.x;
  const int d4 = idx & (DI/4 - 1);
  const int r  = idx >> 9;
  const int b  = r >> 11;
  const int t  = r & (LSEQ-1);
  const int d  = d4 << 2;
  const float4 w0 = *(const float4*)(cw + (size_t)(d+0)*4);
  const float4 w1 = *(const float4*)(cw + (size_t)(d+1)*4);
  const float4 w2 = *(const float4*)(cw + (size_t)(d+2)*4);
  const float4 w3 = *(const float4*)(cw + (size_t)(d+3)*4);
  const float wk[4][4] = {{w0.x,w1.x,w2.x,w3.x},{w0.y,w1.y,w2.y,w3.y},
                          {w0.z,w1.z,w2.z,w3.z},{w0.w,w1.w,w2.w,w3.w}};
  float4 acc = *(const float4*)(cb + d);
  #pragma unroll
  for (int k=0;k<4;k++){
    const int tt = t - 3 + k;
    if (tt < 0) continue;
    const float4 xv = *(const float4*)(xz + ((size_t)b*LSEQ + tt)*XZL + d);
    acc.x = fmaf(wk[k][0], xv.x, acc.x);
    acc.y = fmaf(wk[k][1], xv.y, acc.y);
    acc.z = fmaf(wk[k][2], xv.z, acc.z);
    acc.w = fmaf(wk[k][3], xv.w, acc.w);
  }
  ushort4 h;
  h.x = f2bf(siluf(acc.x));
  h.y = f2bf(siluf(acc.y));
  h.z = f2bf(siluf(acc.z));
  h.w = f2bf(siluf(acc.w));
  *(ushort4*)(xsh + (size_t)r*DI + d) = h;
}

// ---------------- xp (K-split MFMA, LDS-reduce) + fused dt ----------------
__global__ __launch_bounds__(256)
void xp_dt_kernel(const unsigned short* __restrict__ xsh,
                  const unsigned short* __restrict__ wxh, const unsigned short* __restrict__ wxl,
                  const float* __restrict__ Wdt, const float* __restrict__ bdt,
                  float* __restrict__ xp, float* __restrict__ dtb) {
  __shared__ float red[4][64][12];
  __shared__ float xp_lds[16][34];
  __shared__ float wl[256*33 + 8];
  const int tid = threadIdx.x;
  const int wave = tid >> 6, lane = tid & 63;
  const int fr = lane & 15, kg = lane >> 4;
  const int m0 = blockIdx.x << 4;
  const size_t koff = (size_t)wave << 9;

  const unsigned short* pah = xsh + (size_t)(m0 + fr)*DI + (kg<<3) + koff;
  const unsigned short* pbh = wxh + (size_t)fr*DI + (kg<<3) + koff;
  const unsigned short* pbl = wxl + (size_t)fr*DI + (kg<<3) + koff;

  f32x4 acc[3];
  #pragma unroll
  for (int nf=0;nf<3;nf++)
    #pragma unroll
    for (int r=0;r<4;r++) acc[nf][r] = 0.f;

  for (int kk = 0; kk < 512; kk += 32) {
    const bfrag ah = *(const bfrag*)(pah + kk);
    #pragma unroll
    for (int nf=0;nf<3;nf++){
      const bfrag bh = *(const bfrag*)(pbh + (size_t)nf*16*DI + kk);
      const bfrag bl = *(const bfrag*)(pbl + (size_t)nf*16*DI + kk);
      acc[nf] = __builtin_amdgcn_mfma_f32_16x16x32_bf16(ah, bh, acc[nf], 0, 0, 0);
      acc[nf] = __builtin_amdgcn_mfma_f32_16x16x32_bf16(ah, bl, acc[nf], 0, 0, 0);
    }
  }
  #pragma unroll
  for (int nf=0;nf<3;nf++)
    #pragma unroll
    for (int r=0;r<4;r++) red[wave][lane][nf*4+r] = acc[nf][r];
  __syncthreads();
  if (wave == 0){
    #pragma unroll
    for (int nf=0;nf<3;nf++){
      const int col = (nf<<4) + fr;
      #pragma unroll
      for (int r=0;r<4;r++){
        const float v = red[0][lane][nf*4+r] + red[1][lane][nf*4+r]
                      + red[2][lane][nf*4+r] + red[3][lane][nf*4+r];
        if (col < 33){
          const int row = (kg<<2) + r;
          xp_lds[row][col] = v;
          xp[(size_t)(m0 + row)*33 + col] = v;
        }
      }
    }
  }
  __syncthreads();
  for (int j=0;j<8;j++){
    const int d0 = j << 8;
    for (int i = tid; i < 256*33; i += 256) wl[i] = Wdt[(size_t)d0*33 + i];
    __syncthreads();
    const float bv = bdt[d0 + tid];
    const float* wrow = &wl[tid*33];
    #pragma unroll
    for (int row=0; row<16; ++row){
      float s = bv;
      #pragma unroll
      for (int k=0;k<33;k++) s = fmaf(xp_lds[row][k], wrow[k], s);
      const float sp = (s > 20.f) ? s : log1pf(__expf(s));
      dtb[(size_t)(m0 + row)*DI + d0 + tid] = sp + 0.001f;
    }
    __syncthreads();
  }
}

// ---------------- scan pass 1: local chunk scan -> y_loc (xz x-half), P, H ----------------
__global__ __launch_bounds__(256)
void scan1_kernel(const unsigned short* __restrict__ xsh, const float* __restrict__ dt,
                  const float* __restrict__ xp, const float* __restrict__ Alog,
                  const float* __restrict__ Dp,
                  float* __restrict__ y, float* __restrict__ Pbuf, float* __restrict__ Hbuf) {
  const int g  = blockIdx.x*256 + threadIdx.x;
  const int nq = g & 3;
  const int g2 = g >> 2;
  const int d  = g2 & (DI-1);
  const int bc = g2 >> 11;
  const int c  = bc & (NC-1);
  const int b  = bc >> 6;
  const float4 al = *(const float4*)(Alog + (size_t)d*NS + (nq<<2));
  const float Aa[4] = {-__expf(al.x), -__expf(al.y), -__expf(al.z), -__expf(al.w)};
  float rA[4];
  #pragma unroll
  for (int i=0;i<4;i++) rA[i] = 1.f/(Aa[i] + 1e-8f);
  const float Dv = Dp[d];
  float h[4] = {0,0,0,0};
  float P[4] = {1,1,1,1};
  const int t0 = c * TC;
  for (int t = t0; t < t0 + TC; ++t){
    const size_t r = (size_t)b*LSEQ + t;
    const float dtv = dt[r*DI + d];
    const float xv  = bf2f(xsh[r*DI + d]);
    const float* xpr = xp + r*33;
    float yp = 0.f;
    #pragma unroll
    for (int i=0;i<4;i++){
      const int n = (nq<<2) + i;
      const float e = __expf(Aa[i]*dtv);
      P[i] *= e;
      const float Bv = xpr[1 + n];
      const float Cv = xpr[17 + n];
      const float gbx = rA[i] * (1.f - e) * Bv * xv;
      h[i] = fmaf(e, h[i], gbx);
      h[i] = fminf(10.f, fmaxf(-10.f, h[i]));
      yp = fmaf(Cv, h[i], yp);
    }
    yp += __shfl_xor(yp, 1);
    yp += __shfl_xor(yp, 2);
    if (nq == 0) y[r*XZL + d] = yp + Dv*xv;
  }
  const size_t pb = (((size_t)c*B_SZ + b)*DI + d)*NS + (nq<<2);
  *(float4*)(Pbuf+pb) = make_float4(P[0],P[1],P[2],P[3]);
  *(float4*)(Hbuf+pb) = make_float4(h[0],h[1],h[2],h[3]);
}

// ---------------- scan pass 2: sequential chunk combine; hin folded into Hbuf ----
__global__ __launch_bounds__(256)
void scan2_kernel(const float* __restrict__ Pbuf, float* __restrict__ Hbuf) {
  const int g = blockIdx.x*256 + threadIdx.x;
  const size_t cs = (size_t)B_SZ*DI*NS;
  float h = 0.f;
  for (int c=1;c<NC;++c){
    const float Pv = Pbuf[(size_t)(c-1)*cs + g];
    const float Hv = Hbuf[(size_t)(c-1)*cs + g];
    h = fmaf(Pv, h, Hv);
    Hbuf[(size_t)(c-1)*cs + g] = h;
  }
}

// ---------------- scan pass 3: light cross-chunk correction + silu(z) + y split ----
__global__ __launch_bounds__(256)
void scan3_kernel(const float* __restrict__ dt, const float* __restrict__ xp,
                  const float* __restrict__ Alog, const float* __restrict__ hinb,
                  const float* __restrict__ xz,
                  unsigned short* __restrict__ yh, unsigned short* __restrict__ yl) {
  const int g  = blockIdx.x*256 + threadIdx.x;
  const int nq = g & 3;
  const int g2 = g >> 2;
  const int d  = g2 & (DI-1);
  const int bc = g2 >> 11;
  const int c  = bc & (NC-1);
  const int b  = bc >> 6;
  const float4 al = *(const float4*)(Alog + (size_t)d*NS + (nq<<2));
  const float Aa[4] = {-__expf(al.x), -__expf(al.y), -__expf(al.z), -__expf(al.w)};
  float hi[4] = {0.f, 0.f, 0.f, 0.f};
  if (c > 0){
    const size_t pb = (((size_t)(c-1)*B_SZ + b)*DI + d)*NS + (nq<<2);
    const float4 hv = *(const float4*)(hinb + pb);
    hi[0]=hv.x; hi[1]=hv.y; hi[2]=hv.z; hi[3]=hv.w;
  }
  float q[4] = {1,1,1,1};
  const int t0 = c * TC;
  for (int t = t0; t < t0 + TC; ++t){
    const size_t r = (size_t)b*LSEQ + t;
    const float dtv = dt[r*DI + d];
    const float* xpr = xp + r*33;
    float cp = 0.f;
    #pragma unroll
    for (int i=0;i<4;i++){
      q[i] *= __expf(Aa[i]*dtv);
      const float Cv = xpr[17 + (nq<<2) + i];
      cp = fmaf(Cv*q[i], hi[i], cp);
    }
    cp += __shfl_xor(cp, 1);
    cp += __shfl_xor(cp, 2);
    if (nq == 0){
      const float zv = xz[r*XZL + 2048 + d];
      const float yv = (xz[r*XZL + d] + cp) * siluf(zv);
      const unsigned short h16 = f2bf(yv);
      yh[r*DI + d] = h16;
      yl[r*DI + d] = f2bf(yv - bf2f(h16));
    }
  }
}

extern "C" void kernel_launch(void* const* d_in, const int* in_sizes, int n_in,
                              void* d_out, int out_size, void* d_ws, size_t ws_size,
                              hipStream_t stream) {
  const float* x     = (const float*)d_in[0];
  const float* gamma = (const float*)d_in[1];
  const float* beta  = (const float*)d_in[2];
  const float* W_in  = (const float*)d_in[3];
  const float* cw    = (const float*)d_in[4];
  const float* cb    = (const float*)d_in[5];
  const float* Alog  = (const float*)d_in[6];
  const float* Dp    = (const float*)d_in[7];
  const float* Wx    = (const float*)d_in[8];
  const float* Wdt   = (const float*)d_in[9];
  const float* bdt   = (const float*)d_in[10];
  const float* Wout  = (const float*)d_in[11];
  float* out = (float*)d_out;
  float* ws  = (float*)d_ws;

  const size_t M1 = 1048576;
  float* xz   = ws;                 // 16M f32
  float* xsq  = ws + 16*M1;         // 8M f32 slot: xs_h | y_h/y_l overlay
  float* dtb  = ws + 24*M1;         // 8M
  float* Pb   = ws + 32*M1;         // 4M
  float* Hb   = Pb + 4*M1;          // 4M
  float* xpb  = Hb + 4*M1;          // 135168
  float* wxzone = xpb + 135168;
  unsigned short* wx_h = (unsigned short*)wxzone;
  unsigned short* wx_l = wx_h + (size_t)NPAD*DI;
  unsigned short* zone = wx_l + (size_t)NPAD*DI;   // 16M ushort = 32MB
  unsigned short* xn_h = zone;              // 4M us
  unsigned short* xn_l = zone + 4*M1;       // 4M us
  unsigned short* Wi_h = zone + 8*M1;       // 4M us (hi only)
  unsigned short* Wo_h = zone;              // 2M us (split AFTER gemm1, overlays xn_h)
  unsigned short* xs_h = (unsigned short*)xsq;          // 8M us
  unsigned short* y_h  = (unsigned short*)xsq;          // overlay (scan3 writes in place)
  unsigned short* y_l  = (unsigned short*)xsq + 8*M1;

  ln_split_kernel<<<RTOT, 256, 0, stream>>>(x, gamma, beta, xn_h, xn_l);
  split_win_wx_kernel<<<(2*DI*DM/4 + NPAD*DI/4 + 255)/256, 256, 0, stream>>>(
      W_in, Wx, Wi_h, wx_h, wx_l);
  // xz = (xn_h + xn_l) @ Wi_h^T
  gemm_bf16x2<<<dim3(XZL/128, RTOT/128), 256, 0, stream>>>(xn_h, xn_l, Wi_h,
                                                           xz, RTOT, XZL, DM, XZL);
  split_hi_kernel<<<(DM*DI/4 + 255)/256, 256, 0, stream>>>(Wout, Wo_h, DM*DI/4);
  conv_silu_h_kernel<<<(RTOT*(DI/4))/256, 256, 0, stream>>>(xz, cw, cb, xs_h);
  xp_dt_kernel<<<RTOT/16, 256, 0, stream>>>(xs_h, wx_h, wx_l, Wdt, bdt, xpb, dtb);
  scan1_kernel<<<(B_SZ*NC*DI*4)/256, 256, 0, stream>>>(xs_h, dtb, xpb, Alog, Dp, xz, Pb, Hb);
  scan2_kernel<<<(B_SZ*DI*NS)/256, 256, 0, stream>>>(Pb, Hb);
  scan3_kernel<<<(B_SZ*NC*DI*4)/256, 256, 0, stream>>>(dtb, xpb, Alog, Hb, xz, y_h, y_l);
  // out = (y_h + y_l) @ Wo_h^T
  gemm_bf16x2_b64<<<dim3(DM/128, RTOT/64), 256, 0, stream>>>(y_h, y_l, Wo_h,
                                                             out, RTOT, DM, DI, DM);
}

// Round 11
// 345.424 us; speedup vs baseline: 1.3288x; 1.0944x over previous
//
#include <hip/hip_runtime.h>
#include <math.h>

// MambaSSMBlock: B=2, L=2048, Dm=1024, Di=2048, N=16, convK=4
// Round 11: xp_dt_kernel (100us, 1 block/CU, LDS-serial dt phase) split:
//   (1) xp_kernel = MFMA K-split only, + bf16 hi/lo padded xp[4096][64] emit;
//   (2) dt = softplus(xp @ Wdt^T + b) as 128^2 bf16x3 MFMA GEMM, K=64-pad,
//       fused bias+softplus epilogue (512 blocks = 2/CU).
// Everything else byte-identical to R10. Workspace ~187 MB.

#define B_SZ 2
#define LSEQ 2048
#define DM   1024
#define DI   2048
#define NS   16
#define RTOT (B_SZ*LSEQ)
#define NC   64
#define TC   (LSEQ/NC)
#define XZL  4096
#define NPAD 48
#define KDT  64     // padded K for dt GEMM

typedef __attribute__((ext_vector_type(8))) short bfrag;
typedef __attribute__((ext_vector_type(4))) float f32x4;

__device__ __forceinline__ float siluf(float v){ return v / (1.f + __expf(-v)); }

__device__ __forceinline__ unsigned short f2bf(float f){
  unsigned int u = __float_as_uint(f);
  u += 0x7FFFu + ((u >> 16) & 1u);
  return (unsigned short)(u >> 16);
}
__device__ __forceinline__ float bf2f(unsigned short h){
  return __uint_as_float(((unsigned int)h) << 16);
}

// ---------------- LayerNorm fused with bf16 hi/lo split ----------------
__global__ __launch_bounds__(256)
void ln_split_kernel(const float* __restrict__ x, const float* __restrict__ g,
                     const float* __restrict__ b,
                     unsigned short* __restrict__ xh, unsigned short* __restrict__ xl) {
  __shared__ float red[8];
  const int r = blockIdx.x, tid = threadIdx.x;
  const float4 v = ((const float4*)(x + (size_t)r*DM))[tid];
  float s  = v.x+v.y+v.z+v.w;
  float ss = v.x*v.x+v.y*v.y+v.z*v.z+v.w*v.w;
  #pragma unroll
  for (int off=32; off; off>>=1){ s += __shfl_xor(s,off); ss += __shfl_xor(ss,off); }
  if ((tid & 63)==0){ int w=tid>>6; red[w]=s; red[4+w]=ss; }
  __syncthreads();
  s  = red[0]+red[1]+red[2]+red[3];
  ss = red[4]+red[5]+red[6]+red[7];
  const float mu  = s*(1.f/DM);
  const float inv = rsqrtf(ss*(1.f/DM) - mu*mu + 1e-5f);
  const float4 gv = ((const float4*)g)[tid];
  const float4 bv = ((const float4*)b)[tid];
  float o[4];
  o[0] = (v.x-mu)*inv*gv.x + bv.x;
  o[1] = (v.y-mu)*inv*gv.y + bv.y;
  o[2] = (v.z-mu)*inv*gv.z + bv.z;
  o[3] = (v.w-mu)*inv*gv.w + bv.w;
  ushort4 h, l;
  h.x = f2bf(o[0]); l.x = f2bf(o[0] - bf2f(h.x));
  h.y = f2bf(o[1]); l.y = f2bf(o[1] - bf2f(h.y));
  h.z = f2bf(o[2]); l.z = f2bf(o[2] - bf2f(h.z));
  h.w = f2bf(o[3]); l.w = f2bf(o[3] - bf2f(h.w));
  ((ushort4*)(xh + (size_t)r*DM))[tid] = h;
  ((ushort4*)(xl + (size_t)r*DM))[tid] = l;
}

// ---------------- merged W_in(hi only) + Wx(pad48, hi/lo) split ----------------
__global__ __launch_bounds__(256)
void split_win_wx_kernel(const float* __restrict__ Win, const float* __restrict__ Wx,
                         unsigned short* __restrict__ wih,
                         unsigned short* __restrict__ wxh, unsigned short* __restrict__ wxl) {
  const int NWIN = 2*DI*DM/4;
  const int NWX  = NPAD*DI/4;
  const int i = blockIdx.x*256 + threadIdx.x;
  if (i < NWIN){
    const float4 v = ((const float4*)Win)[i];
    ushort4 h;
    h.x = f2bf(v.x); h.y = f2bf(v.y); h.z = f2bf(v.z); h.w = f2bf(v.w);
    ((ushort4*)wih)[i] = h;
  } else if (i < NWIN + NWX){
    const int j = i - NWIN;
    const int row = j >> 9;
    float4 v = make_float4(0.f,0.f,0.f,0.f);
    if (row < 33) v = ((const float4*)Wx)[j];
    ushort4 h, l;
    h.x = f2bf(v.x); l.x = f2bf(v.x - bf2f(h.x));
    h.y = f2bf(v.y); l.y = f2bf(v.y - bf2f(h.y));
    h.z = f2bf(v.z); l.z = f2bf(v.z - bf2f(h.z));
    h.w = f2bf(v.w); l.w = f2bf(v.w - bf2f(h.w));
    ((ushort4*)wxh)[j] = h;
    ((ushort4*)wxl)[j] = l;
  }
}

// ---------------- Wdt [2048][33] -> padded [2048][64] bf16 hi/lo ----------------
__global__ __launch_bounds__(256)
void split_pad_wdt_kernel(const float* __restrict__ Wdt,
                          unsigned short* __restrict__ wdh, unsigned short* __restrict__ wdl) {
  const int i = blockIdx.x*256 + threadIdx.x;   // over 2048*64
  if (i >= DI*KDT) return;
  const int row = i >> 6, col = i & 63;
  float v = (col < 33) ? Wdt[(size_t)row*33 + col] : 0.f;
  const unsigned short h = f2bf(v);
  wdh[i] = h;
  wdl[i] = f2bf(v - bf2f(h));
}

// ---------------- fp32 -> single bf16 (Wout) ----------------
__global__ __launch_bounds__(256)
void split_hi_kernel(const float* __restrict__ in, unsigned short* __restrict__ hi, int n4) {
  const int i = blockIdx.x*256 + threadIdx.x;
  if (i >= n4) return;
  const float4 v = ((const float4*)in)[i];
  ushort4 h;
  h.x = f2bf(v.x); h.y = f2bf(v.y); h.z = f2bf(v.z); h.w = f2bf(v.w);
  ((ushort4*)hi)[i] = h;
}

// ---------------- bf16x2 MFMA GEMM 128x128: C = (Ah+Al) * Bh^T ----------------
__global__ __launch_bounds__(256)
void gemm_bf16x2(const unsigned short* __restrict__ Ah, const unsigned short* __restrict__ Al,
                 const unsigned short* __restrict__ Bh,
                 float* __restrict__ C, int M, int N, int K, int ldc)
{
  __shared__ __align__(16) unsigned short lds[3][128][40];
  const int tid = threadIdx.x;
  const int bm = blockIdx.y << 7;
  const int bn = blockIdx.x << 7;
  const int wave = tid >> 6;
  const int lane = tid & 63;
  const int wm = (wave >> 1) << 6;
  const int wn = (wave & 1) << 6;
  const int fr = lane & 15;
  const int kg = lane >> 4;
  const int srow = tid >> 1;
  const int scol = (tid & 1) << 4;

  const unsigned short* pAh = Ah + (size_t)(bm + srow)*K + scol;
  const unsigned short* pAl = Al + (size_t)(bm + srow)*K + scol;
  const unsigned short* pBh = Bh + (size_t)(bn + srow)*K + scol;

  f32x4 acc[4][4];
  #pragma unroll
  for (int m=0;m<4;m++)
    #pragma unroll
    for (int n=0;n<4;n++)
      #pragma unroll
      for (int r=0;r<4;r++) acc[m][n][r] = 0.f;

  uint4 ra0, ra1, rb0, rb1, rc0, rc1;
#define LOAD6(k0) do { \
    ra0 = *(const uint4*)(pAh + (k0));     ra1 = *(const uint4*)(pAh + (k0) + 8); \
    rb0 = *(const uint4*)(pAl + (k0));     rb1 = *(const uint4*)(pAl + (k0) + 8); \
    rc0 = *(const uint4*)(pBh + (k0));     rc1 = *(const uint4*)(pBh + (k0) + 8); \
  } while(0)

  const int nIter = K >> 5;
  LOAD6(0);
  for (int it = 0; it < nIter; ++it) {
    __syncthreads();
    *(uint4*)&lds[0][srow][scol] = ra0;  *(uint4*)&lds[0][srow][scol+8] = ra1;
    *(uint4*)&lds[1][srow][scol] = rb0;  *(uint4*)&lds[1][srow][scol+8] = rb1;
    *(uint4*)&lds[2][srow][scol] = rc0;  *(uint4*)&lds[2][srow][scol+8] = rc1;
    __syncthreads();
    if (it + 1 < nIter) LOAD6((size_t)(it+1) << 5);

    bfrag ah[4], al[4], bb[4];
    #pragma unroll
    for (int m=0;m<4;m++){
      ah[m] = *(const bfrag*)&lds[0][wm + (m<<4) + fr][kg<<3];
      al[m] = *(const bfrag*)&lds[1][wm + (m<<4) + fr][kg<<3];
    }
    #pragma unroll
    for (int n=0;n<4;n++) bb[n] = *(const bfrag*)&lds[2][wn + (n<<4) + fr][kg<<3];
    #pragma unroll
    for (int m=0;m<4;m++)
      #pragma unroll
      for (int n=0;n<4;n++){
        acc[m][n] = __builtin_amdgcn_mfma_f32_16x16x32_bf16(ah[m], bb[n], acc[m][n], 0, 0, 0);
        acc[m][n] = __builtin_amdgcn_mfma_f32_16x16x32_bf16(al[m], bb[n], acc[m][n], 0, 0, 0);
      }
  }
#undef LOAD6

  #pragma unroll
  for (int m=0;m<4;m++)
    #pragma unroll
    for (int n=0;n<4;n++){
      float* Cp = C + (size_t)(bm + wm + (m<<4) + (kg<<2))*ldc + bn + wn + (n<<4) + fr;
      #pragma unroll
      for (int r=0;r<4;r++) Cp[(size_t)r*ldc] = acc[m][n][r];
    }
}

// ---------------- dt GEMM: dt = softplus((xph+xpl) @ (wdh+wdl)^T + b) + 1e-3 ----
// 128x128 tile, K=64 (nIter=2), bf16x3, fused bias+softplus epilogue.
__global__ __launch_bounds__(256)
void gemm_dt(const unsigned short* __restrict__ Ah, const unsigned short* __restrict__ Al,
             const unsigned short* __restrict__ Bh, const unsigned short* __restrict__ Bl,
             const float* __restrict__ bdt, float* __restrict__ dtb)
{
  __shared__ __align__(16) unsigned short lds[4][128][40];
  const int tid = threadIdx.x;
  const int bm = blockIdx.y << 7;
  const int bn = blockIdx.x << 7;
  const int wave = tid >> 6;
  const int lane = tid & 63;
  const int wm = (wave >> 1) << 6;
  const int wn = (wave & 1) << 6;
  const int fr = lane & 15;
  const int kg = lane >> 4;
  const int srow = tid >> 1;
  const int scol = (tid & 1) << 4;

  const unsigned short* pAh = Ah + (size_t)(bm + srow)*KDT + scol;
  const unsigned short* pAl = Al + (size_t)(bm + srow)*KDT + scol;
  const unsigned short* pBh = Bh + (size_t)(bn + srow)*KDT + scol;
  const unsigned short* pBl = Bl + (size_t)(bn + srow)*KDT + scol;

  f32x4 acc[4][4];
  #pragma unroll
  for (int m=0;m<4;m++)
    #pragma unroll
    for (int n=0;n<4;n++)
      #pragma unroll
      for (int r=0;r<4;r++) acc[m][n][r] = 0.f;

  uint4 ra0, ra1, rb0, rb1, rc0, rc1, rd0, rd1;
#define LOAD8(k0) do { \
    ra0 = *(const uint4*)(pAh + (k0));     ra1 = *(const uint4*)(pAh + (k0) + 8); \
    rb0 = *(const uint4*)(pAl + (k0));     rb1 = *(const uint4*)(pAl + (k0) + 8); \
    rc0 = *(const uint4*)(pBh + (k0));     rc1 = *(const uint4*)(pBh + (k0) + 8); \
    rd0 = *(const uint4*)(pBl + (k0));     rd1 = *(const uint4*)(pBl + (k0) + 8); \
  } while(0)

  LOAD8(0);
  #pragma unroll
  for (int it = 0; it < 2; ++it) {
    __syncthreads();
    *(uint4*)&lds[0][srow][scol] = ra0;  *(uint4*)&lds[0][srow][scol+8] = ra1;
    *(uint4*)&lds[1][srow][scol] = rb0;  *(uint4*)&lds[1][srow][scol+8] = rb1;
    *(uint4*)&lds[2][srow][scol] = rc0;  *(uint4*)&lds[2][srow][scol+8] = rc1;
    *(uint4*)&lds[3][srow][scol] = rd0;  *(uint4*)&lds[3][srow][scol+8] = rd1;
    __syncthreads();
    if (it == 0) LOAD8(32);

    bfrag ah[4], al[4], bb[4];
    #pragma unroll
    for (int m=0;m<4;m++){
      ah[m] = *(const bfrag*)&lds[0][wm + (m<<4) + fr][kg<<3];
      al[m] = *(const bfrag*)&lds[1][wm + (m<<4) + fr][kg<<3];
    }
    #pragma unroll
    for (int n=0;n<4;n++) bb[n] = *(const bfrag*)&lds[2][wn + (n<<4) + fr][kg<<3];
    #pragma unroll
    for (int m=0;m<4;m++)
      #pragma unroll
      for (int n=0;n<4;n++){
        acc[m][n] = __builtin_amdgcn_mfma_f32_16x16x32_bf16(ah[m], bb[n], acc[m][n], 0, 0, 0);
        acc[m][n] = __builtin_amdgcn_mfma_f32_16x16x32_bf16(al[m], bb[n], acc[m][n], 0, 0, 0);
      }
    #pragma unroll
    for (int n=0;n<4;n++) bb[n] = *(const bfrag*)&lds[3][wn + (n<<4) + fr][kg<<3];
    #pragma unroll
    for (int m=0;m<4;m++)
      #pragma unroll
      for (int n=0;n<4;n++)
        acc[m][n] = __builtin_amdgcn_mfma_f32_16x16x32_bf16(ah[m], bb[n], acc[m][n], 0, 0, 0);
  }
#undef LOAD8

  #pragma unroll
  for (int n=0;n<4;n++){
    const int col = bn + wn + (n<<4) + fr;
    const float bv = bdt[col];
    #pragma unroll
    for (int m=0;m<4;m++){
      float* Cp = dtb + (size_t)(bm + wm + (m<<4) + (kg<<2))*DI + col;
      #pragma unroll
      for (int r=0;r<4;r++){
        const float s = acc[m][n][r] + bv;
        const float sp = (s > 20.f) ? s : log1pf(__expf(s));
        Cp[(size_t)r*DI] = sp + 0.001f;
      }
    }
  }
}

// ---------------- bf16x2 MFMA GEMM 64x128 tile, full-K (out GEMM) ----------------
__global__ __launch_bounds__(256)
void gemm_bf16x2_b64(const unsigned short* __restrict__ Ah, const unsigned short* __restrict__ Al,
                     const unsigned short* __restrict__ Bh,
                     float* __restrict__ C, int M, int N, int K, int ldc)
{
  __shared__ __align__(16) unsigned short ldsA[2][64][40];
  __shared__ __align__(16) unsigned short ldsB[128][40];
  const int tid = threadIdx.x;
  const int bm = blockIdx.y << 6;
  const int bn = blockIdx.x << 7;
  const int wave = tid >> 6;
  const int lane = tid & 63;
  const int wm = (wave >> 1) << 5;
  const int wn = (wave & 1) << 6;
  const int fr = lane & 15;
  const int kg = lane >> 4;
  const int arow = tid >> 2, acol = (tid & 3) << 3;
  const int brow = tid >> 1, bcol = (tid & 1) << 4;

  const unsigned short* pAh = Ah + (size_t)(bm + arow)*K + acol;
  const unsigned short* pAl = Al + (size_t)(bm + arow)*K + acol;
  const unsigned short* pBh = Bh + (size_t)(bn + brow)*K + bcol;

  f32x4 acc[2][4];
  #pragma unroll
  for (int m=0;m<2;m++)
    #pragma unroll
    for (int n=0;n<4;n++)
      #pragma unroll
      for (int r=0;r<4;r++) acc[m][n][r] = 0.f;

  uint4 ra, rb, rc0, rc1;
#define LOAD4(k0) do { \
    ra  = *(const uint4*)(pAh + (k0)); \
    rb  = *(const uint4*)(pAl + (k0)); \
    rc0 = *(const uint4*)(pBh + (k0));  rc1 = *(const uint4*)(pBh + (k0) + 8); \
  } while(0)

  const int nIter = K >> 5;
  LOAD4(0);
  for (int it = 0; it < nIter; ++it) {
    __syncthreads();
    *(uint4*)&ldsA[0][arow][acol] = ra;
    *(uint4*)&ldsA[1][arow][acol] = rb;
    *(uint4*)&ldsB[brow][bcol] = rc0;  *(uint4*)&ldsB[brow][bcol+8] = rc1;
    __syncthreads();
    if (it + 1 < nIter) LOAD4((size_t)(it+1) << 5);

    bfrag ah[2], al[2], bh[4];
    #pragma unroll
    for (int m=0;m<2;m++){
      ah[m] = *(const bfrag*)&ldsA[0][wm + (m<<4) + fr][kg<<3];
      al[m] = *(const bfrag*)&ldsA[1][wm + (m<<4) + fr][kg<<3];
    }
    #pragma unroll
    for (int n=0;n<4;n++) bh[n] = *(const bfrag*)&ldsB[wn + (n<<4) + fr][kg<<3];
    #pragma unroll
    for (int m=0;m<2;m++)
      #pragma unroll
      for (int n=0;n<4;n++){
        acc[m][n] = __builtin_amdgcn_mfma_f32_16x16x32_bf16(ah[m], bh[n], acc[m][n], 0, 0, 0);
        acc[m][n] = __builtin_amdgcn_mfma_f32_16x16x32_bf16(al[m], bh[n], acc[m][n], 0, 0, 0);
      }
  }
#undef LOAD4

  #pragma unroll
  for (int m=0;m<2;m++)
    #pragma unroll
    for (int n=0;n<4;n++){
      float* Cp = C + (size_t)(bm + wm + (m<<4) + (kg<<2))*ldc + bn + wn + (n<<4) + fr;
      #pragma unroll
      for (int r=0;r<4;r++) Cp[(size_t)r*ldc] = acc[m][n][r];
    }
}

// ---------------- depthwise causal conv K=4 + bias + SiLU -> single bf16 ----------------
__global__ __launch_bounds__(256)
void conv_silu_h_kernel(const float* __restrict__ xz, const float* __restrict__ cw,
                        const float* __restrict__ cb, unsigned short* __restrict__ xsh) {
  const int idx = blockIdx.x * 256 + threadIdx.x;
  const int d4 = idx & (DI/4 - 1);
  const int r  = idx >> 9;
  const int b  = r >> 11;
  const int t  = r & (LSEQ-1);
  const int d  = d4 << 2;
  const float4 w0 = *(const float4*)(cw + (size_t)(d+0)*4);
  const float4 w1 = *(const float4*)(cw + (size_t)(d+1)*4);
  const float4 w2 = *(const float4*)(cw + (size_t)(d+2)*4);
  const float4 w3 = *(const float4*)(cw + (size_t)(d+3)*4);
  const float wk[4][4] = {{w0.x,w1.x,w2.x,w3.x},{w0.y,w1.y,w2.y,w3.y},
                          {w0.z,w1.z,w2.z,w3.z},{w0.w,w1.w,w2.w,w3.w}};
  float4 acc = *(const float4*)(cb + d);
  #pragma unroll
  for (int k=0;k<4;k++){
    const int tt = t - 3 + k;
    if (tt < 0) continue;
    const float4 xv = *(const float4*)(xz + ((size_t)b*LSEQ + tt)*XZL + d);
    acc.x = fmaf(wk[k][0], xv.x, acc.x);
    acc.y = fmaf(wk[k][1], xv.y, acc.y);
    acc.z = fmaf(wk[k][2], xv.z, acc.z);
    acc.w = fmaf(wk[k][3], xv.w, acc.w);
  }
  ushort4 h;
  h.x = f2bf(siluf(acc.x));
  h.y = f2bf(siluf(acc.y));
  h.z = f2bf(siluf(acc.z));
  h.w = f2bf(siluf(acc.w));
  *(ushort4*)(xsh + (size_t)r*DI + d) = h;
}

// ---------------- xp: K-split MFMA + LDS reduce; emits f32 [r][33] and bf16 pad [r][64] ----
__global__ __launch_bounds__(256)
void xp_kernel(const unsigned short* __restrict__ xsh,
               const unsigned short* __restrict__ wxh, const unsigned short* __restrict__ wxl,
               float* __restrict__ xp,
               unsigned short* __restrict__ xph, unsigned short* __restrict__ xpl) {
  __shared__ float red[4][64][12];
  const int tid = threadIdx.x;
  const int wave = tid >> 6, lane = tid & 63;
  const int fr = lane & 15, kg = lane >> 4;
  const int m0 = blockIdx.x << 4;
  const size_t koff = (size_t)wave << 9;

  const unsigned short* pah = xsh + (size_t)(m0 + fr)*DI + (kg<<3) + koff;
  const unsigned short* pbh = wxh + (size_t)fr*DI + (kg<<3) + koff;
  const unsigned short* pbl = wxl + (size_t)fr*DI + (kg<<3) + koff;

  f32x4 acc[3];
  #pragma unroll
  for (int nf=0;nf<3;nf++)
    #pragma unroll
    for (int r=0;r<4;r++) acc[nf][r] = 0.f;

  for (int kk = 0; kk < 512; kk += 32) {
    const bfrag ah = *(const bfrag*)(pah + kk);
    #pragma unroll
    for (int nf=0;nf<3;nf++){
      const bfrag bh = *(const bfrag*)(pbh + (size_t)nf*16*DI + kk);
      const bfrag bl = *(const bfrag*)(pbl + (size_t)nf*16*DI + kk);
      acc[nf] = __builtin_amdgcn_mfma_f32_16x16x32_bf16(ah, bh, acc[nf], 0, 0, 0);
      acc[nf] = __builtin_amdgcn_mfma_f32_16x16x32_bf16(ah, bl, acc[nf], 0, 0, 0);
    }
  }
  #pragma unroll
  for (int nf=0;nf<3;nf++)
    #pragma unroll
    for (int r=0;r<4;r++) red[wave][lane][nf*4+r] = acc[nf][r];
  __syncthreads();
  if (wave == 0){
    #pragma unroll
    for (int nf=0;nf<3;nf++){
      const int col = (nf<<4) + fr;
      #pragma unroll
      for (int r=0;r<4;r++){
        const float v = red[0][lane][nf*4+r] + red[1][lane][nf*4+r]
                      + red[2][lane][nf*4+r] + red[3][lane][nf*4+r];
        const int row = (kg<<2) + r;
        // bf16 hi/lo padded write (cols 33..47 are exactly 0 via zero-pad Wx)
        const unsigned short hv = f2bf(v);
        xph[(size_t)(m0 + row)*KDT + col] = hv;
        xpl[(size_t)(m0 + row)*KDT + col] = f2bf(v - bf2f(hv));
        if (col < 33) xp[(size_t)(m0 + row)*33 + col] = v;
      }
      }
    // zero-fill cols 48..63
    #pragma unroll
    for (int r=0;r<4;r++){
      const int row = (kg<<2) + r;
      xph[(size_t)(m0 + row)*KDT + 48 + fr] = 0;
      xpl[(size_t)(m0 + row)*KDT + 48 + fr] = 0;
    }
  }
}

// ---------------- scan pass 1: local chunk scan -> y_loc (xz x-half), P, H ----------------
__global__ __launch_bounds__(256)
void scan1_kernel(const unsigned short* __restrict__ xsh, const float* __restrict__ dt,
                  const float* __restrict__ xp, const float* __restrict__ Alog,
                  const float* __restrict__ Dp,
                  float* __restrict__ y, float* __restrict__ Pbuf, float* __restrict__ Hbuf) {
  const int g  = blockIdx.x*256 + threadIdx.x;
  const int nq = g & 3;
  const int g2 = g >> 2;
  const int d  = g2 & (DI-1);
  const int bc = g2 >> 11;
  const int c  = bc & (NC-1);
  const int b  = bc >> 6;
  const float4 al = *(const float4*)(Alog + (size_t)d*NS + (nq<<2));
  const float Aa[4] = {-__expf(al.x), -__expf(al.y), -__expf(al.z), -__expf(al.w)};
  float rA[4];
  #pragma unroll
  for (int i=0;i<4;i++) rA[i] = 1.f/(Aa[i] + 1e-8f);
  const float Dv = Dp[d];
  float h[4] = {0,0,0,0};
  float P[4] = {1,1,1,1};
  const int t0 = c * TC;
  for (int t = t0; t < t0 + TC; ++t){
    const size_t r = (size_t)b*LSEQ + t;
    const float dtv = dt[r*DI + d];
    const float xv  = bf2f(xsh[r*DI + d]);
    const float* xpr = xp + r*33;
    float yp = 0.f;
    #pragma unroll
    for (int i=0;i<4;i++){
      const int n = (nq<<2) + i;
      const float e = __expf(Aa[i]*dtv);
      P[i] *= e;
      const float Bv = xpr[1 + n];
      const float Cv = xpr[17 + n];
      const float gbx = rA[i] * (1.f - e) * Bv * xv;
      h[i] = fmaf(e, h[i], gbx);
      h[i] = fminf(10.f, fmaxf(-10.f, h[i]));
      yp = fmaf(Cv, h[i], yp);
    }
    yp += __shfl_xor(yp, 1);
    yp += __shfl_xor(yp, 2);
    if (nq == 0) y[r*XZL + d] = yp + Dv*xv;
  }
  const size_t pb = (((size_t)c*B_SZ + b)*DI + d)*NS + (nq<<2);
  *(float4*)(Pbuf+pb) = make_float4(P[0],P[1],P[2],P[3]);
  *(float4*)(Hbuf+pb) = make_float4(h[0],h[1],h[2],h[3]);
}

// ---------------- scan pass 2: sequential chunk combine; hin folded into Hbuf ----
__global__ __launch_bounds__(256)
void scan2_kernel(const float* __restrict__ Pbuf, float* __restrict__ Hbuf) {
  const int g = blockIdx.x*256 + threadIdx.x;
  const size_t cs = (size_t)B_SZ*DI*NS;
  float h = 0.f;
  for (int c=1;c<NC;++c){
    const float Pv = Pbuf[(size_t)(c-1)*cs + g];
    const float Hv = Hbuf[(size_t)(c-1)*cs + g];
    h = fmaf(Pv, h, Hv);
    Hbuf[(size_t)(c-1)*cs + g] = h;
  }
}

// ---------------- scan pass 3: light cross-chunk correction + silu(z) + y split ----
__global__ __launch_bounds__(256)
void scan3_kernel(const float* __restrict__ dt, const float* __restrict__ xp,
                  const float* __restrict__ Alog, const float* __restrict__ hinb,
                  const float* __restrict__ xz,
                  unsigned short* __restrict__ yh, unsigned short* __restrict__ yl) {
  const int g  = blockIdx.x*256 + threadIdx.x;
  const int nq = g & 3;
  const int g2 = g >> 2;
  const int d  = g2 & (DI-1);
  const int bc = g2 >> 11;
  const int c  = bc & (NC-1);
  const int b  = bc >> 6;
  const float4 al = *(const float4*)(Alog + (size_t)d*NS + (nq<<2));
  const float Aa[4] = {-__expf(al.x), -__expf(al.y), -__expf(al.z), -__expf(al.w)};
  float hi[4] = {0.f, 0.f, 0.f, 0.f};
  if (c > 0){
    const size_t pb = (((size_t)(c-1)*B_SZ + b)*DI + d)*NS + (nq<<2);
    const float4 hv = *(const float4*)(hinb + pb);
    hi[0]=hv.x; hi[1]=hv.y; hi[2]=hv.z; hi[3]=hv.w;
  }
  float q[4] = {1,1,1,1};
  const int t0 = c * TC;
  for (int t = t0; t < t0 + TC; ++t){
    const size_t r = (size_t)b*LSEQ + t;
    const float dtv = dt[r*DI + d];
    const float* xpr = xp + r*33;
    float cp = 0.f;
    #pragma unroll
    for (int i=0;i<4;i++){
      q[i] *= __expf(Aa[i]*dtv);
      const float Cv = xpr[17 + (nq<<2) + i];
      cp = fmaf(Cv*q[i], hi[i], cp);
    }
    cp += __shfl_xor(cp, 1);
    cp += __shfl_xor(cp, 2);
    if (nq == 0){
      const float zv = xz[r*XZL + 2048 + d];
      const float yv = (xz[r*XZL + d] + cp) * siluf(zv);
      const unsigned short h16 = f2bf(yv);
      yh[r*DI + d] = h16;
      yl[r*DI + d] = f2bf(yv - bf2f(h16));
    }
  }
}

extern "C" void kernel_launch(void* const* d_in, const int* in_sizes, int n_in,
                              void* d_out, int out_size, void* d_ws, size_t ws_size,
                              hipStream_t stream) {
  const float* x     = (const float*)d_in[0];
  const float* gamma = (const float*)d_in[1];
  const float* beta  = (const float*)d_in[2];
  const float* W_in  = (const float*)d_in[3];
  const float* cw    = (const float*)d_in[4];
  const float* cb    = (const float*)d_in[5];
  const float* Alog  = (const float*)d_in[6];
  const float* Dp    = (const float*)d_in[7];
  const float* Wx    = (const float*)d_in[8];
  const float* Wdt   = (const float*)d_in[9];
  const float* bdt   = (const float*)d_in[10];
  const float* Wout  = (const float*)d_in[11];
  float* out = (float*)d_out;
  float* ws  = (float*)d_ws;

  const size_t M1 = 1048576;
  float* xz   = ws;                 // 16M f32
  float* xsq  = ws + 16*M1;         // 8M f32: xs_h | y_h/y_l overlay
  float* dtb  = ws + 24*M1;         // 8M
  float* Pb   = ws + 32*M1;         // 4M
  float* Hb   = Pb + 4*M1;          // 4M
  float* xpb  = Hb + 4*M1;          // 135168 f32
  float* wxzone = xpb + 135168;
  unsigned short* wx_h = (unsigned short*)wxzone;          // 98304 us
  unsigned short* wx_l = wx_h + (size_t)NPAD*DI;           // 98304 us
  unsigned short* xph  = wx_l + (size_t)NPAD*DI;           // 262144 us
  unsigned short* xpl  = xph + (size_t)RTOT*KDT;           // 262144 us
  unsigned short* wdh  = xpl + (size_t)RTOT*KDT;           // 131072 us
  unsigned short* wdl  = wdh + (size_t)DI*KDT;             // 131072 us
  unsigned short* zone = wdl + (size_t)DI*KDT;             // 12M us
  unsigned short* xn_h = zone;              // 4M us
  unsigned short* xn_l = zone + 4*M1;       // 4M us
  unsigned short* Wi_h = zone + 8*M1;       // 4M us (hi only)
  unsigned short* Wo_h = zone;              // 2M us (split AFTER gemm1, overlays xn_h)
  unsigned short* xs_h = (unsigned short*)xsq;
  unsigned short* y_h  = (unsigned short*)xsq;
  unsigned short* y_l  = (unsigned short*)xsq + 8*M1;

  ln_split_kernel<<<RTOT, 256, 0, stream>>>(x, gamma, beta, xn_h, xn_l);
  split_win_wx_kernel<<<(2*DI*DM/4 + NPAD*DI/4 + 255)/256, 256, 0, stream>>>(
      W_in, Wx, Wi_h, wx_h, wx_l);
  split_pad_wdt_kernel<<<(DI*KDT + 255)/256, 256, 0, stream>>>(Wdt, wdh, wdl);
  gemm_bf16x2<<<dim3(XZL/128, RTOT/128), 256, 0, stream>>>(xn_h, xn_l, Wi_h,
                                                           xz, RTOT, XZL, DM, XZL);
  split_hi_kernel<<<(DM*DI/4 + 255)/256, 256, 0, stream>>>(Wout, Wo_h, DM*DI/4);
  conv_silu_h_kernel<<<(RTOT*(DI/4))/256, 256, 0, stream>>>(xz, cw, cb, xs_h);
  xp_kernel<<<RTOT/16, 256, 0, stream>>>(xs_h, wx_h, wx_l, xpb, xph, xpl);
  gemm_dt<<<dim3(DI/128, RTOT/128), 256, 0, stream>>>(xph, xpl, wdh, wdl, bdt, dtb);
  scan1_kernel<<<(B_SZ*NC*DI*4)/256, 256, 0, stream>>>(xs_h, dtb, xpb, Alog, Dp, xz, Pb, Hb);
  scan2_kernel<<<(B_SZ*DI*NS)/256, 256, 0, stream>>>(Pb, Hb);
  scan3_kernel<<<(B_SZ*NC*DI*4)/256, 256, 0, stream>>>(dtb, xpb, Alog, Hb, xz, y_h, y_l);
  gemm_bf16x2_b64<<<dim3(DM/128, RTOT/64), 256, 0, stream>>>(y_h, y_l, Wo_h,
                                                             out, RTOT, DM, DI, DM);
}

// Round 12
// 344.820 us; speedup vs baseline: 1.3311x; 1.0018x over previous
//
#include <hip/hip_runtime.h>
#include <math.h>

// MambaSSMBlock: B=2, L=2048, Dm=1024, Di=2048, N=16, convK=4
// Round 12: xp occupancy fix (R11's xp_kernel was 57us at 1 wave/SIMD):
//   xp_part: grid 1024 = 256 row-tiles x 4 K-quadrants (4 blocks/CU),
//   partials in 3MB L2-resident buffer; xp_reduce sums 4 partials and
//   emits f32 xp + padded bf16 hi/lo. Everything else identical to R11.
// Workspace ~189 MB.

#define B_SZ 2
#define LSEQ 2048
#define DM   1024
#define DI   2048
#define NS   16
#define RTOT (B_SZ*LSEQ)
#define NC   64
#define TC   (LSEQ/NC)
#define XZL  4096
#define NPAD 48
#define KDT  64     // padded K for dt GEMM

typedef __attribute__((ext_vector_type(8))) short bfrag;
typedef __attribute__((ext_vector_type(4))) float f32x4;

__device__ __forceinline__ float siluf(float v){ return v / (1.f + __expf(-v)); }

__device__ __forceinline__ unsigned short f2bf(float f){
  unsigned int u = __float_as_uint(f);
  u += 0x7FFFu + ((u >> 16) & 1u);
  return (unsigned short)(u >> 16);
}
__device__ __forceinline__ float bf2f(unsigned short h){
  return __uint_as_float(((unsigned int)h) << 16);
}

// ---------------- LayerNorm fused with bf16 hi/lo split ----------------
__global__ __launch_bounds__(256)
void ln_split_kernel(const float* __restrict__ x, const float* __restrict__ g,
                     const float* __restrict__ b,
                     unsigned short* __restrict__ xh, unsigned short* __restrict__ xl) {
  __shared__ float red[8];
  const int r = blockIdx.x, tid = threadIdx.x;
  const float4 v = ((const float4*)(x + (size_t)r*DM))[tid];
  float s  = v.x+v.y+v.z+v.w;
  float ss = v.x*v.x+v.y*v.y+v.z*v.z+v.w*v.w;
  #pragma unroll
  for (int off=32; off; off>>=1){ s += __shfl_xor(s,off); ss += __shfl_xor(ss,off); }
  if ((tid & 63)==0){ int w=tid>>6; red[w]=s; red[4+w]=ss; }
  __syncthreads();
  s  = red[0]+red[1]+red[2]+red[3];
  ss = red[4]+red[5]+red[6]+red[7];
  const float mu  = s*(1.f/DM);
  const float inv = rsqrtf(ss*(1.f/DM) - mu*mu + 1e-5f);
  const float4 gv = ((const float4*)g)[tid];
  const float4 bv = ((const float4*)b)[tid];
  float o[4];
  o[0] = (v.x-mu)*inv*gv.x + bv.x;
  o[1] = (v.y-mu)*inv*gv.y + bv.y;
  o[2] = (v.z-mu)*inv*gv.z + bv.z;
  o[3] = (v.w-mu)*inv*gv.w + bv.w;
  ushort4 h, l;
  h.x = f2bf(o[0]); l.x = f2bf(o[0] - bf2f(h.x));
  h.y = f2bf(o[1]); l.y = f2bf(o[1] - bf2f(h.y));
  h.z = f2bf(o[2]); l.z = f2bf(o[2] - bf2f(h.z));
  h.w = f2bf(o[3]); l.w = f2bf(o[3] - bf2f(h.w));
  ((ushort4*)(xh + (size_t)r*DM))[tid] = h;
  ((ushort4*)(xl + (size_t)r*DM))[tid] = l;
}

// ---------------- merged W_in(hi only) + Wx(pad48, hi/lo) split ----------------
__global__ __launch_bounds__(256)
void split_win_wx_kernel(const float* __restrict__ Win, const float* __restrict__ Wx,
                         unsigned short* __restrict__ wih,
                         unsigned short* __restrict__ wxh, unsigned short* __restrict__ wxl) {
  const int NWIN = 2*DI*DM/4;
  const int NWX  = NPAD*DI/4;
  const int i = blockIdx.x*256 + threadIdx.x;
  if (i < NWIN){
    const float4 v = ((const float4*)Win)[i];
    ushort4 h;
    h.x = f2bf(v.x); h.y = f2bf(v.y); h.z = f2bf(v.z); h.w = f2bf(v.w);
    ((ushort4*)wih)[i] = h;
  } else if (i < NWIN + NWX){
    const int j = i - NWIN;
    const int row = j >> 9;
    float4 v = make_float4(0.f,0.f,0.f,0.f);
    if (row < 33) v = ((const float4*)Wx)[j];
    ushort4 h, l;
    h.x = f2bf(v.x); l.x = f2bf(v.x - bf2f(h.x));
    h.y = f2bf(v.y); l.y = f2bf(v.y - bf2f(h.y));
    h.z = f2bf(v.z); l.z = f2bf(v.z - bf2f(h.z));
    h.w = f2bf(v.w); l.w = f2bf(v.w - bf2f(h.w));
    ((ushort4*)wxh)[j] = h;
    ((ushort4*)wxl)[j] = l;
  }
}

// ---------------- Wdt [2048][33] -> padded [2048][64] bf16 hi/lo ----------------
__global__ __launch_bounds__(256)
void split_pad_wdt_kernel(const float* __restrict__ Wdt,
                          unsigned short* __restrict__ wdh, unsigned short* __restrict__ wdl) {
  const int i = blockIdx.x*256 + threadIdx.x;
  if (i >= DI*KDT) return;
  const int row = i >> 6, col = i & 63;
  float v = (col < 33) ? Wdt[(size_t)row*33 + col] : 0.f;
  const unsigned short h = f2bf(v);
  wdh[i] = h;
  wdl[i] = f2bf(v - bf2f(h));
}

// ---------------- fp32 -> single bf16 (Wout) ----------------
__global__ __launch_bounds__(256)
void split_hi_kernel(const float* __restrict__ in, unsigned short* __restrict__ hi, int n4) {
  const int i = blockIdx.x*256 + threadIdx.x;
  if (i >= n4) return;
  const float4 v = ((const float4*)in)[i];
  ushort4 h;
  h.x = f2bf(v.x); h.y = f2bf(v.y); h.z = f2bf(v.z); h.w = f2bf(v.w);
  ((ushort4*)hi)[i] = h;
}

// ---------------- bf16x2 MFMA GEMM 128x128: C = (Ah+Al) * Bh^T ----------------
__global__ __launch_bounds__(256)
void gemm_bf16x2(const unsigned short* __restrict__ Ah, const unsigned short* __restrict__ Al,
                 const unsigned short* __restrict__ Bh,
                 float* __restrict__ C, int M, int N, int K, int ldc)
{
  __shared__ __align__(16) unsigned short lds[3][128][40];
  const int tid = threadIdx.x;
  const int bm = blockIdx.y << 7;
  const int bn = blockIdx.x << 7;
  const int wave = tid >> 6;
  const int lane = tid & 63;
  const int wm = (wave >> 1) << 6;
  const int wn = (wave & 1) << 6;
  const int fr = lane & 15;
  const int kg = lane >> 4;
  const int srow = tid >> 1;
  const int scol = (tid & 1) << 4;

  const unsigned short* pAh = Ah + (size_t)(bm + srow)*K + scol;
  const unsigned short* pAl = Al + (size_t)(bm + srow)*K + scol;
  const unsigned short* pBh = Bh + (size_t)(bn + srow)*K + scol;

  f32x4 acc[4][4];
  #pragma unroll
  for (int m=0;m<4;m++)
    #pragma unroll
    for (int n=0;n<4;n++)
      #pragma unroll
      for (int r=0;r<4;r++) acc[m][n][r] = 0.f;

  uint4 ra0, ra1, rb0, rb1, rc0, rc1;
#define LOAD6(k0) do { \
    ra0 = *(const uint4*)(pAh + (k0));     ra1 = *(const uint4*)(pAh + (k0) + 8); \
    rb0 = *(const uint4*)(pAl + (k0));     rb1 = *(const uint4*)(pAl + (k0) + 8); \
    rc0 = *(const uint4*)(pBh + (k0));     rc1 = *(const uint4*)(pBh + (k0) + 8); \
  } while(0)

  const int nIter = K >> 5;
  LOAD6(0);
  for (int it = 0; it < nIter; ++it) {
    __syncthreads();
    *(uint4*)&lds[0][srow][scol] = ra0;  *(uint4*)&lds[0][srow][scol+8] = ra1;
    *(uint4*)&lds[1][srow][scol] = rb0;  *(uint4*)&lds[1][srow][scol+8] = rb1;
    *(uint4*)&lds[2][srow][scol] = rc0;  *(uint4*)&lds[2][srow][scol+8] = rc1;
    __syncthreads();
    if (it + 1 < nIter) LOAD6((size_t)(it+1) << 5);

    bfrag ah[4], al[4], bb[4];
    #pragma unroll
    for (int m=0;m<4;m++){
      ah[m] = *(const bfrag*)&lds[0][wm + (m<<4) + fr][kg<<3];
      al[m] = *(const bfrag*)&lds[1][wm + (m<<4) + fr][kg<<3];
    }
    #pragma unroll
    for (int n=0;n<4;n++) bb[n] = *(const bfrag*)&lds[2][wn + (n<<4) + fr][kg<<3];
    #pragma unroll
    for (int m=0;m<4;m++)
      #pragma unroll
      for (int n=0;n<4;n++){
        acc[m][n] = __builtin_amdgcn_mfma_f32_16x16x32_bf16(ah[m], bb[n], acc[m][n], 0, 0, 0);
        acc[m][n] = __builtin_amdgcn_mfma_f32_16x16x32_bf16(al[m], bb[n], acc[m][n], 0, 0, 0);
      }
  }
#undef LOAD6

  #pragma unroll
  for (int m=0;m<4;m++)
    #pragma unroll
    for (int n=0;n<4;n++){
      float* Cp = C + (size_t)(bm + wm + (m<<4) + (kg<<2))*ldc + bn + wn + (n<<4) + fr;
      #pragma unroll
      for (int r=0;r<4;r++) Cp[(size_t)r*ldc] = acc[m][n][r];
    }
}

// ---------------- dt GEMM: dt = softplus((xph+xpl) @ (wdh+wdl)^T + b) + 1e-3 ----
__global__ __launch_bounds__(256)
void gemm_dt(const unsigned short* __restrict__ Ah, const unsigned short* __restrict__ Al,
             const unsigned short* __restrict__ Bh, const unsigned short* __restrict__ Bl,
             const float* __restrict__ bdt, float* __restrict__ dtb)
{
  __shared__ __align__(16) unsigned short lds[4][128][40];
  const int tid = threadIdx.x;
  const int bm = blockIdx.y << 7;
  const int bn = blockIdx.x << 7;
  const int wave = tid >> 6;
  const int lane = tid & 63;
  const int wm = (wave >> 1) << 6;
  const int wn = (wave & 1) << 6;
  const int fr = lane & 15;
  const int kg = lane >> 4;
  const int srow = tid >> 1;
  const int scol = (tid & 1) << 4;

  const unsigned short* pAh = Ah + (size_t)(bm + srow)*KDT + scol;
  const unsigned short* pAl = Al + (size_t)(bm + srow)*KDT + scol;
  const unsigned short* pBh = Bh + (size_t)(bn + srow)*KDT + scol;
  const unsigned short* pBl = Bl + (size_t)(bn + srow)*KDT + scol;

  f32x4 acc[4][4];
  #pragma unroll
  for (int m=0;m<4;m++)
    #pragma unroll
    for (int n=0;n<4;n++)
      #pragma unroll
      for (int r=0;r<4;r++) acc[m][n][r] = 0.f;

  uint4 ra0, ra1, rb0, rb1, rc0, rc1, rd0, rd1;
#define LOAD8(k0) do { \
    ra0 = *(const uint4*)(pAh + (k0));     ra1 = *(const uint4*)(pAh + (k0) + 8); \
    rb0 = *(const uint4*)(pAl + (k0));     rb1 = *(const uint4*)(pAl + (k0) + 8); \
    rc0 = *(const uint4*)(pBh + (k0));     rc1 = *(const uint4*)(pBh + (k0) + 8); \
    rd0 = *(const uint4*)(pBl + (k0));     rd1 = *(const uint4*)(pBl + (k0) + 8); \
  } while(0)

  LOAD8(0);
  #pragma unroll
  for (int it = 0; it < 2; ++it) {
    __syncthreads();
    *(uint4*)&lds[0][srow][scol] = ra0;  *(uint4*)&lds[0][srow][scol+8] = ra1;
    *(uint4*)&lds[1][srow][scol] = rb0;  *(uint4*)&lds[1][srow][scol+8] = rb1;
    *(uint4*)&lds[2][srow][scol] = rc0;  *(uint4*)&lds[2][srow][scol+8] = rc1;
    *(uint4*)&lds[3][srow][scol] = rd0;  *(uint4*)&lds[3][srow][scol+8] = rd1;
    __syncthreads();
    if (it == 0) LOAD8(32);

    bfrag ah[4], al[4], bb[4];
    #pragma unroll
    for (int m=0;m<4;m++){
      ah[m] = *(const bfrag*)&lds[0][wm + (m<<4) + fr][kg<<3];
      al[m] = *(const bfrag*)&lds[1][wm + (m<<4) + fr][kg<<3];
    }
    #pragma unroll
    for (int n=0;n<4;n++) bb[n] = *(const bfrag*)&lds[2][wn + (n<<4) + fr][kg<<3];
    #pragma unroll
    for (int m=0;m<4;m++)
      #pragma unroll
      for (int n=0;n<4;n++){
        acc[m][n] = __builtin_amdgcn_mfma_f32_16x16x32_bf16(ah[m], bb[n], acc[m][n], 0, 0, 0);
        acc[m][n] = __builtin_amdgcn_mfma_f32_16x16x32_bf16(al[m], bb[n], acc[m][n], 0, 0, 0);
      }
    #pragma unroll
    for (int n=0;n<4;n++) bb[n] = *(const bfrag*)&lds[3][wn + (n<<4) + fr][kg<<3];
    #pragma unroll
    for (int m=0;m<4;m++)
      #pragma unroll
      for (int n=0;n<4;n++)
        acc[m][n] = __builtin_amdgcn_mfma_f32_16x16x32_bf16(ah[m], bb[n], acc[m][n], 0, 0, 0);
  }
#undef LOAD8

  #pragma unroll
  for (int n=0;n<4;n++){
    const int col = bn + wn + (n<<4) + fr;
    const float bv = bdt[col];
    #pragma unroll
    for (int m=0;m<4;m++){
      float* Cp = dtb + (size_t)(bm + wm + (m<<4) + (kg<<2))*DI + col;
      #pragma unroll
      for (int r=0;r<4;r++){
        const float s = acc[m][n][r] + bv;
        const float sp = (s > 20.f) ? s : log1pf(__expf(s));
        Cp[(size_t)r*DI] = sp + 0.001f;
      }
    }
  }
}

// ---------------- bf16x2 MFMA GEMM 64x128 tile, full-K (out GEMM) ----------------
__global__ __launch_bounds__(256)
void gemm_bf16x2_b64(const unsigned short* __restrict__ Ah, const unsigned short* __restrict__ Al,
                     const unsigned short* __restrict__ Bh,
                     float* __restrict__ C, int M, int N, int K, int ldc)
{
  __shared__ __align__(16) unsigned short ldsA[2][64][40];
  __shared__ __align__(16) unsigned short ldsB[128][40];
  const int tid = threadIdx.x;
  const int bm = blockIdx.y << 6;
  const int bn = blockIdx.x << 7;
  const int wave = tid >> 6;
  const int lane = tid & 63;
  const int wm = (wave >> 1) << 5;
  const int wn = (wave & 1) << 6;
  const int fr = lane & 15;
  const int kg = lane >> 4;
  const int arow = tid >> 2, acol = (tid & 3) << 3;
  const int brow = tid >> 1, bcol = (tid & 1) << 4;

  const unsigned short* pAh = Ah + (size_t)(bm + arow)*K + acol;
  const unsigned short* pAl = Al + (size_t)(bm + arow)*K + acol;
  const unsigned short* pBh = Bh + (size_t)(bn + brow)*K + bcol;

  f32x4 acc[2][4];
  #pragma unroll
  for (int m=0;m<2;m++)
    #pragma unroll
    for (int n=0;n<4;n++)
      #pragma unroll
      for (int r=0;r<4;r++) acc[m][n][r] = 0.f;

  uint4 ra, rb, rc0, rc1;
#define LOAD4(k0) do { \
    ra  = *(const uint4*)(pAh + (k0)); \
    rb  = *(const uint4*)(pAl + (k0)); \
    rc0 = *(const uint4*)(pBh + (k0));  rc1 = *(const uint4*)(pBh + (k0) + 8); \
  } while(0)

  const int nIter = K >> 5;
  LOAD4(0);
  for (int it = 0; it < nIter; ++it) {
    __syncthreads();
    *(uint4*)&ldsA[0][arow][acol] = ra;
    *(uint4*)&ldsA[1][arow][acol] = rb;
    *(uint4*)&ldsB[brow][bcol] = rc0;  *(uint4*)&ldsB[brow][bcol+8] = rc1;
    __syncthreads();
    if (it + 1 < nIter) LOAD4((size_t)(it+1) << 5);

    bfrag ah[2], al[2], bh[4];
    #pragma unroll
    for (int m=0;m<2;m++){
      ah[m] = *(const bfrag*)&ldsA[0][wm + (m<<4) + fr][kg<<3];
      al[m] = *(const bfrag*)&ldsA[1][wm + (m<<4) + fr][kg<<3];
    }
    #pragma unroll
    for (int n=0;n<4;n++) bh[n] = *(const bfrag*)&ldsB[wn + (n<<4) + fr][kg<<3];
    #pragma unroll
    for (int m=0;m<2;m++)
      #pragma unroll
      for (int n=0;n<4;n++){
        acc[m][n] = __builtin_amdgcn_mfma_f32_16x16x32_bf16(ah[m], bh[n], acc[m][n], 0, 0, 0);
        acc[m][n] = __builtin_amdgcn_mfma_f32_16x16x32_bf16(al[m], bh[n], acc[m][n], 0, 0, 0);
      }
  }
#undef LOAD4

  #pragma unroll
  for (int m=0;m<2;m++)
    #pragma unroll
    for (int n=0;n<4;n++){
      float* Cp = C + (size_t)(bm + wm + (m<<4) + (kg<<2))*ldc + bn + wn + (n<<4) + fr;
      #pragma unroll
      for (int r=0;r<4;r++) Cp[(size_t)r*ldc] = acc[m][n][r];
    }
}

// ---------------- depthwise causal conv K=4 + bias + SiLU -> single bf16 ----------------
__global__ __launch_bounds__(256)
void conv_silu_h_kernel(const float* __restrict__ xz, const float* __restrict__ cw,
                        const float* __restrict__ cb, unsigned short* __restrict__ xsh) {
  const int idx = blockIdx.x * 256 + threadIdx.x;
  const int d4 = idx & (DI/4 - 1);
  const int r  = idx >> 9;
  const int b  = r >> 11;
  const int t  = r & (LSEQ-1);
  const int d  = d4 << 2;
  const float4 w0 = *(const float4*)(cw + (size_t)(d+0)*4);
  const float4 w1 = *(const float4*)(cw + (size_t)(d+1)*4);
  const float4 w2 = *(const float4*)(cw + (size_t)(d+2)*4);
  const float4 w3 = *(const float4*)(cw + (size_t)(d+3)*4);
  const float wk[4][4] = {{w0.x,w1.x,w2.x,w3.x},{w0.y,w1.y,w2.y,w3.y},
                          {w0.z,w1.z,w2.z,w3.z},{w0.w,w1.w,w2.w,w3.w}};
  float4 acc = *(const float4*)(cb + d);
  #pragma unroll
  for (int k=0;k<4;k++){
    const int tt = t - 3 + k;
    if (tt < 0) continue;
    const float4 xv = *(const float4*)(xz + ((size_t)b*LSEQ + tt)*XZL + d);
    acc.x = fmaf(wk[k][0], xv.x, acc.x);
    acc.y = fmaf(wk[k][1], xv.y, acc.y);
    acc.z = fmaf(wk[k][2], xv.z, acc.z);
    acc.w = fmaf(wk[k][3], xv.w, acc.w);
  }
  ushort4 h;
  h.x = f2bf(siluf(acc.x));
  h.y = f2bf(siluf(acc.y));
  h.z = f2bf(siluf(acc.z));
  h.w = f2bf(siluf(acc.w));
  *(ushort4*)(xsh + (size_t)r*DI + d) = h;
}

// ---------------- xp partials: grid (row-tile x 4 K-quadrants), 4 blocks/CU ----------------
// block = 16 rows, K-quadrant kq; wave w covers K in [kq*512 + w*128, +128).
__global__ __launch_bounds__(256)
void xp_part_kernel(const unsigned short* __restrict__ xsh,
                    const unsigned short* __restrict__ wxh, const unsigned short* __restrict__ wxl,
                    float* __restrict__ part) {
  __shared__ float red[4][64][12];
  const int tid = threadIdx.x;
  const int wave = tid >> 6, lane = tid & 63;
  const int fr = lane & 15, kg = lane >> 4;
  const int m0 = (blockIdx.x >> 2) << 4;
  const int kq = blockIdx.x & 3;
  const size_t koff = ((size_t)kq << 9) + ((size_t)wave << 7);

  const unsigned short* pah = xsh + (size_t)(m0 + fr)*DI + (kg<<3) + koff;
  const unsigned short* pbh = wxh + (size_t)fr*DI + (kg<<3) + koff;
  const unsigned short* pbl = wxl + (size_t)fr*DI + (kg<<3) + koff;

  f32x4 acc[3];
  #pragma unroll
  for (int nf=0;nf<3;nf++)
    #pragma unroll
    for (int r=0;r<4;r++) acc[nf][r] = 0.f;

  #pragma unroll
  for (int kk = 0; kk < 128; kk += 32) {
    const bfrag ah = *(const bfrag*)(pah + kk);
    #pragma unroll
    for (int nf=0;nf<3;nf++){
      const bfrag bh = *(const bfrag*)(pbh + (size_t)nf*16*DI + kk);
      const bfrag bl = *(const bfrag*)(pbl + (size_t)nf*16*DI + kk);
      acc[nf] = __builtin_amdgcn_mfma_f32_16x16x32_bf16(ah, bh, acc[nf], 0, 0, 0);
      acc[nf] = __builtin_amdgcn_mfma_f32_16x16x32_bf16(ah, bl, acc[nf], 0, 0, 0);
    }
  }
  #pragma unroll
  for (int nf=0;nf<3;nf++)
    #pragma unroll
    for (int r=0;r<4;r++) red[wave][lane][nf*4+r] = acc[nf][r];
  __syncthreads();
  if (wave == 0){
    #pragma unroll
    for (int nf=0;nf<3;nf++){
      const int col = (nf<<4) + fr;
      #pragma unroll
      for (int r=0;r<4;r++){
        const float v = red[0][lane][nf*4+r] + red[1][lane][nf*4+r]
                      + red[2][lane][nf*4+r] + red[3][lane][nf*4+r];
        const int row = (kg<<2) + r;
        part[((size_t)kq*RTOT + m0 + row)*NPAD + col] = v;
      }
    }
  }
}

// ---------------- xp reduce: sum 4 partials -> xp f32 [r][33] + bf16 pad [r][64] ----
__global__ __launch_bounds__(256)
void xp_reduce_kernel(const float* __restrict__ part, float* __restrict__ xp,
                      unsigned short* __restrict__ xph, unsigned short* __restrict__ xpl) {
  const int i = blockIdx.x*256 + threadIdx.x;   // over RTOT*64
  if (i >= RTOT*KDT) return;
  const int row = i >> 6, col = i & 63;
  float v = 0.f;
  if (col < NPAD){
    const size_t rc = (size_t)row*NPAD + col;
    v = part[rc] + part[(size_t)RTOT*NPAD + rc]
      + part[2*(size_t)RTOT*NPAD + rc] + part[3*(size_t)RTOT*NPAD + rc];
  }
  const unsigned short hv = f2bf(v);
  xph[i] = hv;
  xpl[i] = f2bf(v - bf2f(hv));
  if (col < 33) xp[(size_t)row*33 + col] = v;
}

// ---------------- scan pass 1: local chunk scan -> y_loc (xz x-half), P, H ----------------
__global__ __launch_bounds__(256)
void scan1_kernel(const unsigned short* __restrict__ xsh, const float* __restrict__ dt,
                  const float* __restrict__ xp, const float* __restrict__ Alog,
                  const float* __restrict__ Dp,
                  float* __restrict__ y, float* __restrict__ Pbuf, float* __restrict__ Hbuf) {
  const int g  = blockIdx.x*256 + threadIdx.x;
  const int nq = g & 3;
  const int g2 = g >> 2;
  const int d  = g2 & (DI-1);
  const int bc = g2 >> 11;
  const int c  = bc & (NC-1);
  const int b  = bc >> 6;
  const float4 al = *(const float4*)(Alog + (size_t)d*NS + (nq<<2));
  const float Aa[4] = {-__expf(al.x), -__expf(al.y), -__expf(al.z), -__expf(al.w)};
  float rA[4];
  #pragma unroll
  for (int i=0;i<4;i++) rA[i] = 1.f/(Aa[i] + 1e-8f);
  const float Dv = Dp[d];
  float h[4] = {0,0,0,0};
  float P[4] = {1,1,1,1};
  const int t0 = c * TC;
  for (int t = t0; t < t0 + TC; ++t){
    const size_t r = (size_t)b*LSEQ + t;
    const float dtv = dt[r*DI + d];
    const float xv  = bf2f(xsh[r*DI + d]);
    const float* xpr = xp + r*33;
    float yp = 0.f;
    #pragma unroll
    for (int i=0;i<4;i++){
      const int n = (nq<<2) + i;
      const float e = __expf(Aa[i]*dtv);
      P[i] *= e;
      const float Bv = xpr[1 + n];
      const float Cv = xpr[17 + n];
      const float gbx = rA[i] * (1.f - e) * Bv * xv;
      h[i] = fmaf(e, h[i], gbx);
      h[i] = fminf(10.f, fmaxf(-10.f, h[i]));
      yp = fmaf(Cv, h[i], yp);
    }
    yp += __shfl_xor(yp, 1);
    yp += __shfl_xor(yp, 2);
    if (nq == 0) y[r*XZL + d] = yp + Dv*xv;
  }
  const size_t pb = (((size_t)c*B_SZ + b)*DI + d)*NS + (nq<<2);
  *(float4*)(Pbuf+pb) = make_float4(P[0],P[1],P[2],P[3]);
  *(float4*)(Hbuf+pb) = make_float4(h[0],h[1],h[2],h[3]);
}

// ---------------- scan pass 2: sequential chunk combine; hin folded into Hbuf ----
__global__ __launch_bounds__(256)
void scan2_kernel(const float* __restrict__ Pbuf, float* __restrict__ Hbuf) {
  const int g = blockIdx.x*256 + threadIdx.x;
  const size_t cs = (size_t)B_SZ*DI*NS;
  float h = 0.f;
  for (int c=1;c<NC;++c){
    const float Pv = Pbuf[(size_t)(c-1)*cs + g];
    const float Hv = Hbuf[(size_t)(c-1)*cs + g];
    h = fmaf(Pv, h, Hv);
    Hbuf[(size_t)(c-1)*cs + g] = h;
  }
}

// ---------------- scan pass 3: light cross-chunk correction + silu(z) + y split ----
__global__ __launch_bounds__(256)
void scan3_kernel(const float* __restrict__ dt, const float* __restrict__ xp,
                  const float* __restrict__ Alog, const float* __restrict__ hinb,
                  const float* __restrict__ xz,
                  unsigned short* __restrict__ yh, unsigned short* __restrict__ yl) {
  const int g  = blockIdx.x*256 + threadIdx.x;
  const int nq = g & 3;
  const int g2 = g >> 2;
  const int d  = g2 & (DI-1);
  const int bc = g2 >> 11;
  const int c  = bc & (NC-1);
  const int b  = bc >> 6;
  const float4 al = *(const float4*)(Alog + (size_t)d*NS + (nq<<2));
  const float Aa[4] = {-__expf(al.x), -__expf(al.y), -__expf(al.z), -__expf(al.w)};
  float hi[4] = {0.f, 0.f, 0.f, 0.f};
  if (c > 0){
    const size_t pb = (((size_t)(c-1)*B_SZ + b)*DI + d)*NS + (nq<<2);
    const float4 hv = *(const float4*)(hinb + pb);
    hi[0]=hv.x; hi[1]=hv.y; hi[2]=hv.z; hi[3]=hv.w;
  }
  float q[4] = {1,1,1,1};
  const int t0 = c * TC;
  for (int t = t0; t < t0 + TC; ++t){
    const size_t r = (size_t)b*LSEQ + t;
    const float dtv = dt[r*DI + d];
    const float* xpr = xp + r*33;
    float cp = 0.f;
    #pragma unroll
    for (int i=0;i<4;i++){
      q[i] *= __expf(Aa[i]*dtv);
      const float Cv = xpr[17 + (nq<<2) + i];
      cp = fmaf(Cv*q[i], hi[i], cp);
    }
    cp += __shfl_xor(cp, 1);
    cp += __shfl_xor(cp, 2);
    if (nq == 0){
      const float zv = xz[r*XZL + 2048 + d];
      const float yv = (xz[r*XZL + d] + cp) * siluf(zv);
      const unsigned short h16 = f2bf(yv);
      yh[r*DI + d] = h16;
      yl[r*DI + d] = f2bf(yv - bf2f(h16));
    }
  }
}

extern "C" void kernel_launch(void* const* d_in, const int* in_sizes, int n_in,
                              void* d_out, int out_size, void* d_ws, size_t ws_size,
                              hipStream_t stream) {
  const float* x     = (const float*)d_in[0];
  const float* gamma = (const float*)d_in[1];
  const float* beta  = (const float*)d_in[2];
  const float* W_in  = (const float*)d_in[3];
  const float* cw    = (const float*)d_in[4];
  const float* cb    = (const float*)d_in[5];
  const float* Alog  = (const float*)d_in[6];
  const float* Dp    = (const float*)d_in[7];
  const float* Wx    = (const float*)d_in[8];
  const float* Wdt   = (const float*)d_in[9];
  const float* bdt   = (const float*)d_in[10];
  const float* Wout  = (const float*)d_in[11];
  float* out = (float*)d_out;
  float* ws  = (float*)d_ws;

  const size_t M1 = 1048576;
  float* xz   = ws;                 // 16M f32
  float* xsq  = ws + 16*M1;         // 8M f32: xs_h | y_h/y_l overlay
  float* dtb  = ws + 24*M1;         // 8M
  float* Pb   = ws + 32*M1;         // 4M
  float* Hb   = Pb + 4*M1;          // 4M
  float* xpb  = Hb + 4*M1;          // 135168 f32
  float* part = xpb + 135168;       // 4*RTOT*NPAD = 786432 f32
  float* wxzone = part + 786432;
  unsigned short* wx_h = (unsigned short*)wxzone;          // 98304 us
  unsigned short* wx_l = wx_h + (size_t)NPAD*DI;           // 98304 us
  unsigned short* xph  = wx_l + (size_t)NPAD*DI;           // 262144 us
  unsigned short* xpl  = xph + (size_t)RTOT*KDT;           // 262144 us
  unsigned short* wdh  = xpl + (size_t)RTOT*KDT;           // 131072 us
  unsigned short* wdl  = wdh + (size_t)DI*KDT;             // 131072 us
  unsigned short* zone = wdl + (size_t)DI*KDT;             // 12M us
  unsigned short* xn_h = zone;              // 4M us
  unsigned short* xn_l = zone + 4*M1;       // 4M us
  unsigned short* Wi_h = zone + 8*M1;       // 4M us (hi only)
  unsigned short* Wo_h = zone;              // 2M us (split AFTER gemm1, overlays xn_h)
  unsigned short* xs_h = (unsigned short*)xsq;
  unsigned short* y_h  = (unsigned short*)xsq;
  unsigned short* y_l  = (unsigned short*)xsq + 8*M1;

  ln_split_kernel<<<RTOT, 256, 0, stream>>>(x, gamma, beta, xn_h, xn_l);
  split_win_wx_kernel<<<(2*DI*DM/4 + NPAD*DI/4 + 255)/256, 256, 0, stream>>>(
      W_in, Wx, Wi_h, wx_h, wx_l);
  split_pad_wdt_kernel<<<(DI*KDT + 255)/256, 256, 0, stream>>>(Wdt, wdh, wdl);
  gemm_bf16x2<<<dim3(XZL/128, RTOT/128), 256, 0, stream>>>(xn_h, xn_l, Wi_h,
                                                           xz, RTOT, XZL, DM, XZL);
  split_hi_kernel<<<(DM*DI/4 + 255)/256, 256, 0, stream>>>(Wout, Wo_h, DM*DI/4);
  conv_silu_h_kernel<<<(RTOT*(DI/4))/256, 256, 0, stream>>>(xz, cw, cb, xs_h);
  xp_part_kernel<<<(RTOT/16)*4, 256, 0, stream>>>(xs_h, wx_h, wx_l, part);
  xp_reduce_kernel<<<(RTOT*KDT + 255)/256, 256, 0, stream>>>(part, xpb, xph, xpl);
  gemm_dt<<<dim3(DI/128, RTOT/128), 256, 0, stream>>>(xph, xpl, wdh, wdl, bdt, dtb);
  scan1_kernel<<<(B_SZ*NC*DI*4)/256, 256, 0, stream>>>(xs_h, dtb, xpb, Alog, Dp, xz, Pb, Hb);
  scan2_kernel<<<(B_SZ*DI*NS)/256, 256, 0, stream>>>(Pb, Hb);
  scan3_kernel<<<(B_SZ*NC*DI*4)/256, 256, 0, stream>>>(dtb, xpb, Alog, Hb, xz, y_h, y_l);
  gemm_bf16x2_b64<<<dim3(DM/128, RTOT/64), 256, 0, stream>>>(y_h, y_l, Wo_h,
                                                             out, RTOT, DM, DI, DM);
}